// Round 7
// baseline (1451.049 us; speedup 1.0000x reference)
//
#include <hip/hip_runtime.h>
#include <hip/hip_bf16.h>

// Informer forward, MI355X. Round 15: 2-phase double-buffered GEMM staging.
//  - Round-14: 1443us; fattn family ~190us total -> GEMM chain (~1ms, 174GF @ ~160TF)
//    is the pot. Old K-loop: barrier; STAGE(gl_lds16); barrier -> staging latency
//    (200-900cy) fully exposed every 32-K step against ~250cy compute.
//  - Fix (guide T3 minimal): LDS ping-pong (As/Ws[2]); issue stage t+1 BEFORE tile t's
//    ds_read+MFMA; ONE __syncthreads per iter (its vmcnt(0) drain now only pays the
//    residue after ~250cy of overlap). Buffer-safety: reads of buf[x] complete before
//    the barrier preceding the next write of buf[x]. Staging/MFMA/accum order
//    unchanged -> bit-identical numerics. mgemm64 LDS 8->16KB (8 blk/CU by thread
//    cap), mgemm 16->32KB (5 blk/CU).
//  - fattn untouched (round-14 state: ~90us, VALUBusy 67, Occ 71) for clean A/B.
// Retained: round-13 GEMM routing (mgemm 128^2 for L1 QKV/FFN1, mgemm64 64^2 else),
// round-14 fused-row fattn with ballot radix-select, global_load_lds staging,
// weight-transpose prologue, dtype sniffer.
// Round 14: passed, absmax 0.0098, 1443.4 us.
// B=16, LE=512, LD=256, D=512, H=8, dk=64, DFF=2048, NE=3, ND=2, TOPK=16.
// Encoder lengths: 512 -> conv(514)/pool -> 257 -> conv(259)/pool -> 130.

#define DM 512
#define DK 64

using bf16 = __hip_bfloat16;
typedef short s8v __attribute__((ext_vector_type(8)));
typedef float f4v __attribute__((ext_vector_type(4)));

__device__ inline float b2f(bf16 x) { return __bfloat162float(x); }
__device__ inline float u2f(unsigned short u) { return __uint_as_float((unsigned)u << 16); }

// flag f: 1 = raw inputs are bf16, 0 = raw inputs are fp32. idx in ELEMENTS.
__device__ inline float ldw(const void* p, unsigned i, int f) {
    return f ? b2f(((const bf16*)p)[i]) : ((const float*)p)[i];
}

// order-preserving float->u32 (monotonic)
__device__ inline unsigned f2ord(float s) {
    unsigned u = __float_as_uint(s);
    return u ^ ((unsigned)((int)u >> 31) | 0x80000000u);
}

// popcount of mask bits strictly below this lane
__device__ inline int popc_lt(unsigned long long m) {
    return (int)__builtin_amdgcn_mbcnt_hi((unsigned)(m >> 32),
            __builtin_amdgcn_mbcnt_lo((unsigned)m, 0u));
}

// async global->LDS, 16 B per lane; lds dst must be wave-uniform (lane i lands at dst+16*i)
__device__ inline void gl_lds16(const short* g, short* l) {
    __builtin_amdgcn_global_load_lds(
        (const __attribute__((address_space(1))) unsigned int*)g,
        (__attribute__((address_space(3))) unsigned int*)l,
        16, 0, 0);
}

// ---------------- dtype sniffer ----------------
__global__ __launch_bounds__(256) void sniff_k(const unsigned* __restrict__ x, int nwords,
                                               int* __restrict__ flag) {
    __shared__ int red[4];
    const int t = threadIdx.x;
    int c = 0;
    for (int i = t; i < nwords; i += 256) c += ((x[i] & 0x7F80u) == 0x3F80u) ? 1 : 0;
    #pragma unroll
    for (int o = 32; o > 0; o >>= 1) c += __shfl_down(c, o);
    __syncthreads();
    if ((t & 63) == 0) red[t >> 6] = c;
    __syncthreads();
    if (t == 0) flag[0] = (red[0] + red[1] + red[2] + red[3] > nwords / 20) ? 1 : 0;
}

// ---------------- reductions (blockDim == 256) ----------------
__device__ inline float block_sum256(float v, float* red) {
    #pragma unroll
    for (int o = 32; o > 0; o >>= 1) v += __shfl_down(v, o);
    __syncthreads();
    if ((threadIdx.x & 63) == 0) red[threadIdx.x >> 6] = v;
    __syncthreads();
    return red[0] + red[1] + red[2] + red[3];
}

// ---------------- embedding ----------------
__global__ __launch_bounds__(256) void embed_k(
    const void* __restrict__ xv, const void* __restrict__ vw, const void* __restrict__ vb,
    const void* __restrict__ xm, const void* __restrict__ mw, const void* __restrict__ mb,
    bf16* __restrict__ Out, int rows, int Cv, int Cm, const int* __restrict__ flagp)
{
    const int f = *flagp;
    int i = blockIdx.x * 256 + threadIdx.x;
    if (i >= rows * DM) return;
    const int r = i >> 9, d = i & 511;
    float acc = ldw(vb, d, f) + ldw(mb, d, f);
    for (int c = 0; c < Cv; ++c) acc += ldw(xv, r * Cv + c, f) * ldw(vw, c * DM + d, f);
    for (int c = 0; c < Cm; ++c) acc += ldw(xm, r * Cm + c, f) * ldw(mw, c * DM + d, f);
    Out[i] = __float2bfloat16(acc);
}

// ---------------- weight transpose: raw [K][N] -> bf16 [N][K]; z batches sub-mats ----------------
__global__ __launch_bounds__(256) void transp_k(
    const void* __restrict__ W, unsigned off, unsigned zstride, bf16* __restrict__ out,
    int K, int N, const int* __restrict__ flagp)
{
    __shared__ float tile[32][33];
    const int f = *flagp;
    const unsigned zo = blockIdx.z * zstride;
    const int t = threadIdx.x;
    const int tx = t & 31, ty = t >> 5;               // 32 x 8
    const int n0 = blockIdx.x * 32, k0 = blockIdx.y * 32;
    #pragma unroll
    for (int i = 0; i < 4; ++i)
        tile[ty + 8 * i][tx] = ldw(W, off + zo + (unsigned)(k0 + ty + 8 * i) * N + n0 + tx, f);
    __syncthreads();
    #pragma unroll
    for (int i = 0; i < 4; ++i)
        out[(size_t)zo + (size_t)(n0 + ty + 8 * i) * K + k0 + tx] = __float2bfloat16(tile[tx][ty + 8 * i]);
}

// ---------------- MFMA GEMM 128x128 (256 thr): C = A[M,K]@Wt[N,K]^T + bias ----------------
// 2-phase double-buffered staging via global_load_lds (16 B/lane): stage t+1 issued
// BEFORE tile t's ds_read+MFMA; one __syncthreads per K-step hides most load latency.
// Used only for large-grid GEMMs (encoder L1 QKV / FFN1: >= 768 blocks).
template<bool G3, bool RELU>
__global__ __launch_bounds__(256) void mgemm_k(
    const short* __restrict__ A, const int* __restrict__ ridx,
    const short* __restrict__ Wt,
    const void* __restrict__ bias, unsigned boff0,
    bf16* __restrict__ C, int M, int N, int K, int lda, int ldc,
    const int* __restrict__ flagp)
{
    __shared__ short As[2][128 * 32];
    __shared__ short Ws[2][128 * 32];
    const int t = threadIdx.x;
    const int bm = blockIdx.y * 128, bn = blockIdx.x * 128;
    const int lane = t & 63, wave = t >> 6;
    const int mbase = (wave >> 1) * 64, nbase = (wave & 1) * 64;
    const int l15 = lane & 15, quad = lane >> 4;
    const int lrow = lane >> 2, lk = (lane & 3) * 8;

    f4v acc[4][4] = {};

    auto stage = [&](int buf, int k0) {
        #pragma unroll
        for (int j = 0; j < 2; ++j) {
            const int rb = wave * 32 + j * 16;
            const int row = bm + rb + lrow;
            const int rowc = row < M ? row : M - 1;
            const short* g;
            if (G3) {
                const int r = ridx[(k0 >> 9) * M + rowc];
                g = A + (size_t)r * lda + (k0 & 511) + lk;
            } else {
                g = A + (size_t)rowc * lda + k0 + lk;
            }
            gl_lds16(g, &As[buf][rb * 32]);
        }
        #pragma unroll
        for (int j = 0; j < 2; ++j) {
            const int nb = wave * 32 + j * 16;
            gl_lds16(Wt + (size_t)(bn + nb + lrow) * K + k0 + lk, &Ws[buf][nb * 32]);
        }
    };

    const int nt = K >> 5;
    stage(0, 0);
    __syncthreads();
    for (int it = 0; it < nt; ++it) {
        if (it + 1 < nt) stage((it + 1) & 1, (it + 1) << 5);
        const int cb = it & 1;
        s8v af[4], bfv[4];
        #pragma unroll
        for (int i = 0; i < 4; ++i) {
            af[i]  = *(const s8v*)&As[cb][(mbase + i * 16 + l15) * 32 + quad * 8];
            bfv[i] = *(const s8v*)&Ws[cb][(nbase + i * 16 + l15) * 32 + quad * 8];
        }
        #pragma unroll
        for (int mi = 0; mi < 4; ++mi)
            #pragma unroll
            for (int ni = 0; ni < 4; ++ni)
                acc[mi][ni] = __builtin_amdgcn_mfma_f32_16x16x32_bf16(
                    af[mi], bfv[ni], acc[mi][ni], 0, 0, 0);
        if (it + 1 < nt) __syncthreads();
    }

    const int f = *flagp;
    float bv[4];
    #pragma unroll
    for (int ni = 0; ni < 4; ++ni)
        bv[ni] = ldw(bias, boff0 + (unsigned)(bn + nbase + ni * 16 + l15), f);

    #pragma unroll
    for (int mi = 0; mi < 4; ++mi) {
        #pragma unroll
        for (int r = 0; r < 4; ++r) {
            const int row = bm + mbase + mi * 16 + quad * 4 + r;
            if (row < M) {
                #pragma unroll
                for (int ni = 0; ni < 4; ++ni) {
                    float o = acc[mi][ni][r] + bv[ni];
                    if (RELU) o = fmaxf(o, 0.f);
                    C[(size_t)row * ldc + bn + nbase + ni * 16 + l15] = __float2bfloat16(o);
                }
            }
        }
    }
}

// ---------------- MFMA GEMM 64x64 (256 thr, 4 waves x 32x32): concurrency-first ----------------
// grid (N/64, cdiv(M,64)); 2-phase double-buffered staging (16 KB LDS, 8 blocks/CU cap).
template<bool G3, bool RELU>
__global__ __launch_bounds__(256) void mgemm64_k(
    const short* __restrict__ A, const int* __restrict__ ridx,
    const short* __restrict__ Wt,
    const void* __restrict__ bias, unsigned boff0,
    bf16* __restrict__ C, int M, int N, int K, int lda, int ldc,
    const int* __restrict__ flagp)
{
    __shared__ short As[2][64 * 32];
    __shared__ short Ws[2][64 * 32];
    const int t = threadIdx.x;
    const int bm = blockIdx.y * 64, bn = blockIdx.x * 64;
    const int lane = t & 63, wave = t >> 6;
    const int mbase = (wave >> 1) * 32, nbase = (wave & 1) * 32;
    const int l15 = lane & 15, quad = lane >> 4;
    const int lrow = lane >> 2, lk = (lane & 3) * 8;

    f4v acc[2][2] = {};

    auto stage = [&](int buf, int k0) {
        {   // A chunk: 16 rows per wave (4 waves cover 64)
            const int rb = wave * 16;
            const int row = bm + rb + lrow;
            const int rowc = row < M ? row : M - 1;
            const short* g;
            if (G3) {
                const int r = ridx[(k0 >> 9) * M + rowc];
                g = A + (size_t)r * lda + (k0 & 511) + lk;
            } else {
                g = A + (size_t)rowc * lda + k0 + lk;
            }
            gl_lds16(g, &As[buf][rb * 32]);
        }
        {   // B chunk: 16 rows per wave
            const int nb = wave * 16;
            gl_lds16(Wt + (size_t)(bn + nb + lrow) * K + k0 + lk, &Ws[buf][nb * 32]);
        }
    };

    const int nt = K >> 5;
    stage(0, 0);
    __syncthreads();
    for (int it = 0; it < nt; ++it) {
        if (it + 1 < nt) stage((it + 1) & 1, (it + 1) << 5);
        const int cb = it & 1;
        s8v af[2], bfv[2];
        #pragma unroll
        for (int i = 0; i < 2; ++i) {
            af[i]  = *(const s8v*)&As[cb][(mbase + i * 16 + l15) * 32 + quad * 8];
            bfv[i] = *(const s8v*)&Ws[cb][(nbase + i * 16 + l15) * 32 + quad * 8];
        }
        #pragma unroll
        for (int mi = 0; mi < 2; ++mi)
            #pragma unroll
            for (int ni = 0; ni < 2; ++ni)
                acc[mi][ni] = __builtin_amdgcn_mfma_f32_16x16x32_bf16(
                    af[mi], bfv[ni], acc[mi][ni], 0, 0, 0);
        if (it + 1 < nt) __syncthreads();
    }

    const int f = *flagp;
    float bv[2];
    #pragma unroll
    for (int ni = 0; ni < 2; ++ni)
        bv[ni] = ldw(bias, boff0 + (unsigned)(bn + nbase + ni * 16 + l15), f);

    #pragma unroll
    for (int mi = 0; mi < 2; ++mi) {
        #pragma unroll
        for (int r = 0; r < 4; ++r) {
            const int row = bm + mbase + mi * 16 + quad * 4 + r;
            if (row < M) {
                #pragma unroll
                for (int ni = 0; ni < 2; ++ni) {
                    float o = acc[mi][ni][r] + bv[ni];
                    if (RELU) o = fmaxf(o, 0.f);
                    C[(size_t)row * ldc + bn + nbase + ni * 16 + l15] = __float2bfloat16(o);
                }
            }
        }
    }
}

// ---------------- fused tile attention (strided q/k/v), 512 threads ----------------
// MODE 0: ProbSparse top-16. MODE 1: causal. MODE 2: plain cross.
// 8 waves: phase 1 = MFMA QK^T, direct-global K frags, 2-deep load pipeline;
// phase 2+3 = each wave owns rows {wave, wave+8}, processed FUSED (independent
// serial chains interleaved to hide VALU->SALU latency; shared V loads in MODE 1/2).
template<int MODE>
__global__ __launch_bounds__(512, 8) void fattn_k(
    bf16* __restrict__ q, const bf16* __restrict__ k, const bf16* __restrict__ v,
    int ldq, int ldkv, int Lq, int Lk)
{
    __shared__ short Qs[16 * 72];
    __shared__ float S[16 * 516];
    __shared__ int   PC[16][16];
    __shared__ float PE[16][16];

    const int t = threadIdx.x;
    const int q0 = blockIdx.x * 16, h = blockIdx.y, b = blockIdx.z;
    const int lane = t & 63, wave = t >> 6;           // 8 waves
    const int l15 = lane & 15, quad = lane >> 4;

    const int qv = (Lq - q0) < 16 ? (Lq - q0) : 16;

    const bf16* Kbase = k + (size_t)b * Lk * ldkv + h * DK;
    const bf16* Vbase = v + (size_t)b * Lk * ldkv + h * DK;
    bf16* Qbase = q + (size_t)(b * Lq + q0) * ldq + h * DK;

    const int kmax = (MODE == 1) ? (q0 + 16 < Lk ? q0 + 16 : Lk) : Lk;
    const int ntile = (kmax + 63) >> 6;
    const int kpad = ntile << 6;
    const int nchunk = kpad >> 4;

    {   // Q stage: all 512 threads (4B each; 16 rows x 128B)
        const int qr = t >> 5;
        const int qsrc = qr < qv ? qr : qv - 1;
        *(ushort2*)&Qs[qr * 72 + (t & 31) * 2] =
            *(const ushort2*)(Qbase + (size_t)qsrc * ldq + (t & 31) * 2);
    }
    __syncthreads();

    // ---- phase 1: S = QK^T / 8 (+ masks); 2-deep K-load pipeline ----
    {
        const s8v a0 = *(const s8v*)&Qs[l15 * 72 + quad * 8];
        const s8v a1 = *(const s8v*)&Qs[l15 * 72 + 32 + quad * 8];
        int c = wave;
        s8v b0, b1;
        if (c < nchunk) {
            int srow = c * 16 + l15; if (srow >= Lk) srow = Lk - 1;
            const bf16* kp = Kbase + (size_t)srow * ldkv + quad * 8;
            b0 = *(const s8v*)kp;
            b1 = *(const s8v*)(kp + 32);
        }
        while (c < nchunk) {
            const int cn = c + 8;
            s8v n0, n1;
            if (cn < nchunk) {
                int srow = cn * 16 + l15; if (srow >= Lk) srow = Lk - 1;
                const bf16* kp = Kbase + (size_t)srow * ldkv + quad * 8;
                n0 = *(const s8v*)kp;
                n1 = *(const s8v*)(kp + 32);
            }
            f4v acc = {0.f, 0.f, 0.f, 0.f};
            acc = __builtin_amdgcn_mfma_f32_16x16x32_bf16(a0, b0, acc, 0, 0, 0);
            acc = __builtin_amdgcn_mfma_f32_16x16x32_bf16(a1, b1, acc, 0, 0, 0);
            const int colg = c * 16 + l15;
            #pragma unroll
            for (int r = 0; r < 4; ++r) {
                const int qrow = quad * 4 + r;
                float s = acc[r] * 0.125f;
                if (colg >= Lk) s = -1e9f;
                if (MODE == 1 && colg > q0 + qrow) s = -1e9f;
                S[qrow * 516 + colg] = s;
            }
            b0 = n0; b1 = n1; c = cn;
        }
    }
    __syncthreads();

    // ---- phase 2+3: rows {wave, wave+8} processed fused ----
    const int rowA = wave, rowB = wave + 8;
    float aA = 0.f, aB = 0.f;
    float invA, invB;
    if (MODE == 0) {
        // packed keys: 23-bit quantized score | 9-bit col; 0 for padded cols
        unsigned keyA[8], keyB[8];
        #pragma unroll
        for (int j = 0; j < 8; ++j) {
            const int col = lane + 64 * j;
            const bool ok = col < kpad;
            keyA[j] = ok ? ((f2ord(S[rowA * 516 + col]) & 0xFFFFFE00u) | (unsigned)col) : 0u;
            keyB[j] = ok ? ((f2ord(S[rowB * 516 + col]) & 0xFFFFFE00u) | (unsigned)col) : 0u;
        }
        // row maxes (exp offsets): two interleaved butterflies
        unsigned kmA = keyA[0], kmB = keyB[0];
        #pragma unroll
        for (int j = 1; j < 8; ++j) {
            kmA = kmA > keyA[j] ? kmA : keyA[j];
            kmB = kmB > keyB[j] ? kmB : keyB[j];
        }
        #pragma unroll
        for (int off = 1; off < 64; off <<= 1) {
            const unsigned oA = __shfl_xor(kmA, off);
            const unsigned oB = __shfl_xor(kmB, off);
            kmA = kmA > oA ? kmA : oA;
            kmB = kmB > oB ? kmB : oB;
        }
        const float mrA = S[rowA * 516 + (int)(kmA & 511u)];
        const float mrB = S[rowB * 516 + (int)(kmB & 511u)];

        // interleaved full-32-bit binary searches (independent chains hide each
        // other's VALU->SALU->branch latency). Largest T with count(key >= T) >= 16;
        // keys distinct -> exact 16.
        unsigned TA = 0u, TB = 0u;
        bool dA = false, dB = false;
        for (int bbit = 31; bbit >= 0; --bbit) {
            if (!dA) {
                const unsigned T2 = TA | (1u << bbit);
                int c = 0;
                #pragma unroll
                for (int j = 0; j < 8; ++j)
                    c += (int)__popcll(__ballot(keyA[j] >= T2));
                if (c >= 16) { TA = T2; dA = (c == 16); }
            }
            if (!dB) {
                const unsigned T2 = TB | (1u << bbit);
                int c = 0;
                #pragma unroll
                for (int j = 0; j < 8; ++j)
                    c += (int)__popcll(__ballot(keyB[j] >= T2));
                if (c >= 16) { TB = T2; dB = (c == 16); }
            }
            if (dA && dB) break;
        }

        // compaction: exactly the 16 keys >= T per row -> (col, e) in LDS
        int cntA = 0, cntB = 0;
        #pragma unroll
        for (int j = 0; j < 8; ++j) {
            const bool sA = keyA[j] >= TA;
            const unsigned long long balA = __ballot(sA);
            if (sA) {
                const int p = cntA + popc_lt(balA);
                const int col = (int)(keyA[j] & 511u);
                PC[rowA][p] = col;
                PE[rowA][p] = expf(S[rowA * 516 + col] - mrA);
            }
            cntA += (int)__popcll(balA);
            const bool sB = keyB[j] >= TB;
            const unsigned long long balB = __ballot(sB);
            if (sB) {
                const int p = cntB + popc_lt(balB);
                const int col = (int)(keyB[j] & 511u);
                PC[rowB][p] = col;
                PE[rowB][p] = expf(S[rowB * 516 + col] - mrB);
            }
            cntB += (int)__popcll(balB);
        }
        // wave-private rows: same-wave DS ops in order; no barrier needed

        float denA = 0.f, denB = 0.f;
        #pragma unroll
        for (int it = 0; it < 16; ++it) {
            const int cA = PC[rowA][it];
            const float eA = PE[rowA][it];
            denA += eA;
            aA += eA * b2f(Vbase[(size_t)cA * ldkv + lane]);
            const int cB = PC[rowB][it];
            const float eB = PE[rowB][it];
            denB += eB;
            aB += eB * b2f(Vbase[(size_t)cB * ldkv + lane]);
        }
        invA = 1.f / denA;
        invB = 1.f / denB;
    } else {
        float lvA = -INFINITY, lvB = -INFINITY;
        #pragma unroll
        for (int j = 0; j < 8; ++j) {
            const int col = lane + 64 * j;
            if (col < kpad) {
                lvA = fmaxf(lvA, S[rowA * 516 + col]);
                lvB = fmaxf(lvB, S[rowB * 516 + col]);
            }
        }
        #pragma unroll
        for (int off = 1; off < 64; off <<= 1) {
            lvA = fmaxf(lvA, __shfl_xor(lvA, off));
            lvB = fmaxf(lvB, __shfl_xor(lvB, off));
        }
        float pA = 0.f, pB = 0.f;
        #pragma unroll
        for (int j = 0; j < 8; ++j) {
            const int col = lane + 64 * j;
            if (col < kpad) {
                const float wA = expf(S[rowA * 516 + col] - lvA);
                const float wB = expf(S[rowB * 516 + col] - lvB);
                S[rowA * 516 + col] = wA;
                S[rowB * 516 + col] = wB;
                pA += wA; pB += wB;
            }
        }
        #pragma unroll
        for (int off = 1; off < 64; off <<= 1) {
            pA += __shfl_xor(pA, off);
            pB += __shfl_xor(pB, off);
        }
        invA = 1.f / pA;
        invB = 1.f / pB;
        // fused PV: one V row feeds both rows' FMAs. Causal-masked cols have
        // w = exp(-1e9 - lv) = +0 exactly -> running to kmax is bit-identical.
        #pragma unroll 8
        for (int k2 = 0; k2 < kmax; ++k2) {
            const float vv = b2f(Vbase[(size_t)k2 * ldkv + lane]);
            aA += S[rowA * 516 + k2] * vv;
            aB += S[rowB * 516 + k2] * vv;
        }
    }
    if (rowA < qv)
        Qbase[(size_t)rowA * ldq + lane] = __float2bfloat16(aA * invA);
    if (rowB < qv)
        Qbase[(size_t)rowB * ldq + lane] = __float2bfloat16(aB * invB);
}

// ---------------- layernorm over D=512, optional residual; in-place safe ----------------
__global__ __launch_bounds__(256) void ln_off_k(
    const bf16* __restrict__ X, const bf16* __restrict__ R,
    const void* __restrict__ gb, unsigned goff,
    bf16* __restrict__ Out, const int* __restrict__ flagp)
{
    __shared__ float red[4];
    const int f = *flagp;
    const int t = threadIdx.x;
    const size_t base = (size_t)blockIdx.x * DM;
    float v0 = b2f(X[base + t]), v1 = b2f(X[base + t + 256]);
    if (R) { v0 += b2f(R[base + t]); v1 += b2f(R[base + t + 256]); }
    const float mean = block_sum256(v0 + v1, red) * (1.f / 512.f);
    const float d0 = v0 - mean, d1 = v1 - mean;
    const float var = block_sum256(d0 * d0 + d1 * d1, red) * (1.f / 512.f);
    const float rstd = rsqrtf(var + 1e-5f);
    Out[base + t]       = __float2bfloat16(d0 * rstd * ldw(gb, goff + t, f)       + ldw(gb, goff + 512 + t, f));
    Out[base + t + 256] = __float2bfloat16(d1 * rstd * ldw(gb, goff + t + 256, f) + ldw(gb, goff + 768 + t, f));
}

// ---------------- conv distill helpers ----------------
// conv weights w[2][o][c][j] -> transposed GEMM layout wt[layer][o][j*512+c]
__global__ __launch_bounds__(256) void convw_k(const void* __restrict__ w,
                                               bf16* __restrict__ wt, int total,
                                               const int* __restrict__ flagp) {
    const int f = *flagp;
    int i = blockIdx.x * 256 + threadIdx.x;
    if (i >= total) return;
    const int layer = i / 786432, rem2 = i % 786432;
    const int o = rem2 / 1536, rem = rem2 % 1536;
    const int j = rem >> 9, c = rem & 511;
    wt[i] = __float2bfloat16(ldw(w, (unsigned)layer * 786432u + (unsigned)(o * 512 + c) * 3 + j, f));
}

__global__ __launch_bounds__(256) void convidx_k(int* __restrict__ idx, int Lc, int L, int total) {
    int i = blockIdx.x * 256 + threadIdx.x;
    if (i >= total) return;
    const int j = i / (16 * Lc), mrem = i % (16 * Lc);
    const int b = mrem / Lc, l = mrem % Lc;
    int src = l + j - 2;
    src %= L; if (src < 0) src += L;
    idx[i] = b * L + src;
}

__global__ __launch_bounds__(256) void bnstat1_k(const bf16* __restrict__ Y, float* __restrict__ part, int M) {
    const int t = threadIdx.x;
    float s0 = 0.f, q0 = 0.f, s1 = 0.f, q1 = 0.f;
    for (int r = blockIdx.x; r < M; r += gridDim.x) {
        const ushort2 u = *reinterpret_cast<const ushort2*>(Y + (size_t)r * DM + t * 2);
        const float a = u2f(u.x), c = u2f(u.y);
        s0 += a; q0 += a * a;
        s1 += c; q1 += c * c;
    }
    float* p = part + (size_t)blockIdx.x * 1024;
    p[2 * t] = s0; p[2 * t + 1] = s1;
    p[512 + 2 * t] = q0; p[512 + 2 * t + 1] = q1;
}

__global__ __launch_bounds__(256) void bnstat2_k(const float* __restrict__ part, float* __restrict__ stats,
                                                 int nchunk, int M) {
    const int ch = blockIdx.x * 256 + threadIdx.x;
    if (ch >= 512) return;
    float S = 0.f, Qs = 0.f;
    for (int c = 0; c < nchunk; ++c) { S += part[c * 1024 + ch]; Qs += part[c * 1024 + 512 + ch]; }
    const float mean = S / (float)M;
    const float var = Qs / (float)M - mean * mean;
    stats[ch] = mean;
    stats[512 + ch] = fmaxf(var, 0.f);
}

__global__ __launch_bounds__(256) void bnpool_k(
    const bf16* __restrict__ Yc, const float* __restrict__ stats,
    const void* __restrict__ g, const void* __restrict__ bb, unsigned off,
    bf16* __restrict__ Out, int Lc, int Lout, int total, const int* __restrict__ flagp)
{
    const int f = *flagp;
    int i = blockIdx.x * 256 + threadIdx.x;
    if (i >= total) return;
    const int ch = i & 511;
    const int lp = (i >> 9) % Lout;
    const int b = i / (512 * Lout);
    const float mean = stats[ch], var = stats[512 + ch];
    const float sc = ldw(g, off + ch, f) * rsqrtf(var + 1e-5f);
    const float sh = ldw(bb, off + ch, f) - mean * sc;
    float mx = -INFINITY;
    const int l0 = 2 * lp - 1;
    #pragma unroll
    for (int d = 0; d < 3; ++d) {
        const int l = l0 + d;
        if (l >= 0 && l < Lc) {
            float v = b2f(Yc[((size_t)b * Lc + l) * DM + ch]) * sc + sh;
            v = v > 0.f ? v : expm1f(v);  // ELU
            mx = fmaxf(mx, v);
        }
    }
    Out[((size_t)b * Lout + lp) * DM + ch] = __float2bfloat16(mx);
}

// ---------------- final projection to CO=7, dtype-matched store ----------------
__global__ __launch_bounds__(256) void fc_k(
    const bf16* __restrict__ Yn, const void* __restrict__ fcw, const void* __restrict__ fcb,
    void* __restrict__ out, int total, const int* __restrict__ flagp)
{
    const int f = *flagp;
    int i = blockIdx.x * 256 + threadIdx.x;
    if (i >= total) return;
    const int r = i / 7, co = i % 7;
    const bf16* yr = Yn + (size_t)r * DM;
    float acc = ldw(fcb, co, f);
    for (int d = 0; d < DM; ++d) acc += b2f(yr[d]) * ldw(fcw, d * 7 + co, f);
    if (f) ((bf16*)out)[i] = __float2bfloat16(acc);
    else   ((float*)out)[i] = acc;
}

// =============================================================================
extern "C" void kernel_launch(void* const* d_in, const int* in_sizes, int n_in,
                              void* d_out, int out_size, void* d_ws, size_t ws_size,
                              hipStream_t stream)
{
    const void* x_enc      = d_in[0];
    const void* x_mark_enc = d_in[1];
    const void* x_dec      = d_in[2];
    const void* x_mark_dec = d_in[3];
    const void* enc_vw = d_in[4];
    const void* enc_vb = d_in[5];
    const void* enc_mw = d_in[6];
    const void* enc_mb = d_in[7];
    const void* dec_vw = d_in[8];
    const void* dec_vb = d_in[9];
    const void* dec_mw = d_in[10];
    const void* dec_mb = d_in[11];
    const void* eW    = d_in[12];
    const void* ebi   = d_in[13];
    const void* effw1 = d_in[14];
    const void* effb1 = d_in[15];
    const void* effw2 = d_in[16];
    const void* effb2 = d_in[17];
    const void* eln1  = d_in[18];
    const void* eln2  = d_in[19];
    const void* cw    = d_in[20];
    const void* cb    = d_in[21];
    const void* cbn_g = d_in[22];
    const void* cbn_b = d_in[23];
    const void* enc_norm = d_in[24];
    const void* dsW   = d_in[25];
    const void* dsb   = d_in[26];
    const void* dcW   = d_in[27];
    const void* dcb   = d_in[28];
    const void* dffw1 = d_in[29];
    const void* dffb1 = d_in[30];
    const void* dffw2 = d_in[31];
    const void* dffb2 = d_in[32];
    const void* dln   = d_in[33];
    const void* dec_norm = d_in[34];
    const void* fcw   = d_in[35];
    const void* fcb   = d_in[36];

    // ---- workspace layout (~90 MiB; 111 MiB footprint ran clean in round 1) ----
    // X    [0, 8M)      : encoder acts; MEM + Yd in decoder phase
    // QKV  [8M, 40M)    : fused QKV / FFN hidden (aliased) / conv out / cross CQ+CKV
    // OUT  [40M, 48M)   : O-proj / FFN2 dest
    // WT   [48M, ~86.8M): ALL transposed weights (one-time prologue)
    // misc [88M, ~90M)  : IDX0/IDX1, PART, STATS, FLAG
    char* wsp = (char*)d_ws;
    bf16* X    = (bf16*)wsp;
    bf16* QKV  = (bf16*)(wsp + ((size_t)8 << 20));
    bf16* HID  = QKV;                                 // FFN hidden aliases dead QKV
    bf16* OUT  = (bf16*)(wsp + ((size_t)40 << 20));
    bf16* WT   = (bf16*)(wsp + ((size_t)48 << 20));
    int*   IDX0 = (int*)(wsp + ((size_t)88 << 20));   // 3*16*514 = 24672 ints
    int*   IDX1 = IDX0 + 24672;                       // 3*16*259 = 12432 ints
    float* PART = (float*)(wsp + ((size_t)89 << 20));
    float* STATS= (float*)(wsp + ((size_t)89 << 20) + (1 << 18));
    int*   FLAG = (int*)(wsp + ((size_t)89 << 20) + (1 << 18) + 4096);
    bf16* MEMb = X;                                               // [2080][512]
    bf16* Yd   = (bf16*)(wsp + (size_t)16 * 130 * 512 * 2);       // [4096][512]

    // transposed weight sub-arenas (element offsets)
    bf16* WTE  = WT;                    // enc QKVO: (i*4+q)*262144
    bf16* EW1T = WT + 3145728;          // + i*1048576
    bf16* EW2T = WT + 6291456;          // + i*1048576
    bf16* CWT  = WT + 9437184;          // + i*786432
    bf16* DSWt = WT + 11010048;         // + (i*4+q)*262144
    bf16* DCWt = WT + 13107200;
    bf16* DW1T = WT + 15204352;
    bf16* DW2T = WT + 17301504;

    auto cdiv = [](int a, int b) { return (a + b - 1) / b; };
    auto gemm = [&](const bf16* A, const bf16* Wt, const void* bias, unsigned boff,
                    bf16* C, int M, int N, int K, int lda, int ldc, bool relu) {
        dim3 g(N / 128, cdiv(M, 128));
        if (relu) mgemm_k<false, true><<<g, 256, 0, stream>>>(
            (const short*)A, nullptr, (const short*)Wt, bias, boff, C, M, N, K, lda, ldc, FLAG);
        else      mgemm_k<false, false><<<g, 256, 0, stream>>>(
            (const short*)A, nullptr, (const short*)Wt, bias, boff, C, M, N, K, lda, ldc, FLAG);
    };
    auto gemm64 = [&](const bf16* A, const bf16* Wt, const void* bias, unsigned boff,
                      bf16* C, int M, int N, int K, int lda, int ldc, bool relu) {
        dim3 g(N / 64, cdiv(M, 64));
        if (relu) mgemm64_k<false, true><<<g, 256, 0, stream>>>(
            (const short*)A, nullptr, (const short*)Wt, bias, boff, C, M, N, K, lda, ldc, FLAG);
        else      mgemm64_k<false, false><<<g, 256, 0, stream>>>(
            (const short*)A, nullptr, (const short*)Wt, bias, boff, C, M, N, K, lda, ldc, FLAG);
    };
    auto transp = [&](const void* W, unsigned zstride, int nz, bf16* out, int K, int N) {
        transp_k<<<dim3(N / 32, K / 32, nz), 256, 0, stream>>>(W, 0u, zstride, out, K, N, FLAG);
    };

    // ---- prologue: sniff, all weight transposes, conv indices, embeddings ----
    sniff_k<<<1, 256, 0, stream>>>((const unsigned*)x_mark_enc, 16384, FLAG);
    transp(eW,    262144u, 12, WTE,  512, 512);
    transp(effw1, 1048576u, 3, EW1T, 512, 2048);
    transp(effw2, 1048576u, 3, EW2T, 2048, 512);
    convw_k<<<cdiv(1572864, 256), 256, 0, stream>>>(cw, CWT, 1572864, FLAG);
    transp(dsW,   262144u, 8, DSWt, 512, 512);
    transp(dcW,   262144u, 8, DCWt, 512, 512);
    transp(dffw1, 1048576u, 2, DW1T, 512, 2048);
    transp(dffw2, 1048576u, 2, DW2T, 2048, 512);
    convidx_k<<<cdiv(24672, 256), 256, 0, stream>>>(IDX0, 514, 512, 24672);
    convidx_k<<<cdiv(12432, 256), 256, 0, stream>>>(IDX1, 259, 257, 12432);
    embed_k<<<cdiv(16 * 512 * 512, 256), 256, 0, stream>>>(
        x_enc, enc_vw, enc_vb, x_mark_enc, enc_mw, enc_mb, X, 16 * 512, 7, 4, FLAG);

    // ---- encoder ----
    int L = 512;
    for (int i = 0; i < 3; ++i) {
        const int rows = 16 * L;
        const unsigned b0 = (unsigned)i * 4u * 512u;
        // QKV: big grid only at L=512 -> mgemm; else 64x64 for concurrency
        if (i == 0) gemm(X, WTE + (size_t)i * 4 * 262144, ebi, b0, QKV, rows, 1536, 512, 512, 1536, false);
        else      gemm64(X, WTE + (size_t)i * 4 * 262144, ebi, b0, QKV, rows, 1536, 512, 512, 1536, false);
        fattn_k<0><<<dim3(cdiv(L, 16), 8, 16), 512, 0, stream>>>(
            QKV, QKV + 512, QKV + 1024, 1536, 1536, L, L);
        gemm64(QKV, WTE + (size_t)(i * 4 + 3) * 262144, ebi, b0 + 1536u, OUT, rows, 512, 512, 1536, 512, false);
        ln_off_k<<<rows, 256, 0, stream>>>(X, OUT, eln1, (unsigned)i * 1024u, X, FLAG);

        if (i == 0) gemm(X, EW1T + (size_t)i * 1048576, effb1, (unsigned)i * 2048u, HID, rows, 2048, 512, 512, 2048, true);
        else      gemm64(X, EW1T + (size_t)i * 1048576, effb1, (unsigned)i * 2048u, HID, rows, 2048, 512, 512, 2048, true);
        gemm64(HID, EW2T + (size_t)i * 1048576, effb2, (unsigned)i * 512u, OUT, rows, 512, 2048, 2048, 512, false);
        ln_off_k<<<rows, 256, 0, stream>>>(X, OUT, eln2, (unsigned)i * 1024u, X, FLAG);

        if (i < 2) {
            const int Lc = L + 2, Mc = 16 * Lc;
            const int* IDXi = (i == 0) ? IDX0 : IDX1;
            mgemm64_k<true, false><<<dim3(8, cdiv(Mc, 64)), 256, 0, stream>>>(
                (const short*)X, IDXi, (const short*)(CWT + (size_t)i * 786432),
                cb, (unsigned)i * 512u, QKV, Mc, 512, 1536, 512, 512, FLAG);
            bnstat1_k<<<32, 256, 0, stream>>>(QKV, PART, Mc);
            bnstat2_k<<<2, 256, 0, stream>>>(PART, STATS, 32, Mc);
            const int Lout = (L + 1) / 2 + 1;   // 514->257, 259->130
            const int tot = 16 * Lout * 512;
            bnpool_k<<<cdiv(tot, 256), 256, 0, stream>>>(
                QKV, STATS, cbn_g, cbn_b, (unsigned)i * 512u, X, Lc, Lout, tot, FLAG);
            L = Lout;
        }
    }
    const int Lm = L;  // 130
    ln_off_k<<<16 * Lm, 256, 0, stream>>>(X, nullptr, enc_norm, 0u, MEMb, FLAG);

    // ---- decoder embedding ----
    const int rowsD = 16 * 256;
    embed_k<<<cdiv(rowsD * 512, 256), 256, 0, stream>>>(
        x_dec, dec_vw, dec_vb, x_mark_dec, dec_mw, dec_mb, Yd, rowsD, 7, 4, FLAG);

    // ---- decoder (all GEMMs via 64x64 for concurrency) ----
    bf16* CQ  = QKV;                       // [4096][512]
    bf16* CKV = QKV + (size_t)4096 * 512;  // [2080][1024]
    for (int i = 0; i < 2; ++i) {
        const unsigned b0 = (unsigned)i * 4u * 512u;
        // self-attention
        gemm64(Yd, DSWt + (size_t)i * 4 * 262144, dsb, b0, QKV, rowsD, 1536, 512, 512, 1536, false);
        fattn_k<1><<<dim3(16, 8, 16), 512, 0, stream>>>(
            QKV, QKV + 512, QKV + 1024, 1536, 1536, 256, 256);
        gemm64(QKV, DSWt + (size_t)(i * 4 + 3) * 262144, dsb, b0 + 1536u, OUT, rowsD, 512, 512, 1536, 512, false);
        ln_off_k<<<rowsD, 256, 0, stream>>>(Yd, OUT, dln, (unsigned)(i * 3 + 0) * 1024u, Yd, FLAG);

        // cross-attention
        gemm64(Yd, DCWt + (size_t)i * 4 * 262144, dcb, b0, CQ, rowsD, 512, 512, 512, 512, false);
        gemm64(MEMb, DCWt + (size_t)(i * 4 + 1) * 262144, dcb, b0 + 512u, CKV, 16 * Lm, 1024, 512, 512, 1024, false);
        fattn_k<2><<<dim3(16, 8, 16), 512, 0, stream>>>(
            CQ, CKV, CKV + 512, 512, 1024, 256, Lm);
        gemm64(CQ, DCWt + (size_t)(i * 4 + 3) * 262144, dcb, b0 + 1536u, OUT, rowsD, 512, 512, 512, 512, false);
        ln_off_k<<<rowsD, 256, 0, stream>>>(Yd, OUT, dln, (unsigned)(i * 3 + 1) * 1024u, Yd, FLAG);

        // FFN
        gemm64(Yd, DW1T + (size_t)i * 1048576, dffb1, (unsigned)i * 2048u, HID, rowsD, 2048, 512, 512, 2048, true);
        gemm64(HID, DW2T + (size_t)i * 1048576, dffb2, (unsigned)i * 512u, OUT, rowsD, 512, 2048, 2048, 512, false);
        ln_off_k<<<rowsD, 256, 0, stream>>>(Yd, OUT, dln, (unsigned)(i * 3 + 2) * 1024u, Yd, FLAG);
    }

    ln_off_k<<<rowsD, 256, 0, stream>>>(Yd, nullptr, dec_norm, 0u, OUT, FLAG);
    fc_k<<<cdiv(rowsD * 7, 256), 256, 0, stream>>>(OUT, fcw, fcb, d_out, rowsD * 7, FLAG);
}

// Round 8
// 1367.224 us; speedup vs baseline: 1.0613x; 1.0613x over previous
//
#include <hip/hip_runtime.h>
#include <hip/hip_bf16.h>

// Informer forward, MI355X. Round 16: fattn XCD-locality swizzle + dbuf post-mortem.
//  - Round-15 dbuf was NEUTRAL (1443->1451): implicit multi-block overlap already
//    hides staging (guide m99/m100). Revert mgemm_k to single-buffer (restores
//    8 blocks/CU; dbuf had cut it to 5). Keep mgemm64_k dbuf (thread-capped at 8
//    blocks/CU either way; helps its small grids).
//  - LDS fingerprint re-read: MODE1/2 fattn = 35328 B, MODE0 = 37376 B. Round-13's
//    96us top rows were DECODER MODE1/2 (write 4.1MB = decoder output); round-14's
//    PV fusion fixed those. Now top = fattn<0> L=512: 89.5us with FETCH 68.5MB +
//    WRITE 90MB = 160MB @ 1.78TB/s == the 89us. Unique data ~33MB -> amplification:
//    qb-major dispatch spreads the 32 blocks sharing one (b,h)'s K/V across all 8
//    XCD L2s (8x re-fetch) + writeback churn.
//  - Fix (T1): bijective XCD swizzle inside fattn: id = (lin%8)*(nwg/8) + lin/8;
//    each XCD gets a contiguous id range; consecutive ids share (b,h) -> K/V
//    L2-resident (~2MB/XCD). nwg = gx*128 always %8==0 -> bijection. Same work,
//    bit-identical output.
//  - bnstat1: 32 -> 64 blocks (PART arena holds 64*4KB) + 4-deep unrolled row loop.
// Round 15: passed, absmax 0.0098, 1451.0 us (round 14: 1443.4).
// B=16, LE=512, LD=256, D=512, H=8, dk=64, DFF=2048, NE=3, ND=2, TOPK=16.
// Encoder lengths: 512 -> conv(514)/pool -> 257 -> conv(259)/pool -> 130.

#define DM 512
#define DK 64

using bf16 = __hip_bfloat16;
typedef short s8v __attribute__((ext_vector_type(8)));
typedef float f4v __attribute__((ext_vector_type(4)));

__device__ inline float b2f(bf16 x) { return __bfloat162float(x); }
__device__ inline float u2f(unsigned short u) { return __uint_as_float((unsigned)u << 16); }

// flag f: 1 = raw inputs are bf16, 0 = raw inputs are fp32. idx in ELEMENTS.
__device__ inline float ldw(const void* p, unsigned i, int f) {
    return f ? b2f(((const bf16*)p)[i]) : ((const float*)p)[i];
}

// order-preserving float->u32 (monotonic)
__device__ inline unsigned f2ord(float s) {
    unsigned u = __float_as_uint(s);
    return u ^ ((unsigned)((int)u >> 31) | 0x80000000u);
}

// popcount of mask bits strictly below this lane
__device__ inline int popc_lt(unsigned long long m) {
    return (int)__builtin_amdgcn_mbcnt_hi((unsigned)(m >> 32),
            __builtin_amdgcn_mbcnt_lo((unsigned)m, 0u));
}

// async global->LDS, 16 B per lane; lds dst must be wave-uniform (lane i lands at dst+16*i)
__device__ inline void gl_lds16(const short* g, short* l) {
    __builtin_amdgcn_global_load_lds(
        (const __attribute__((address_space(1))) unsigned int*)g,
        (__attribute__((address_space(3))) unsigned int*)l,
        16, 0, 0);
}

// ---------------- dtype sniffer ----------------
__global__ __launch_bounds__(256) void sniff_k(const unsigned* __restrict__ x, int nwords,
                                               int* __restrict__ flag) {
    __shared__ int red[4];
    const int t = threadIdx.x;
    int c = 0;
    for (int i = t; i < nwords; i += 256) c += ((x[i] & 0x7F80u) == 0x3F80u) ? 1 : 0;
    #pragma unroll
    for (int o = 32; o > 0; o >>= 1) c += __shfl_down(c, o);
    __syncthreads();
    if ((t & 63) == 0) red[t >> 6] = c;
    __syncthreads();
    if (t == 0) flag[0] = (red[0] + red[1] + red[2] + red[3] > nwords / 20) ? 1 : 0;
}

// ---------------- reductions (blockDim == 256) ----------------
__device__ inline float block_sum256(float v, float* red) {
    #pragma unroll
    for (int o = 32; o > 0; o >>= 1) v += __shfl_down(v, o);
    __syncthreads();
    if ((threadIdx.x & 63) == 0) red[threadIdx.x >> 6] = v;
    __syncthreads();
    return red[0] + red[1] + red[2] + red[3];
}

// ---------------- embedding ----------------
__global__ __launch_bounds__(256) void embed_k(
    const void* __restrict__ xv, const void* __restrict__ vw, const void* __restrict__ vb,
    const void* __restrict__ xm, const void* __restrict__ mw, const void* __restrict__ mb,
    bf16* __restrict__ Out, int rows, int Cv, int Cm, const int* __restrict__ flagp)
{
    const int f = *flagp;
    int i = blockIdx.x * 256 + threadIdx.x;
    if (i >= rows * DM) return;
    const int r = i >> 9, d = i & 511;
    float acc = ldw(vb, d, f) + ldw(mb, d, f);
    for (int c = 0; c < Cv; ++c) acc += ldw(xv, r * Cv + c, f) * ldw(vw, c * DM + d, f);
    for (int c = 0; c < Cm; ++c) acc += ldw(xm, r * Cm + c, f) * ldw(mw, c * DM + d, f);
    Out[i] = __float2bfloat16(acc);
}

// ---------------- weight transpose: raw [K][N] -> bf16 [N][K]; z batches sub-mats ----------------
__global__ __launch_bounds__(256) void transp_k(
    const void* __restrict__ W, unsigned off, unsigned zstride, bf16* __restrict__ out,
    int K, int N, const int* __restrict__ flagp)
{
    __shared__ float tile[32][33];
    const int f = *flagp;
    const unsigned zo = blockIdx.z * zstride;
    const int t = threadIdx.x;
    const int tx = t & 31, ty = t >> 5;               // 32 x 8
    const int n0 = blockIdx.x * 32, k0 = blockIdx.y * 32;
    #pragma unroll
    for (int i = 0; i < 4; ++i)
        tile[ty + 8 * i][tx] = ldw(W, off + zo + (unsigned)(k0 + ty + 8 * i) * N + n0 + tx, f);
    __syncthreads();
    #pragma unroll
    for (int i = 0; i < 4; ++i)
        out[(size_t)zo + (size_t)(n0 + ty + 8 * i) * K + k0 + tx] = __float2bfloat16(tile[tx][ty + 8 * i]);
}

// ---------------- MFMA GEMM 128x128 (256 thr): C = A[M,K]@Wt[N,K]^T + bias ----------------
// Single-buffered staging via global_load_lds (16 B/lane): round-15's dbuf was neutral
// and cost occupancy (8->5 blocks/CU); implicit multi-block overlap hides the latency.
// Used only for large-grid GEMMs (encoder L1 QKV / FFN1: >= 768 blocks).
template<bool G3, bool RELU>
__global__ __launch_bounds__(256) void mgemm_k(
    const short* __restrict__ A, const int* __restrict__ ridx,
    const short* __restrict__ Wt,
    const void* __restrict__ bias, unsigned boff0,
    bf16* __restrict__ C, int M, int N, int K, int lda, int ldc,
    const int* __restrict__ flagp)
{
    __shared__ short As[128 * 32];
    __shared__ short Ws[128 * 32];
    const int t = threadIdx.x;
    const int bm = blockIdx.y * 128, bn = blockIdx.x * 128;
    const int lane = t & 63, wave = t >> 6;
    const int mbase = (wave >> 1) * 64, nbase = (wave & 1) * 64;
    const int l15 = lane & 15, quad = lane >> 4;
    const int lrow = lane >> 2, lk = (lane & 3) * 8;

    f4v acc[4][4] = {};

    for (int k0 = 0; k0 < K; k0 += 32) {
        __syncthreads();
        #pragma unroll
        for (int j = 0; j < 2; ++j) {
            const int rb = wave * 32 + j * 16;
            const int row = bm + rb + lrow;
            const int rowc = row < M ? row : M - 1;
            const short* g;
            if (G3) {
                const int r = ridx[(k0 >> 9) * M + rowc];
                g = A + (size_t)r * lda + (k0 & 511) + lk;
            } else {
                g = A + (size_t)rowc * lda + k0 + lk;
            }
            gl_lds16(g, &As[rb * 32]);
        }
        #pragma unroll
        for (int j = 0; j < 2; ++j) {
            const int nb = wave * 32 + j * 16;
            gl_lds16(Wt + (size_t)(bn + nb + lrow) * K + k0 + lk, &Ws[nb * 32]);
        }
        __syncthreads();
        s8v af[4], bfv[4];
        #pragma unroll
        for (int i = 0; i < 4; ++i) {
            af[i]  = *(const s8v*)&As[(mbase + i * 16 + l15) * 32 + quad * 8];
            bfv[i] = *(const s8v*)&Ws[(nbase + i * 16 + l15) * 32 + quad * 8];
        }
        #pragma unroll
        for (int mi = 0; mi < 4; ++mi)
            #pragma unroll
            for (int ni = 0; ni < 4; ++ni)
                acc[mi][ni] = __builtin_amdgcn_mfma_f32_16x16x32_bf16(
                    af[mi], bfv[ni], acc[mi][ni], 0, 0, 0);
    }

    const int f = *flagp;
    float bv[4];
    #pragma unroll
    for (int ni = 0; ni < 4; ++ni)
        bv[ni] = ldw(bias, boff0 + (unsigned)(bn + nbase + ni * 16 + l15), f);

    #pragma unroll
    for (int mi = 0; mi < 4; ++mi) {
        #pragma unroll
        for (int r = 0; r < 4; ++r) {
            const int row = bm + mbase + mi * 16 + quad * 4 + r;
            if (row < M) {
                #pragma unroll
                for (int ni = 0; ni < 4; ++ni) {
                    float o = acc[mi][ni][r] + bv[ni];
                    if (RELU) o = fmaxf(o, 0.f);
                    C[(size_t)row * ldc + bn + nbase + ni * 16 + l15] = __float2bfloat16(o);
                }
            }
        }
    }
}

// ---------------- MFMA GEMM 64x64 (256 thr, 4 waves x 32x32): concurrency-first ----------------
// grid (N/64, cdiv(M,64)); 2-phase double-buffered staging (16 KB LDS, 8 blocks/CU cap).
template<bool G3, bool RELU>
__global__ __launch_bounds__(256) void mgemm64_k(
    const short* __restrict__ A, const int* __restrict__ ridx,
    const short* __restrict__ Wt,
    const void* __restrict__ bias, unsigned boff0,
    bf16* __restrict__ C, int M, int N, int K, int lda, int ldc,
    const int* __restrict__ flagp)
{
    __shared__ short As[2][64 * 32];
    __shared__ short Ws[2][64 * 32];
    const int t = threadIdx.x;
    const int bm = blockIdx.y * 64, bn = blockIdx.x * 64;
    const int lane = t & 63, wave = t >> 6;
    const int mbase = (wave >> 1) * 32, nbase = (wave & 1) * 32;
    const int l15 = lane & 15, quad = lane >> 4;
    const int lrow = lane >> 2, lk = (lane & 3) * 8;

    f4v acc[2][2] = {};

    auto stage = [&](int buf, int k0) {
        {   // A chunk: 16 rows per wave (4 waves cover 64)
            const int rb = wave * 16;
            const int row = bm + rb + lrow;
            const int rowc = row < M ? row : M - 1;
            const short* g;
            if (G3) {
                const int r = ridx[(k0 >> 9) * M + rowc];
                g = A + (size_t)r * lda + (k0 & 511) + lk;
            } else {
                g = A + (size_t)rowc * lda + k0 + lk;
            }
            gl_lds16(g, &As[buf][rb * 32]);
        }
        {   // B chunk: 16 rows per wave
            const int nb = wave * 16;
            gl_lds16(Wt + (size_t)(bn + nb + lrow) * K + k0 + lk, &Ws[buf][nb * 32]);
        }
    };

    const int nt = K >> 5;
    stage(0, 0);
    __syncthreads();
    for (int it = 0; it < nt; ++it) {
        if (it + 1 < nt) stage((it + 1) & 1, (it + 1) << 5);
        const int cb = it & 1;
        s8v af[2], bfv[2];
        #pragma unroll
        for (int i = 0; i < 2; ++i) {
            af[i]  = *(const s8v*)&As[cb][(mbase + i * 16 + l15) * 32 + quad * 8];
            bfv[i] = *(const s8v*)&Ws[cb][(nbase + i * 16 + l15) * 32 + quad * 8];
        }
        #pragma unroll
        for (int mi = 0; mi < 2; ++mi)
            #pragma unroll
            for (int ni = 0; ni < 2; ++ni)
                acc[mi][ni] = __builtin_amdgcn_mfma_f32_16x16x32_bf16(
                    af[mi], bfv[ni], acc[mi][ni], 0, 0, 0);
        if (it + 1 < nt) __syncthreads();
    }

    const int f = *flagp;
    float bv[2];
    #pragma unroll
    for (int ni = 0; ni < 2; ++ni)
        bv[ni] = ldw(bias, boff0 + (unsigned)(bn + nbase + ni * 16 + l15), f);

    #pragma unroll
    for (int mi = 0; mi < 2; ++mi) {
        #pragma unroll
        for (int r = 0; r < 4; ++r) {
            const int row = bm + mbase + mi * 16 + quad * 4 + r;
            if (row < M) {
                #pragma unroll
                for (int ni = 0; ni < 2; ++ni) {
                    float o = acc[mi][ni][r] + bv[ni];
                    if (RELU) o = fmaxf(o, 0.f);
                    C[(size_t)row * ldc + bn + nbase + ni * 16 + l15] = __float2bfloat16(o);
                }
            }
        }
    }
}

// ---------------- fused tile attention (strided q/k/v), 512 threads ----------------
// MODE 0: ProbSparse top-16. MODE 1: causal. MODE 2: plain cross.
// XCD-locality swizzle: bijective remap so each XCD L2 serves a contiguous id range
// (consecutive ids share (b,h) -> K/V stay L2-resident instead of 8x re-fetch).
// 8 waves: phase 1 = MFMA QK^T, direct-global K frags, 2-deep load pipeline;
// phase 2+3 = each wave owns rows {wave, wave+8}, processed FUSED.
template<int MODE>
__global__ __launch_bounds__(512, 8) void fattn_k(
    bf16* __restrict__ q, const bf16* __restrict__ k, const bf16* __restrict__ v,
    int ldq, int ldkv, int Lq, int Lk)
{
    __shared__ short Qs[16 * 72];
    __shared__ float S[16 * 516];
    __shared__ int   PC[16][16];
    __shared__ float PE[16][16];

    const int t = threadIdx.x;
    // ---- XCD swizzle (bijective: nwg = gx*128, always % 8 == 0) ----
    const int gx = gridDim.x;
    const int nwg = gx * 128;                         // y=8, z=16 fixed
    const int lin = blockIdx.x + gx * (blockIdx.y + 8 * blockIdx.z);
    const int id = (lin & 7) * (nwg >> 3) + (lin >> 3);
    const int q0 = (id % gx) * 16;
    const int h  = (id / gx) & 7;
    const int b  = id / (gx * 8);

    const int lane = t & 63, wave = t >> 6;           // 8 waves
    const int l15 = lane & 15, quad = lane >> 4;

    const int qv = (Lq - q0) < 16 ? (Lq - q0) : 16;

    const bf16* Kbase = k + (size_t)b * Lk * ldkv + h * DK;
    const bf16* Vbase = v + (size_t)b * Lk * ldkv + h * DK;
    bf16* Qbase = q + (size_t)(b * Lq + q0) * ldq + h * DK;

    const int kmax = (MODE == 1) ? (q0 + 16 < Lk ? q0 + 16 : Lk) : Lk;
    const int ntile = (kmax + 63) >> 6;
    const int kpad = ntile << 6;
    const int nchunk = kpad >> 4;

    {   // Q stage: all 512 threads (4B each; 16 rows x 128B)
        const int qr = t >> 5;
        const int qsrc = qr < qv ? qr : qv - 1;
        *(ushort2*)&Qs[qr * 72 + (t & 31) * 2] =
            *(const ushort2*)(Qbase + (size_t)qsrc * ldq + (t & 31) * 2);
    }
    __syncthreads();

    // ---- phase 1: S = QK^T / 8 (+ masks); 2-deep K-load pipeline ----
    {
        const s8v a0 = *(const s8v*)&Qs[l15 * 72 + quad * 8];
        const s8v a1 = *(const s8v*)&Qs[l15 * 72 + 32 + quad * 8];
        int c = wave;
        s8v b0, b1;
        if (c < nchunk) {
            int srow = c * 16 + l15; if (srow >= Lk) srow = Lk - 1;
            const bf16* kp = Kbase + (size_t)srow * ldkv + quad * 8;
            b0 = *(const s8v*)kp;
            b1 = *(const s8v*)(kp + 32);
        }
        while (c < nchunk) {
            const int cn = c + 8;
            s8v n0, n1;
            if (cn < nchunk) {
                int srow = cn * 16 + l15; if (srow >= Lk) srow = Lk - 1;
                const bf16* kp = Kbase + (size_t)srow * ldkv + quad * 8;
                n0 = *(const s8v*)kp;
                n1 = *(const s8v*)(kp + 32);
            }
            f4v acc = {0.f, 0.f, 0.f, 0.f};
            acc = __builtin_amdgcn_mfma_f32_16x16x32_bf16(a0, b0, acc, 0, 0, 0);
            acc = __builtin_amdgcn_mfma_f32_16x16x32_bf16(a1, b1, acc, 0, 0, 0);
            const int colg = c * 16 + l15;
            #pragma unroll
            for (int r = 0; r < 4; ++r) {
                const int qrow = quad * 4 + r;
                float s = acc[r] * 0.125f;
                if (colg >= Lk) s = -1e9f;
                if (MODE == 1 && colg > q0 + qrow) s = -1e9f;
                S[qrow * 516 + colg] = s;
            }
            b0 = n0; b1 = n1; c = cn;
        }
    }
    __syncthreads();

    // ---- phase 2+3: rows {wave, wave+8} processed fused ----
    const int rowA = wave, rowB = wave + 8;
    float aA = 0.f, aB = 0.f;
    float invA, invB;
    if (MODE == 0) {
        // packed keys: 23-bit quantized score | 9-bit col; 0 for padded cols
        unsigned keyA[8], keyB[8];
        #pragma unroll
        for (int j = 0; j < 8; ++j) {
            const int col = lane + 64 * j;
            const bool ok = col < kpad;
            keyA[j] = ok ? ((f2ord(S[rowA * 516 + col]) & 0xFFFFFE00u) | (unsigned)col) : 0u;
            keyB[j] = ok ? ((f2ord(S[rowB * 516 + col]) & 0xFFFFFE00u) | (unsigned)col) : 0u;
        }
        // row maxes (exp offsets): two interleaved butterflies
        unsigned kmA = keyA[0], kmB = keyB[0];
        #pragma unroll
        for (int j = 1; j < 8; ++j) {
            kmA = kmA > keyA[j] ? kmA : keyA[j];
            kmB = kmB > keyB[j] ? kmB : keyB[j];
        }
        #pragma unroll
        for (int off = 1; off < 64; off <<= 1) {
            const unsigned oA = __shfl_xor(kmA, off);
            const unsigned oB = __shfl_xor(kmB, off);
            kmA = kmA > oA ? kmA : oA;
            kmB = kmB > oB ? kmB : oB;
        }
        const float mrA = S[rowA * 516 + (int)(kmA & 511u)];
        const float mrB = S[rowB * 516 + (int)(kmB & 511u)];

        // interleaved full-32-bit binary searches (independent chains hide each
        // other's VALU->SALU->branch latency). Largest T with count(key >= T) >= 16;
        // keys distinct -> exact 16.
        unsigned TA = 0u, TB = 0u;
        bool dA = false, dB = false;
        for (int bbit = 31; bbit >= 0; --bbit) {
            if (!dA) {
                const unsigned T2 = TA | (1u << bbit);
                int c = 0;
                #pragma unroll
                for (int j = 0; j < 8; ++j)
                    c += (int)__popcll(__ballot(keyA[j] >= T2));
                if (c >= 16) { TA = T2; dA = (c == 16); }
            }
            if (!dB) {
                const unsigned T2 = TB | (1u << bbit);
                int c = 0;
                #pragma unroll
                for (int j = 0; j < 8; ++j)
                    c += (int)__popcll(__ballot(keyB[j] >= T2));
                if (c >= 16) { TB = T2; dB = (c == 16); }
            }
            if (dA && dB) break;
        }

        // compaction: exactly the 16 keys >= T per row -> (col, e) in LDS
        int cntA = 0, cntB = 0;
        #pragma unroll
        for (int j = 0; j < 8; ++j) {
            const bool sA = keyA[j] >= TA;
            const unsigned long long balA = __ballot(sA);
            if (sA) {
                const int p = cntA + popc_lt(balA);
                const int col = (int)(keyA[j] & 511u);
                PC[rowA][p] = col;
                PE[rowA][p] = expf(S[rowA * 516 + col] - mrA);
            }
            cntA += (int)__popcll(balA);
            const bool sB = keyB[j] >= TB;
            const unsigned long long balB = __ballot(sB);
            if (sB) {
                const int p = cntB + popc_lt(balB);
                const int col = (int)(keyB[j] & 511u);
                PC[rowB][p] = col;
                PE[rowB][p] = expf(S[rowB * 516 + col] - mrB);
            }
            cntB += (int)__popcll(balB);
        }
        // wave-private rows: same-wave DS ops in order; no barrier needed

        float denA = 0.f, denB = 0.f;
        #pragma unroll
        for (int it = 0; it < 16; ++it) {
            const int cA = PC[rowA][it];
            const float eA = PE[rowA][it];
            denA += eA;
            aA += eA * b2f(Vbase[(size_t)cA * ldkv + lane]);
            const int cB = PC[rowB][it];
            const float eB = PE[rowB][it];
            denB += eB;
            aB += eB * b2f(Vbase[(size_t)cB * ldkv + lane]);
        }
        invA = 1.f / denA;
        invB = 1.f / denB;
    } else {
        float lvA = -INFINITY, lvB = -INFINITY;
        #pragma unroll
        for (int j = 0; j < 8; ++j) {
            const int col = lane + 64 * j;
            if (col < kpad) {
                lvA = fmaxf(lvA, S[rowA * 516 + col]);
                lvB = fmaxf(lvB, S[rowB * 516 + col]);
            }
        }
        #pragma unroll
        for (int off = 1; off < 64; off <<= 1) {
            lvA = fmaxf(lvA, __shfl_xor(lvA, off));
            lvB = fmaxf(lvB, __shfl_xor(lvB, off));
        }
        float pA = 0.f, pB = 0.f;
        #pragma unroll
        for (int j = 0; j < 8; ++j) {
            const int col = lane + 64 * j;
            if (col < kpad) {
                const float wA = expf(S[rowA * 516 + col] - lvA);
                const float wB = expf(S[rowB * 516 + col] - lvB);
                S[rowA * 516 + col] = wA;
                S[rowB * 516 + col] = wB;
                pA += wA; pB += wB;
            }
        }
        #pragma unroll
        for (int off = 1; off < 64; off <<= 1) {
            pA += __shfl_xor(pA, off);
            pB += __shfl_xor(pB, off);
        }
        invA = 1.f / pA;
        invB = 1.f / pB;
        // fused PV: one V row feeds both rows' FMAs. Causal-masked cols have
        // w = exp(-1e9 - lv) = +0 exactly -> running to kmax is bit-identical.
        #pragma unroll 8
        for (int k2 = 0; k2 < kmax; ++k2) {
            const float vv = b2f(Vbase[(size_t)k2 * ldkv + lane]);
            aA += S[rowA * 516 + k2] * vv;
            aB += S[rowB * 516 + k2] * vv;
        }
    }
    if (rowA < qv)
        Qbase[(size_t)rowA * ldq + lane] = __float2bfloat16(aA * invA);
    if (rowB < qv)
        Qbase[(size_t)rowB * ldq + lane] = __float2bfloat16(aB * invB);
}

// ---------------- layernorm over D=512, optional residual; in-place safe ----------------
__global__ __launch_bounds__(256) void ln_off_k(
    const bf16* __restrict__ X, const bf16* __restrict__ R,
    const void* __restrict__ gb, unsigned goff,
    bf16* __restrict__ Out, const int* __restrict__ flagp)
{
    __shared__ float red[4];
    const int f = *flagp;
    const int t = threadIdx.x;
    const size_t base = (size_t)blockIdx.x * DM;
    float v0 = b2f(X[base + t]), v1 = b2f(X[base + t + 256]);
    if (R) { v0 += b2f(R[base + t]); v1 += b2f(R[base + t + 256]); }
    const float mean = block_sum256(v0 + v1, red) * (1.f / 512.f);
    const float d0 = v0 - mean, d1 = v1 - mean;
    const float var = block_sum256(d0 * d0 + d1 * d1, red) * (1.f / 512.f);
    const float rstd = rsqrtf(var + 1e-5f);
    Out[base + t]       = __float2bfloat16(d0 * rstd * ldw(gb, goff + t, f)       + ldw(gb, goff + 512 + t, f));
    Out[base + t + 256] = __float2bfloat16(d1 * rstd * ldw(gb, goff + t + 256, f) + ldw(gb, goff + 768 + t, f));
}

// ---------------- conv distill helpers ----------------
// conv weights w[2][o][c][j] -> transposed GEMM layout wt[layer][o][j*512+c]
__global__ __launch_bounds__(256) void convw_k(const void* __restrict__ w,
                                               bf16* __restrict__ wt, int total,
                                               const int* __restrict__ flagp) {
    const int f = *flagp;
    int i = blockIdx.x * 256 + threadIdx.x;
    if (i >= total) return;
    const int layer = i / 786432, rem2 = i % 786432;
    const int o = rem2 / 1536, rem = rem2 % 1536;
    const int j = rem >> 9, c = rem & 511;
    wt[i] = __float2bfloat16(ldw(w, (unsigned)layer * 786432u + (unsigned)(o * 512 + c) * 3 + j, f));
}

__global__ __launch_bounds__(256) void convidx_k(int* __restrict__ idx, int Lc, int L, int total) {
    int i = blockIdx.x * 256 + threadIdx.x;
    if (i >= total) return;
    const int j = i / (16 * Lc), mrem = i % (16 * Lc);
    const int b = mrem / Lc, l = mrem % Lc;
    int src = l + j - 2;
    src %= L; if (src < 0) src += L;
    idx[i] = b * L + src;
}

// 64 blocks (PART arena = 64 * 4KB), 4-deep unrolled row loop for memory parallelism
__global__ __launch_bounds__(256) void bnstat1_k(const bf16* __restrict__ Y, float* __restrict__ part, int M) {
    const int t = threadIdx.x;
    const int g = gridDim.x;
    float s0 = 0.f, q0 = 0.f, s1 = 0.f, q1 = 0.f;
    int r = blockIdx.x;
    for (; r + 3 * g < M; r += 4 * g) {
        const ushort2 u0 = *reinterpret_cast<const ushort2*>(Y + (size_t)r * DM + t * 2);
        const ushort2 u1 = *reinterpret_cast<const ushort2*>(Y + (size_t)(r + g) * DM + t * 2);
        const ushort2 u2 = *reinterpret_cast<const ushort2*>(Y + (size_t)(r + 2 * g) * DM + t * 2);
        const ushort2 u3 = *reinterpret_cast<const ushort2*>(Y + (size_t)(r + 3 * g) * DM + t * 2);
        float a, c;
        a = u2f(u0.x); c = u2f(u0.y); s0 += a; q0 += a * a; s1 += c; q1 += c * c;
        a = u2f(u1.x); c = u2f(u1.y); s0 += a; q0 += a * a; s1 += c; q1 += c * c;
        a = u2f(u2.x); c = u2f(u2.y); s0 += a; q0 += a * a; s1 += c; q1 += c * c;
        a = u2f(u3.x); c = u2f(u3.y); s0 += a; q0 += a * a; s1 += c; q1 += c * c;
    }
    for (; r < M; r += g) {
        const ushort2 u = *reinterpret_cast<const ushort2*>(Y + (size_t)r * DM + t * 2);
        const float a = u2f(u.x), c = u2f(u.y);
        s0 += a; q0 += a * a;
        s1 += c; q1 += c * c;
    }
    float* p = part + (size_t)blockIdx.x * 1024;
    p[2 * t] = s0; p[2 * t + 1] = s1;
    p[512 + 2 * t] = q0; p[512 + 2 * t + 1] = q1;
}

__global__ __launch_bounds__(256) void bnstat2_k(const float* __restrict__ part, float* __restrict__ stats,
                                                 int nchunk, int M) {
    const int ch = blockIdx.x * 256 + threadIdx.x;
    if (ch >= 512) return;
    float S = 0.f, Qs = 0.f;
    for (int c = 0; c < nchunk; ++c) { S += part[c * 1024 + ch]; Qs += part[c * 1024 + 512 + ch]; }
    const float mean = S / (float)M;
    const float var = Qs / (float)M - mean * mean;
    stats[ch] = mean;
    stats[512 + ch] = fmaxf(var, 0.f);
}

__global__ __launch_bounds__(256) void bnpool_k(
    const bf16* __restrict__ Yc, const float* __restrict__ stats,
    const void* __restrict__ g, const void* __restrict__ bb, unsigned off,
    bf16* __restrict__ Out, int Lc, int Lout, int total, const int* __restrict__ flagp)
{
    const int f = *flagp;
    int i = blockIdx.x * 256 + threadIdx.x;
    if (i >= total) return;
    const int ch = i & 511;
    const int lp = (i >> 9) % Lout;
    const int b = i / (512 * Lout);
    const float mean = stats[ch], var = stats[512 + ch];
    const float sc = ldw(g, off + ch, f) * rsqrtf(var + 1e-5f);
    const float sh = ldw(bb, off + ch, f) - mean * sc;
    float mx = -INFINITY;
    const int l0 = 2 * lp - 1;
    #pragma unroll
    for (int d = 0; d < 3; ++d) {
        const int l = l0 + d;
        if (l >= 0 && l < Lc) {
            float v = b2f(Yc[((size_t)b * Lc + l) * DM + ch]) * sc + sh;
            v = v > 0.f ? v : expm1f(v);  // ELU
            mx = fmaxf(mx, v);
        }
    }
    Out[((size_t)b * Lout + lp) * DM + ch] = __float2bfloat16(mx);
}

// ---------------- final projection to CO=7, dtype-matched store ----------------
__global__ __launch_bounds__(256) void fc_k(
    const bf16* __restrict__ Yn, const void* __restrict__ fcw, const void* __restrict__ fcb,
    void* __restrict__ out, int total, const int* __restrict__ flagp)
{
    const int f = *flagp;
    int i = blockIdx.x * 256 + threadIdx.x;
    if (i >= total) return;
    const int r = i / 7, co = i % 7;
    const bf16* yr = Yn + (size_t)r * DM;
    float acc = ldw(fcb, co, f);
    for (int d = 0; d < DM; ++d) acc += b2f(yr[d]) * ldw(fcw, d * 7 + co, f);
    if (f) ((bf16*)out)[i] = __float2bfloat16(acc);
    else   ((float*)out)[i] = acc;
}

// =============================================================================
extern "C" void kernel_launch(void* const* d_in, const int* in_sizes, int n_in,
                              void* d_out, int out_size, void* d_ws, size_t ws_size,
                              hipStream_t stream)
{
    const void* x_enc      = d_in[0];
    const void* x_mark_enc = d_in[1];
    const void* x_dec      = d_in[2];
    const void* x_mark_dec = d_in[3];
    const void* enc_vw = d_in[4];
    const void* enc_vb = d_in[5];
    const void* enc_mw = d_in[6];
    const void* enc_mb = d_in[7];
    const void* dec_vw = d_in[8];
    const void* dec_vb = d_in[9];
    const void* dec_mw = d_in[10];
    const void* dec_mb = d_in[11];
    const void* eW    = d_in[12];
    const void* ebi   = d_in[13];
    const void* effw1 = d_in[14];
    const void* effb1 = d_in[15];
    const void* effw2 = d_in[16];
    const void* effb2 = d_in[17];
    const void* eln1  = d_in[18];
    const void* eln2  = d_in[19];
    const void* cw    = d_in[20];
    const void* cb    = d_in[21];
    const void* cbn_g = d_in[22];
    const void* cbn_b = d_in[23];
    const void* enc_norm = d_in[24];
    const void* dsW   = d_in[25];
    const void* dsb   = d_in[26];
    const void* dcW   = d_in[27];
    const void* dcb   = d_in[28];
    const void* dffw1 = d_in[29];
    const void* dffb1 = d_in[30];
    const void* dffw2 = d_in[31];
    const void* dffb2 = d_in[32];
    const void* dln   = d_in[33];
    const void* dec_norm = d_in[34];
    const void* fcw   = d_in[35];
    const void* fcb   = d_in[36];

    // ---- workspace layout (~90 MiB; 111 MiB footprint ran clean in round 1) ----
    // X    [0, 8M)      : encoder acts; MEM + Yd in decoder phase
    // QKV  [8M, 40M)    : fused QKV / FFN hidden (aliased) / conv out / cross CQ+CKV
    // OUT  [40M, 48M)   : O-proj / FFN2 dest
    // WT   [48M, ~86.8M): ALL transposed weights (one-time prologue)
    // misc [88M, ~90M)  : IDX0/IDX1, PART (64*4KB), STATS, FLAG
    char* wsp = (char*)d_ws;
    bf16* X    = (bf16*)wsp;
    bf16* QKV  = (bf16*)(wsp + ((size_t)8 << 20));
    bf16* HID  = QKV;                                 // FFN hidden aliases dead QKV
    bf16* OUT  = (bf16*)(wsp + ((size_t)40 << 20));
    bf16* WT   = (bf16*)(wsp + ((size_t)48 << 20));
    int*   IDX0 = (int*)(wsp + ((size_t)88 << 20));   // 3*16*514 = 24672 ints
    int*   IDX1 = IDX0 + 24672;                       // 3*16*259 = 12432 ints
    float* PART = (float*)(wsp + ((size_t)89 << 20));
    float* STATS= (float*)(wsp + ((size_t)89 << 20) + (1 << 18));
    int*   FLAG = (int*)(wsp + ((size_t)89 << 20) + (1 << 18) + 4096);
    bf16* MEMb = X;                                               // [2080][512]
    bf16* Yd   = (bf16*)(wsp + (size_t)16 * 130 * 512 * 2);       // [4096][512]

    // transposed weight sub-arenas (element offsets)
    bf16* WTE  = WT;                    // enc QKVO: (i*4+q)*262144
    bf16* EW1T = WT + 3145728;          // + i*1048576
    bf16* EW2T = WT + 6291456;          // + i*1048576
    bf16* CWT  = WT + 9437184;          // + i*786432
    bf16* DSWt = WT + 11010048;         // + (i*4+q)*262144
    bf16* DCWt = WT + 13107200;
    bf16* DW1T = WT + 15204352;
    bf16* DW2T = WT + 17301504;

    auto cdiv = [](int a, int b) { return (a + b - 1) / b; };
    auto gemm = [&](const bf16* A, const bf16* Wt, const void* bias, unsigned boff,
                    bf16* C, int M, int N, int K, int lda, int ldc, bool relu) {
        dim3 g(N / 128, cdiv(M, 128));
        if (relu) mgemm_k<false, true><<<g, 256, 0, stream>>>(
            (const short*)A, nullptr, (const short*)Wt, bias, boff, C, M, N, K, lda, ldc, FLAG);
        else      mgemm_k<false, false><<<g, 256, 0, stream>>>(
            (const short*)A, nullptr, (const short*)Wt, bias, boff, C, M, N, K, lda, ldc, FLAG);
    };
    auto gemm64 = [&](const bf16* A, const bf16* Wt, const void* bias, unsigned boff,
                      bf16* C, int M, int N, int K, int lda, int ldc, bool relu) {
        dim3 g(N / 64, cdiv(M, 64));
        if (relu) mgemm64_k<false, true><<<g, 256, 0, stream>>>(
            (const short*)A, nullptr, (const short*)Wt, bias, boff, C, M, N, K, lda, ldc, FLAG);
        else      mgemm64_k<false, false><<<g, 256, 0, stream>>>(
            (const short*)A, nullptr, (const short*)Wt, bias, boff, C, M, N, K, lda, ldc, FLAG);
    };
    auto transp = [&](const void* W, unsigned zstride, int nz, bf16* out, int K, int N) {
        transp_k<<<dim3(N / 32, K / 32, nz), 256, 0, stream>>>(W, 0u, zstride, out, K, N, FLAG);
    };

    // ---- prologue: sniff, all weight transposes, conv indices, embeddings ----
    sniff_k<<<1, 256, 0, stream>>>((const unsigned*)x_mark_enc, 16384, FLAG);
    transp(eW,    262144u, 12, WTE,  512, 512);
    transp(effw1, 1048576u, 3, EW1T, 512, 2048);
    transp(effw2, 1048576u, 3, EW2T, 2048, 512);
    convw_k<<<cdiv(1572864, 256), 256, 0, stream>>>(cw, CWT, 1572864, FLAG);
    transp(dsW,   262144u, 8, DSWt, 512, 512);
    transp(dcW,   262144u, 8, DCWt, 512, 512);
    transp(dffw1, 1048576u, 2, DW1T, 512, 2048);
    transp(dffw2, 1048576u, 2, DW2T, 2048, 512);
    convidx_k<<<cdiv(24672, 256), 256, 0, stream>>>(IDX0, 514, 512, 24672);
    convidx_k<<<cdiv(12432, 256), 256, 0, stream>>>(IDX1, 259, 257, 12432);
    embed_k<<<cdiv(16 * 512 * 512, 256), 256, 0, stream>>>(
        x_enc, enc_vw, enc_vb, x_mark_enc, enc_mw, enc_mb, X, 16 * 512, 7, 4, FLAG);

    // ---- encoder ----
    int L = 512;
    for (int i = 0; i < 3; ++i) {
        const int rows = 16 * L;
        const unsigned b0 = (unsigned)i * 4u * 512u;
        // QKV: big grid only at L=512 -> mgemm; else 64x64 for concurrency
        if (i == 0) gemm(X, WTE + (size_t)i * 4 * 262144, ebi, b0, QKV, rows, 1536, 512, 512, 1536, false);
        else      gemm64(X, WTE + (size_t)i * 4 * 262144, ebi, b0, QKV, rows, 1536, 512, 512, 1536, false);
        fattn_k<0><<<dim3(cdiv(L, 16), 8, 16), 512, 0, stream>>>(
            QKV, QKV + 512, QKV + 1024, 1536, 1536, L, L);
        gemm64(QKV, WTE + (size_t)(i * 4 + 3) * 262144, ebi, b0 + 1536u, OUT, rows, 512, 512, 1536, 512, false);
        ln_off_k<<<rows, 256, 0, stream>>>(X, OUT, eln1, (unsigned)i * 1024u, X, FLAG);

        if (i == 0) gemm(X, EW1T + (size_t)i * 1048576, effb1, (unsigned)i * 2048u, HID, rows, 2048, 512, 512, 2048, true);
        else      gemm64(X, EW1T + (size_t)i * 1048576, effb1, (unsigned)i * 2048u, HID, rows, 2048, 512, 512, 2048, true);
        gemm64(HID, EW2T + (size_t)i * 1048576, effb2, (unsigned)i * 512u, OUT, rows, 512, 2048, 2048, 512, false);
        ln_off_k<<<rows, 256, 0, stream>>>(X, OUT, eln2, (unsigned)i * 1024u, X, FLAG);

        if (i < 2) {
            const int Lc = L + 2, Mc = 16 * Lc;
            const int* IDXi = (i == 0) ? IDX0 : IDX1;
            mgemm64_k<true, false><<<dim3(8, cdiv(Mc, 64)), 256, 0, stream>>>(
                (const short*)X, IDXi, (const short*)(CWT + (size_t)i * 786432),
                cb, (unsigned)i * 512u, QKV, Mc, 512, 1536, 512, 512, FLAG);
            bnstat1_k<<<64, 256, 0, stream>>>(QKV, PART, Mc);
            bnstat2_k<<<2, 256, 0, stream>>>(PART, STATS, 64, Mc);
            const int Lout = (L + 1) / 2 + 1;   // 514->257, 259->130
            const int tot = 16 * Lout * 512;
            bnpool_k<<<cdiv(tot, 256), 256, 0, stream>>>(
                QKV, STATS, cbn_g, cbn_b, (unsigned)i * 512u, X, Lc, Lout, tot, FLAG);
            L = Lout;
        }
    }
    const int Lm = L;  // 130
    ln_off_k<<<16 * Lm, 256, 0, stream>>>(X, nullptr, enc_norm, 0u, MEMb, FLAG);

    // ---- decoder embedding ----
    const int rowsD = 16 * 256;
    embed_k<<<cdiv(rowsD * 512, 256), 256, 0, stream>>>(
        x_dec, dec_vw, dec_vb, x_mark_dec, dec_mw, dec_mb, Yd, rowsD, 7, 4, FLAG);

    // ---- decoder (all GEMMs via 64x64 for concurrency) ----
    bf16* CQ  = QKV;                       // [4096][512]
    bf16* CKV = QKV + (size_t)4096 * 512;  // [2080][1024]
    for (int i = 0; i < 2; ++i) {
        const unsigned b0 = (unsigned)i * 4u * 512u;
        // self-attention
        gemm64(Yd, DSWt + (size_t)i * 4 * 262144, dsb, b0, QKV, rowsD, 1536, 512, 512, 1536, false);
        fattn_k<1><<<dim3(16, 8, 16), 512, 0, stream>>>(
            QKV, QKV + 512, QKV + 1024, 1536, 1536, 256, 256);
        gemm64(QKV, DSWt + (size_t)(i * 4 + 3) * 262144, dsb, b0 + 1536u, OUT, rowsD, 512, 512, 1536, 512, false);
        ln_off_k<<<rowsD, 256, 0, stream>>>(Yd, OUT, dln, (unsigned)(i * 3 + 0) * 1024u, Yd, FLAG);

        // cross-attention
        gemm64(Yd, DCWt + (size_t)i * 4 * 262144, dcb, b0, CQ, rowsD, 512, 512, 512, 512, false);
        gemm64(MEMb, DCWt + (size_t)(i * 4 + 1) * 262144, dcb, b0 + 512u, CKV, 16 * Lm, 1024, 512, 512, 1024, false);
        fattn_k<2><<<dim3(16, 8, 16), 512, 0, stream>>>(
            CQ, CKV, CKV + 512, 512, 1024, 256, Lm);
        gemm64(CQ, DCWt + (size_t)(i * 4 + 3) * 262144, dcb, b0 + 1536u, OUT, rowsD, 512, 512, 512, 512, false);
        ln_off_k<<<rowsD, 256, 0, stream>>>(Yd, OUT, dln, (unsigned)(i * 3 + 1) * 1024u, Yd, FLAG);

        // FFN
        gemm64(Yd, DW1T + (size_t)i * 1048576, dffb1, (unsigned)i * 2048u, HID, rowsD, 2048, 512, 512, 2048, true);
        gemm64(HID, DW2T + (size_t)i * 1048576, dffb2, (unsigned)i * 512u, OUT, rowsD, 512, 2048, 2048, 512, false);
        ln_off_k<<<rowsD, 256, 0, stream>>>(Yd, OUT, dln, (unsigned)(i * 3 + 2) * 1024u, Yd, FLAG);
    }

    ln_off_k<<<rowsD, 256, 0, stream>>>(Yd, nullptr, dec_norm, 0u, OUT, FLAG);
    fc_k<<<cdiv(rowsD * 7, 256), 256, 0, stream>>>(OUT, fcw, fcb, d_out, rowsD * 7, FLAG);
}

// Round 9
// 1315.461 us; speedup vs baseline: 1.1031x; 1.0393x over previous
//
#include <hip/hip_runtime.h>
#include <hip/hip_bf16.h>

// Informer forward, MI355X. Round 17: mgemm64 BK=64 + T2 XOR-swizzle.
//  - Round-16: 1367us; XCD swizzle cut fattn FETCH 68.5->17.3MB (T1 confirmed).
//    GEMM chain ~870us for 174GF (200TF, 8% peak) is the pot. mgemm64 at BK=32:
//    2x2 MFMA (~80cy) per barrier, 16 barriers/K=512, grids 4-6 blk/CU -> load
//    latency not covered (round-15 showed deeper buffering alone is neutral;
//    the lever is WORK PER BARRIER).
//  - Fix: BK 32->64: 8 MFMA + 8 ds_read_b128 per iter, 8 barriers per K=512,
//    2x compute under the 1-iter-ahead prefetch. 128B LDS rows would be a 32-bank
//    wrap (G4) -> T2 swizzle via rule #21: linear LDS dest + inverse-swizzled
//    GLOBAL source (lk = ((lane&7)^(lrow&7))*8) + swizzled read
//    (chunk' = (kk*4+quad)^(row&7)). Same data, same k-order (kk=0,1 ascending)
//    -> bit-identical. LDS 32KB -> 5 blk/CU cap (grids supply <= 6 anyway).
//  - mgemm_k (2 big-grid launches) and fattn untouched for clean A/B.
// Round 16: passed, absmax 0.0088, 1367.2 us.
// B=16, LE=512, LD=256, D=512, H=8, dk=64, DFF=2048, NE=3, ND=2, TOPK=16.
// Encoder lengths: 512 -> conv(514)/pool -> 257 -> conv(259)/pool -> 130.

#define DM 512
#define DK 64

using bf16 = __hip_bfloat16;
typedef short s8v __attribute__((ext_vector_type(8)));
typedef float f4v __attribute__((ext_vector_type(4)));

__device__ inline float b2f(bf16 x) { return __bfloat162float(x); }
__device__ inline float u2f(unsigned short u) { return __uint_as_float((unsigned)u << 16); }

// flag f: 1 = raw inputs are bf16, 0 = raw inputs are fp32. idx in ELEMENTS.
__device__ inline float ldw(const void* p, unsigned i, int f) {
    return f ? b2f(((const bf16*)p)[i]) : ((const float*)p)[i];
}

// order-preserving float->u32 (monotonic)
__device__ inline unsigned f2ord(float s) {
    unsigned u = __float_as_uint(s);
    return u ^ ((unsigned)((int)u >> 31) | 0x80000000u);
}

// popcount of mask bits strictly below this lane
__device__ inline int popc_lt(unsigned long long m) {
    return (int)__builtin_amdgcn_mbcnt_hi((unsigned)(m >> 32),
            __builtin_amdgcn_mbcnt_lo((unsigned)m, 0u));
}

// async global->LDS, 16 B per lane; lds dst must be wave-uniform (lane i lands at dst+16*i)
__device__ inline void gl_lds16(const short* g, short* l) {
    __builtin_amdgcn_global_load_lds(
        (const __attribute__((address_space(1))) unsigned int*)g,
        (__attribute__((address_space(3))) unsigned int*)l,
        16, 0, 0);
}

// ---------------- dtype sniffer ----------------
__global__ __launch_bounds__(256) void sniff_k(const unsigned* __restrict__ x, int nwords,
                                               int* __restrict__ flag) {
    __shared__ int red[4];
    const int t = threadIdx.x;
    int c = 0;
    for (int i = t; i < nwords; i += 256) c += ((x[i] & 0x7F80u) == 0x3F80u) ? 1 : 0;
    #pragma unroll
    for (int o = 32; o > 0; o >>= 1) c += __shfl_down(c, o);
    __syncthreads();
    if ((t & 63) == 0) red[t >> 6] = c;
    __syncthreads();
    if (t == 0) flag[0] = (red[0] + red[1] + red[2] + red[3] > nwords / 20) ? 1 : 0;
}

// ---------------- reductions (blockDim == 256) ----------------
__device__ inline float block_sum256(float v, float* red) {
    #pragma unroll
    for (int o = 32; o > 0; o >>= 1) v += __shfl_down(v, o);
    __syncthreads();
    if ((threadIdx.x & 63) == 0) red[threadIdx.x >> 6] = v;
    __syncthreads();
    return red[0] + red[1] + red[2] + red[3];
}

// ---------------- embedding ----------------
__global__ __launch_bounds__(256) void embed_k(
    const void* __restrict__ xv, const void* __restrict__ vw, const void* __restrict__ vb,
    const void* __restrict__ xm, const void* __restrict__ mw, const void* __restrict__ mb,
    bf16* __restrict__ Out, int rows, int Cv, int Cm, const int* __restrict__ flagp)
{
    const int f = *flagp;
    int i = blockIdx.x * 256 + threadIdx.x;
    if (i >= rows * DM) return;
    const int r = i >> 9, d = i & 511;
    float acc = ldw(vb, d, f) + ldw(mb, d, f);
    for (int c = 0; c < Cv; ++c) acc += ldw(xv, r * Cv + c, f) * ldw(vw, c * DM + d, f);
    for (int c = 0; c < Cm; ++c) acc += ldw(xm, r * Cm + c, f) * ldw(mw, c * DM + d, f);
    Out[i] = __float2bfloat16(acc);
}

// ---------------- weight transpose: raw [K][N] -> bf16 [N][K]; z batches sub-mats ----------------
__global__ __launch_bounds__(256) void transp_k(
    const void* __restrict__ W, unsigned off, unsigned zstride, bf16* __restrict__ out,
    int K, int N, const int* __restrict__ flagp)
{
    __shared__ float tile[32][33];
    const int f = *flagp;
    const unsigned zo = blockIdx.z * zstride;
    const int t = threadIdx.x;
    const int tx = t & 31, ty = t >> 5;               // 32 x 8
    const int n0 = blockIdx.x * 32, k0 = blockIdx.y * 32;
    #pragma unroll
    for (int i = 0; i < 4; ++i)
        tile[ty + 8 * i][tx] = ldw(W, off + zo + (unsigned)(k0 + ty + 8 * i) * N + n0 + tx, f);
    __syncthreads();
    #pragma unroll
    for (int i = 0; i < 4; ++i)
        out[(size_t)zo + (size_t)(n0 + ty + 8 * i) * K + k0 + tx] = __float2bfloat16(tile[tx][ty + 8 * i]);
}

// ---------------- MFMA GEMM 128x128 (256 thr): C = A[M,K]@Wt[N,K]^T + bias ----------------
// Single-buffered BK=32 staging via global_load_lds (16 B/lane).
// Used only for large-grid GEMMs (encoder L1 QKV / FFN1: >= 768 blocks).
template<bool G3, bool RELU>
__global__ __launch_bounds__(256) void mgemm_k(
    const short* __restrict__ A, const int* __restrict__ ridx,
    const short* __restrict__ Wt,
    const void* __restrict__ bias, unsigned boff0,
    bf16* __restrict__ C, int M, int N, int K, int lda, int ldc,
    const int* __restrict__ flagp)
{
    __shared__ short As[128 * 32];
    __shared__ short Ws[128 * 32];
    const int t = threadIdx.x;
    const int bm = blockIdx.y * 128, bn = blockIdx.x * 128;
    const int lane = t & 63, wave = t >> 6;
    const int mbase = (wave >> 1) * 64, nbase = (wave & 1) * 64;
    const int l15 = lane & 15, quad = lane >> 4;
    const int lrow = lane >> 2, lk = (lane & 3) * 8;

    f4v acc[4][4] = {};

    for (int k0 = 0; k0 < K; k0 += 32) {
        __syncthreads();
        #pragma unroll
        for (int j = 0; j < 2; ++j) {
            const int rb = wave * 32 + j * 16;
            const int row = bm + rb + lrow;
            const int rowc = row < M ? row : M - 1;
            const short* g;
            if (G3) {
                const int r = ridx[(k0 >> 9) * M + rowc];
                g = A + (size_t)r * lda + (k0 & 511) + lk;
            } else {
                g = A + (size_t)rowc * lda + k0 + lk;
            }
            gl_lds16(g, &As[rb * 32]);
        }
        #pragma unroll
        for (int j = 0; j < 2; ++j) {
            const int nb = wave * 32 + j * 16;
            gl_lds16(Wt + (size_t)(bn + nb + lrow) * K + k0 + lk, &Ws[nb * 32]);
        }
        __syncthreads();
        s8v af[4], bfv[4];
        #pragma unroll
        for (int i = 0; i < 4; ++i) {
            af[i]  = *(const s8v*)&As[(mbase + i * 16 + l15) * 32 + quad * 8];
            bfv[i] = *(const s8v*)&Ws[(nbase + i * 16 + l15) * 32 + quad * 8];
        }
        #pragma unroll
        for (int mi = 0; mi < 4; ++mi)
            #pragma unroll
            for (int ni = 0; ni < 4; ++ni)
                acc[mi][ni] = __builtin_amdgcn_mfma_f32_16x16x32_bf16(
                    af[mi], bfv[ni], acc[mi][ni], 0, 0, 0);
    }

    const int f = *flagp;
    float bv[4];
    #pragma unroll
    for (int ni = 0; ni < 4; ++ni)
        bv[ni] = ldw(bias, boff0 + (unsigned)(bn + nbase + ni * 16 + l15), f);

    #pragma unroll
    for (int mi = 0; mi < 4; ++mi) {
        #pragma unroll
        for (int r = 0; r < 4; ++r) {
            const int row = bm + mbase + mi * 16 + quad * 4 + r;
            if (row < M) {
                #pragma unroll
                for (int ni = 0; ni < 4; ++ni) {
                    float o = acc[mi][ni][r] + bv[ni];
                    if (RELU) o = fmaxf(o, 0.f);
                    C[(size_t)row * ldc + bn + nbase + ni * 16 + l15] = __float2bfloat16(o);
                }
            }
        }
    }
}

// ---------------- MFMA GEMM 64x64 (256 thr, 4 waves x 32x32), BK=64, dbuf ----------------
// grid (N/64, cdiv(M,64)). 8 MFMA + 8 swizzled ds_read_b128 per iter, ONE barrier/iter,
// 8 iters per K=512 (was 16 barriers). 128B LDS rows need T2 XOR-swizzle (rule #21):
// linear LDS dest, inverse-swizzled GLOBAL source chunk, swizzled read. Bit-identical
// k-order. LDS 32 KB -> 5 blocks/CU cap (grids supply <= 6).
template<bool G3, bool RELU>
__global__ __launch_bounds__(256) void mgemm64_k(
    const short* __restrict__ A, const int* __restrict__ ridx,
    const short* __restrict__ Wt,
    const void* __restrict__ bias, unsigned boff0,
    bf16* __restrict__ C, int M, int N, int K, int lda, int ldc,
    const int* __restrict__ flagp)
{
    __shared__ short As[2][64 * 64];
    __shared__ short Ws[2][64 * 64];
    const int t = threadIdx.x;
    const int bm = blockIdx.y * 64, bn = blockIdx.x * 64;
    const int lane = t & 63, wave = t >> 6;
    const int mbase = (wave >> 1) * 32, nbase = (wave & 1) * 32;
    const int l15 = lane & 15, quad = lane >> 4;
    const int lrow = lane >> 3;                        // 8 rows per gl_lds16 call
    const int lk = ((lane & 7) ^ (lrow & 7)) * 8;      // inverse-swizzled source chunk

    f4v acc[2][2] = {};

    auto stage = [&](int buf, int k0) {
        #pragma unroll
        for (int j = 0; j < 2; ++j) {                  // A: 16 rows per wave
            const int rb = wave * 16 + j * 8;
            const int row = bm + rb + lrow;
            const int rowc = row < M ? row : M - 1;
            const short* g;
            if (G3) {
                const int r = ridx[(k0 >> 9) * M + rowc];
                g = A + (size_t)r * lda + (k0 & 511) + lk;
            } else {
                g = A + (size_t)rowc * lda + k0 + lk;
            }
            gl_lds16(g, &As[buf][rb * 64]);
        }
        #pragma unroll
        for (int j = 0; j < 2; ++j) {                  // B: 16 rows per wave
            const int nb = wave * 16 + j * 8;
            gl_lds16(Wt + (size_t)(bn + nb + lrow) * K + k0 + lk, &Ws[buf][nb * 64]);
        }
    };

    const int nt = K >> 6;
    stage(0, 0);
    __syncthreads();
    for (int it = 0; it < nt; ++it) {
        if (it + 1 < nt) stage((it + 1) & 1, (it + 1) << 6);
        const int cb = it & 1;
        #pragma unroll
        for (int kk = 0; kk < 2; ++kk) {               // k0+32*kk ascending -> bit-identical
            s8v af[2], bfv[2];
            #pragma unroll
            for (int i = 0; i < 2; ++i) {
                const int ra = mbase + i * 16 + l15;
                af[i]  = *(const s8v*)&As[cb][ra * 64 + (((kk * 4 + quad) ^ (ra & 7)) << 3)];
                const int rb2 = nbase + i * 16 + l15;
                bfv[i] = *(const s8v*)&Ws[cb][rb2 * 64 + (((kk * 4 + quad) ^ (rb2 & 7)) << 3)];
            }
            #pragma unroll
            for (int mi = 0; mi < 2; ++mi)
                #pragma unroll
                for (int ni = 0; ni < 2; ++ni)
                    acc[mi][ni] = __builtin_amdgcn_mfma_f32_16x16x32_bf16(
                        af[mi], bfv[ni], acc[mi][ni], 0, 0, 0);
        }
        if (it + 1 < nt) __syncthreads();
    }

    const int f = *flagp;
    float bv[2];
    #pragma unroll
    for (int ni = 0; ni < 2; ++ni)
        bv[ni] = ldw(bias, boff0 + (unsigned)(bn + nbase + ni * 16 + l15), f);

    #pragma unroll
    for (int mi = 0; mi < 2; ++mi) {
        #pragma unroll
        for (int r = 0; r < 4; ++r) {
            const int row = bm + mbase + mi * 16 + quad * 4 + r;
            if (row < M) {
                #pragma unroll
                for (int ni = 0; ni < 2; ++ni) {
                    float o = acc[mi][ni][r] + bv[ni];
                    if (RELU) o = fmaxf(o, 0.f);
                    C[(size_t)row * ldc + bn + nbase + ni * 16 + l15] = __float2bfloat16(o);
                }
            }
        }
    }
}

// ---------------- fused tile attention (strided q/k/v), 512 threads ----------------
// MODE 0: ProbSparse top-16. MODE 1: causal. MODE 2: plain cross.
// XCD-locality swizzle: bijective remap so each XCD L2 serves a contiguous id range.
// 8 waves: phase 1 = MFMA QK^T, direct-global K frags, 2-deep load pipeline;
// phase 2+3 = each wave owns rows {wave, wave+8}, processed FUSED.
template<int MODE>
__global__ __launch_bounds__(512, 8) void fattn_k(
    bf16* __restrict__ q, const bf16* __restrict__ k, const bf16* __restrict__ v,
    int ldq, int ldkv, int Lq, int Lk)
{
    __shared__ short Qs[16 * 72];
    __shared__ float S[16 * 516];
    __shared__ int   PC[16][16];
    __shared__ float PE[16][16];

    const int t = threadIdx.x;
    // ---- XCD swizzle (bijective: nwg = gx*128, always % 8 == 0) ----
    const int gx = gridDim.x;
    const int nwg = gx * 128;                         // y=8, z=16 fixed
    const int lin = blockIdx.x + gx * (blockIdx.y + 8 * blockIdx.z);
    const int id = (lin & 7) * (nwg >> 3) + (lin >> 3);
    const int q0 = (id % gx) * 16;
    const int h  = (id / gx) & 7;
    const int b  = id / (gx * 8);

    const int lane = t & 63, wave = t >> 6;           // 8 waves
    const int l15 = lane & 15, quad = lane >> 4;

    const int qv = (Lq - q0) < 16 ? (Lq - q0) : 16;

    const bf16* Kbase = k + (size_t)b * Lk * ldkv + h * DK;
    const bf16* Vbase = v + (size_t)b * Lk * ldkv + h * DK;
    bf16* Qbase = q + (size_t)(b * Lq + q0) * ldq + h * DK;

    const int kmax = (MODE == 1) ? (q0 + 16 < Lk ? q0 + 16 : Lk) : Lk;
    const int ntile = (kmax + 63) >> 6;
    const int kpad = ntile << 6;
    const int nchunk = kpad >> 4;

    {   // Q stage: all 512 threads (4B each; 16 rows x 128B)
        const int qr = t >> 5;
        const int qsrc = qr < qv ? qr : qv - 1;
        *(ushort2*)&Qs[qr * 72 + (t & 31) * 2] =
            *(const ushort2*)(Qbase + (size_t)qsrc * ldq + (t & 31) * 2);
    }
    __syncthreads();

    // ---- phase 1: S = QK^T / 8 (+ masks); 2-deep K-load pipeline ----
    {
        const s8v a0 = *(const s8v*)&Qs[l15 * 72 + quad * 8];
        const s8v a1 = *(const s8v*)&Qs[l15 * 72 + 32 + quad * 8];
        int c = wave;
        s8v b0, b1;
        if (c < nchunk) {
            int srow = c * 16 + l15; if (srow >= Lk) srow = Lk - 1;
            const bf16* kp = Kbase + (size_t)srow * ldkv + quad * 8;
            b0 = *(const s8v*)kp;
            b1 = *(const s8v*)(kp + 32);
        }
        while (c < nchunk) {
            const int cn = c + 8;
            s8v n0, n1;
            if (cn < nchunk) {
                int srow = cn * 16 + l15; if (srow >= Lk) srow = Lk - 1;
                const bf16* kp = Kbase + (size_t)srow * ldkv + quad * 8;
                n0 = *(const s8v*)kp;
                n1 = *(const s8v*)(kp + 32);
            }
            f4v acc = {0.f, 0.f, 0.f, 0.f};
            acc = __builtin_amdgcn_mfma_f32_16x16x32_bf16(a0, b0, acc, 0, 0, 0);
            acc = __builtin_amdgcn_mfma_f32_16x16x32_bf16(a1, b1, acc, 0, 0, 0);
            const int colg = c * 16 + l15;
            #pragma unroll
            for (int r = 0; r < 4; ++r) {
                const int qrow = quad * 4 + r;
                float s = acc[r] * 0.125f;
                if (colg >= Lk) s = -1e9f;
                if (MODE == 1 && colg > q0 + qrow) s = -1e9f;
                S[qrow * 516 + colg] = s;
            }
            b0 = n0; b1 = n1; c = cn;
        }
    }
    __syncthreads();

    // ---- phase 2+3: rows {wave, wave+8} processed fused ----
    const int rowA = wave, rowB = wave + 8;
    float aA = 0.f, aB = 0.f;
    float invA, invB;
    if (MODE == 0) {
        // packed keys: 23-bit quantized score | 9-bit col; 0 for padded cols
        unsigned keyA[8], keyB[8];
        #pragma unroll
        for (int j = 0; j < 8; ++j) {
            const int col = lane + 64 * j;
            const bool ok = col < kpad;
            keyA[j] = ok ? ((f2ord(S[rowA * 516 + col]) & 0xFFFFFE00u) | (unsigned)col) : 0u;
            keyB[j] = ok ? ((f2ord(S[rowB * 516 + col]) & 0xFFFFFE00u) | (unsigned)col) : 0u;
        }
        // row maxes (exp offsets): two interleaved butterflies
        unsigned kmA = keyA[0], kmB = keyB[0];
        #pragma unroll
        for (int j = 1; j < 8; ++j) {
            kmA = kmA > keyA[j] ? kmA : keyA[j];
            kmB = kmB > keyB[j] ? kmB : keyB[j];
        }
        #pragma unroll
        for (int off = 1; off < 64; off <<= 1) {
            const unsigned oA = __shfl_xor(kmA, off);
            const unsigned oB = __shfl_xor(kmB, off);
            kmA = kmA > oA ? kmA : oA;
            kmB = kmB > oB ? kmB : oB;
        }
        const float mrA = S[rowA * 516 + (int)(kmA & 511u)];
        const float mrB = S[rowB * 516 + (int)(kmB & 511u)];

        // interleaved full-32-bit binary searches (independent chains hide each
        // other's VALU->SALU->branch latency). Largest T with count(key >= T) >= 16;
        // keys distinct -> exact 16.
        unsigned TA = 0u, TB = 0u;
        bool dA = false, dB = false;
        for (int bbit = 31; bbit >= 0; --bbit) {
            if (!dA) {
                const unsigned T2 = TA | (1u << bbit);
                int c = 0;
                #pragma unroll
                for (int j = 0; j < 8; ++j)
                    c += (int)__popcll(__ballot(keyA[j] >= T2));
                if (c >= 16) { TA = T2; dA = (c == 16); }
            }
            if (!dB) {
                const unsigned T2 = TB | (1u << bbit);
                int c = 0;
                #pragma unroll
                for (int j = 0; j < 8; ++j)
                    c += (int)__popcll(__ballot(keyB[j] >= T2));
                if (c >= 16) { TB = T2; dB = (c == 16); }
            }
            if (dA && dB) break;
        }

        // compaction: exactly the 16 keys >= T per row -> (col, e) in LDS
        int cntA = 0, cntB = 0;
        #pragma unroll
        for (int j = 0; j < 8; ++j) {
            const bool sA = keyA[j] >= TA;
            const unsigned long long balA = __ballot(sA);
            if (sA) {
                const int p = cntA + popc_lt(balA);
                const int col = (int)(keyA[j] & 511u);
                PC[rowA][p] = col;
                PE[rowA][p] = expf(S[rowA * 516 + col] - mrA);
            }
            cntA += (int)__popcll(balA);
            const bool sB = keyB[j] >= TB;
            const unsigned long long balB = __ballot(sB);
            if (sB) {
                const int p = cntB + popc_lt(balB);
                const int col = (int)(keyB[j] & 511u);
                PC[rowB][p] = col;
                PE[rowB][p] = expf(S[rowB * 516 + col] - mrB);
            }
            cntB += (int)__popcll(balB);
        }
        // wave-private rows: same-wave DS ops in order; no barrier needed

        float denA = 0.f, denB = 0.f;
        #pragma unroll
        for (int it = 0; it < 16; ++it) {
            const int cA = PC[rowA][it];
            const float eA = PE[rowA][it];
            denA += eA;
            aA += eA * b2f(Vbase[(size_t)cA * ldkv + lane]);
            const int cB = PC[rowB][it];
            const float eB = PE[rowB][it];
            denB += eB;
            aB += eB * b2f(Vbase[(size_t)cB * ldkv + lane]);
        }
        invA = 1.f / denA;
        invB = 1.f / denB;
    } else {
        float lvA = -INFINITY, lvB = -INFINITY;
        #pragma unroll
        for (int j = 0; j < 8; ++j) {
            const int col = lane + 64 * j;
            if (col < kpad) {
                lvA = fmaxf(lvA, S[rowA * 516 + col]);
                lvB = fmaxf(lvB, S[rowB * 516 + col]);
            }
        }
        #pragma unroll
        for (int off = 1; off < 64; off <<= 1) {
            lvA = fmaxf(lvA, __shfl_xor(lvA, off));
            lvB = fmaxf(lvB, __shfl_xor(lvB, off));
        }
        float pA = 0.f, pB = 0.f;
        #pragma unroll
        for (int j = 0; j < 8; ++j) {
            const int col = lane + 64 * j;
            if (col < kpad) {
                const float wA = expf(S[rowA * 516 + col] - lvA);
                const float wB = expf(S[rowB * 516 + col] - lvB);
                S[rowA * 516 + col] = wA;
                S[rowB * 516 + col] = wB;
                pA += wA; pB += wB;
            }
        }
        #pragma unroll
        for (int off = 1; off < 64; off <<= 1) {
            pA += __shfl_xor(pA, off);
            pB += __shfl_xor(pB, off);
        }
        invA = 1.f / pA;
        invB = 1.f / pB;
        // fused PV: one V row feeds both rows' FMAs. Causal-masked cols have
        // w = exp(-1e9 - lv) = +0 exactly -> running to kmax is bit-identical.
        #pragma unroll 8
        for (int k2 = 0; k2 < kmax; ++k2) {
            const float vv = b2f(Vbase[(size_t)k2 * ldkv + lane]);
            aA += S[rowA * 516 + k2] * vv;
            aB += S[rowB * 516 + k2] * vv;
        }
    }
    if (rowA < qv)
        Qbase[(size_t)rowA * ldq + lane] = __float2bfloat16(aA * invA);
    if (rowB < qv)
        Qbase[(size_t)rowB * ldq + lane] = __float2bfloat16(aB * invB);
}

// ---------------- layernorm over D=512, optional residual; in-place safe ----------------
__global__ __launch_bounds__(256) void ln_off_k(
    const bf16* __restrict__ X, const bf16* __restrict__ R,
    const void* __restrict__ gb, unsigned goff,
    bf16* __restrict__ Out, const int* __restrict__ flagp)
{
    __shared__ float red[4];
    const int f = *flagp;
    const int t = threadIdx.x;
    const size_t base = (size_t)blockIdx.x * DM;
    float v0 = b2f(X[base + t]), v1 = b2f(X[base + t + 256]);
    if (R) { v0 += b2f(R[base + t]); v1 += b2f(R[base + t + 256]); }
    const float mean = block_sum256(v0 + v1, red) * (1.f / 512.f);
    const float d0 = v0 - mean, d1 = v1 - mean;
    const float var = block_sum256(d0 * d0 + d1 * d1, red) * (1.f / 512.f);
    const float rstd = rsqrtf(var + 1e-5f);
    Out[base + t]       = __float2bfloat16(d0 * rstd * ldw(gb, goff + t, f)       + ldw(gb, goff + 512 + t, f));
    Out[base + t + 256] = __float2bfloat16(d1 * rstd * ldw(gb, goff + t + 256, f) + ldw(gb, goff + 768 + t, f));
}

// ---------------- conv distill helpers ----------------
// conv weights w[2][o][c][j] -> transposed GEMM layout wt[layer][o][j*512+c]
__global__ __launch_bounds__(256) void convw_k(const void* __restrict__ w,
                                               bf16* __restrict__ wt, int total,
                                               const int* __restrict__ flagp) {
    const int f = *flagp;
    int i = blockIdx.x * 256 + threadIdx.x;
    if (i >= total) return;
    const int layer = i / 786432, rem2 = i % 786432;
    const int o = rem2 / 1536, rem = rem2 % 1536;
    const int j = rem >> 9, c = rem & 511;
    wt[i] = __float2bfloat16(ldw(w, (unsigned)layer * 786432u + (unsigned)(o * 512 + c) * 3 + j, f));
}

__global__ __launch_bounds__(256) void convidx_k(int* __restrict__ idx, int Lc, int L, int total) {
    int i = blockIdx.x * 256 + threadIdx.x;
    if (i >= total) return;
    const int j = i / (16 * Lc), mrem = i % (16 * Lc);
    const int b = mrem / Lc, l = mrem % Lc;
    int src = l + j - 2;
    src %= L; if (src < 0) src += L;
    idx[i] = b * L + src;
}

// 64 blocks (PART arena = 64 * 4KB), 4-deep unrolled row loop for memory parallelism
__global__ __launch_bounds__(256) void bnstat1_k(const bf16* __restrict__ Y, float* __restrict__ part, int M) {
    const int t = threadIdx.x;
    const int g = gridDim.x;
    float s0 = 0.f, q0 = 0.f, s1 = 0.f, q1 = 0.f;
    int r = blockIdx.x;
    for (; r + 3 * g < M; r += 4 * g) {
        const ushort2 u0 = *reinterpret_cast<const ushort2*>(Y + (size_t)r * DM + t * 2);
        const ushort2 u1 = *reinterpret_cast<const ushort2*>(Y + (size_t)(r + g) * DM + t * 2);
        const ushort2 u2 = *reinterpret_cast<const ushort2*>(Y + (size_t)(r + 2 * g) * DM + t * 2);
        const ushort2 u3 = *reinterpret_cast<const ushort2*>(Y + (size_t)(r + 3 * g) * DM + t * 2);
        float a, c;
        a = u2f(u0.x); c = u2f(u0.y); s0 += a; q0 += a * a; s1 += c; q1 += c * c;
        a = u2f(u1.x); c = u2f(u1.y); s0 += a; q0 += a * a; s1 += c; q1 += c * c;
        a = u2f(u2.x); c = u2f(u2.y); s0 += a; q0 += a * a; s1 += c; q1 += c * c;
        a = u2f(u3.x); c = u2f(u3.y); s0 += a; q0 += a * a; s1 += c; q1 += c * c;
    }
    for (; r < M; r += g) {
        const ushort2 u = *reinterpret_cast<const ushort2*>(Y + (size_t)r * DM + t * 2);
        const float a = u2f(u.x), c = u2f(u.y);
        s0 += a; q0 += a * a;
        s1 += c; q1 += c * c;
    }
    float* p = part + (size_t)blockIdx.x * 1024;
    p[2 * t] = s0; p[2 * t + 1] = s1;
    p[512 + 2 * t] = q0; p[512 + 2 * t + 1] = q1;
}

__global__ __launch_bounds__(256) void bnstat2_k(const float* __restrict__ part, float* __restrict__ stats,
                                                 int nchunk, int M) {
    const int ch = blockIdx.x * 256 + threadIdx.x;
    if (ch >= 512) return;
    float S = 0.f, Qs = 0.f;
    for (int c = 0; c < nchunk; ++c) { S += part[c * 1024 + ch]; Qs += part[c * 1024 + 512 + ch]; }
    const float mean = S / (float)M;
    const float var = Qs / (float)M - mean * mean;
    stats[ch] = mean;
    stats[512 + ch] = fmaxf(var, 0.f);
}

__global__ __launch_bounds__(256) void bnpool_k(
    const bf16* __restrict__ Yc, const float* __restrict__ stats,
    const void* __restrict__ g, const void* __restrict__ bb, unsigned off,
    bf16* __restrict__ Out, int Lc, int Lout, int total, const int* __restrict__ flagp)
{
    const int f = *flagp;
    int i = blockIdx.x * 256 + threadIdx.x;
    if (i >= total) return;
    const int ch = i & 511;
    const int lp = (i >> 9) % Lout;
    const int b = i / (512 * Lout);
    const float mean = stats[ch], var = stats[512 + ch];
    const float sc = ldw(g, off + ch, f) * rsqrtf(var + 1e-5f);
    const float sh = ldw(bb, off + ch, f) - mean * sc;
    float mx = -INFINITY;
    const int l0 = 2 * lp - 1;
    #pragma unroll
    for (int d = 0; d < 3; ++d) {
        const int l = l0 + d;
        if (l >= 0 && l < Lc) {
            float v = b2f(Yc[((size_t)b * Lc + l) * DM + ch]) * sc + sh;
            v = v > 0.f ? v : expm1f(v);  // ELU
            mx = fmaxf(mx, v);
        }
    }
    Out[((size_t)b * Lout + lp) * DM + ch] = __float2bfloat16(mx);
}

// ---------------- final projection to CO=7, dtype-matched store ----------------
__global__ __launch_bounds__(256) void fc_k(
    const bf16* __restrict__ Yn, const void* __restrict__ fcw, const void* __restrict__ fcb,
    void* __restrict__ out, int total, const int* __restrict__ flagp)
{
    const int f = *flagp;
    int i = blockIdx.x * 256 + threadIdx.x;
    if (i >= total) return;
    const int r = i / 7, co = i % 7;
    const bf16* yr = Yn + (size_t)r * DM;
    float acc = ldw(fcb, co, f);
    for (int d = 0; d < DM; ++d) acc += b2f(yr[d]) * ldw(fcw, d * 7 + co, f);
    if (f) ((bf16*)out)[i] = __float2bfloat16(acc);
    else   ((float*)out)[i] = acc;
}

// =============================================================================
extern "C" void kernel_launch(void* const* d_in, const int* in_sizes, int n_in,
                              void* d_out, int out_size, void* d_ws, size_t ws_size,
                              hipStream_t stream)
{
    const void* x_enc      = d_in[0];
    const void* x_mark_enc = d_in[1];
    const void* x_dec      = d_in[2];
    const void* x_mark_dec = d_in[3];
    const void* enc_vw = d_in[4];
    const void* enc_vb = d_in[5];
    const void* enc_mw = d_in[6];
    const void* enc_mb = d_in[7];
    const void* dec_vw = d_in[8];
    const void* dec_vb = d_in[9];
    const void* dec_mw = d_in[10];
    const void* dec_mb = d_in[11];
    const void* eW    = d_in[12];
    const void* ebi   = d_in[13];
    const void* effw1 = d_in[14];
    const void* effb1 = d_in[15];
    const void* effw2 = d_in[16];
    const void* effb2 = d_in[17];
    const void* eln1  = d_in[18];
    const void* eln2  = d_in[19];
    const void* cw    = d_in[20];
    const void* cb    = d_in[21];
    const void* cbn_g = d_in[22];
    const void* cbn_b = d_in[23];
    const void* enc_norm = d_in[24];
    const void* dsW   = d_in[25];
    const void* dsb   = d_in[26];
    const void* dcW   = d_in[27];
    const void* dcb   = d_in[28];
    const void* dffw1 = d_in[29];
    const void* dffb1 = d_in[30];
    const void* dffw2 = d_in[31];
    const void* dffb2 = d_in[32];
    const void* dln   = d_in[33];
    const void* dec_norm = d_in[34];
    const void* fcw   = d_in[35];
    const void* fcb   = d_in[36];

    // ---- workspace layout (~90 MiB; 111 MiB footprint ran clean in round 1) ----
    // X    [0, 8M)      : encoder acts; MEM + Yd in decoder phase
    // QKV  [8M, 40M)    : fused QKV / FFN hidden (aliased) / conv out / cross CQ+CKV
    // OUT  [40M, 48M)   : O-proj / FFN2 dest
    // WT   [48M, ~86.8M): ALL transposed weights (one-time prologue)
    // misc [88M, ~90M)  : IDX0/IDX1, PART (64*4KB), STATS, FLAG
    char* wsp = (char*)d_ws;
    bf16* X    = (bf16*)wsp;
    bf16* QKV  = (bf16*)(wsp + ((size_t)8 << 20));
    bf16* HID  = QKV;                                 // FFN hidden aliases dead QKV
    bf16* OUT  = (bf16*)(wsp + ((size_t)40 << 20));
    bf16* WT   = (bf16*)(wsp + ((size_t)48 << 20));
    int*   IDX0 = (int*)(wsp + ((size_t)88 << 20));   // 3*16*514 = 24672 ints
    int*   IDX1 = IDX0 + 24672;                       // 3*16*259 = 12432 ints
    float* PART = (float*)(wsp + ((size_t)89 << 20));
    float* STATS= (float*)(wsp + ((size_t)89 << 20) + (1 << 18));
    int*   FLAG = (int*)(wsp + ((size_t)89 << 20) + (1 << 18) + 4096);
    bf16* MEMb = X;                                               // [2080][512]
    bf16* Yd   = (bf16*)(wsp + (size_t)16 * 130 * 512 * 2);       // [4096][512]

    // transposed weight sub-arenas (element offsets)
    bf16* WTE  = WT;                    // enc QKVO: (i*4+q)*262144
    bf16* EW1T = WT + 3145728;          // + i*1048576
    bf16* EW2T = WT + 6291456;          // + i*1048576
    bf16* CWT  = WT + 9437184;          // + i*786432
    bf16* DSWt = WT + 11010048;         // + (i*4+q)*262144
    bf16* DCWt = WT + 13107200;
    bf16* DW1T = WT + 15204352;
    bf16* DW2T = WT + 17301504;

    auto cdiv = [](int a, int b) { return (a + b - 1) / b; };
    auto gemm = [&](const bf16* A, const bf16* Wt, const void* bias, unsigned boff,
                    bf16* C, int M, int N, int K, int lda, int ldc, bool relu) {
        dim3 g(N / 128, cdiv(M, 128));
        if (relu) mgemm_k<false, true><<<g, 256, 0, stream>>>(
            (const short*)A, nullptr, (const short*)Wt, bias, boff, C, M, N, K, lda, ldc, FLAG);
        else      mgemm_k<false, false><<<g, 256, 0, stream>>>(
            (const short*)A, nullptr, (const short*)Wt, bias, boff, C, M, N, K, lda, ldc, FLAG);
    };
    auto gemm64 = [&](const bf16* A, const bf16* Wt, const void* bias, unsigned boff,
                      bf16* C, int M, int N, int K, int lda, int ldc, bool relu) {
        dim3 g(N / 64, cdiv(M, 64));
        if (relu) mgemm64_k<false, true><<<g, 256, 0, stream>>>(
            (const short*)A, nullptr, (const short*)Wt, bias, boff, C, M, N, K, lda, ldc, FLAG);
        else      mgemm64_k<false, false><<<g, 256, 0, stream>>>(
            (const short*)A, nullptr, (const short*)Wt, bias, boff, C, M, N, K, lda, ldc, FLAG);
    };
    auto transp = [&](const void* W, unsigned zstride, int nz, bf16* out, int K, int N) {
        transp_k<<<dim3(N / 32, K / 32, nz), 256, 0, stream>>>(W, 0u, zstride, out, K, N, FLAG);
    };

    // ---- prologue: sniff, all weight transposes, conv indices, embeddings ----
    sniff_k<<<1, 256, 0, stream>>>((const unsigned*)x_mark_enc, 16384, FLAG);
    transp(eW,    262144u, 12, WTE,  512, 512);
    transp(effw1, 1048576u, 3, EW1T, 512, 2048);
    transp(effw2, 1048576u, 3, EW2T, 2048, 512);
    convw_k<<<cdiv(1572864, 256), 256, 0, stream>>>(cw, CWT, 1572864, FLAG);
    transp(dsW,   262144u, 8, DSWt, 512, 512);
    transp(dcW,   262144u, 8, DCWt, 512, 512);
    transp(dffw1, 1048576u, 2, DW1T, 512, 2048);
    transp(dffw2, 1048576u, 2, DW2T, 2048, 512);
    convidx_k<<<cdiv(24672, 256), 256, 0, stream>>>(IDX0, 514, 512, 24672);
    convidx_k<<<cdiv(12432, 256), 256, 0, stream>>>(IDX1, 259, 257, 12432);
    embed_k<<<cdiv(16 * 512 * 512, 256), 256, 0, stream>>>(
        x_enc, enc_vw, enc_vb, x_mark_enc, enc_mw, enc_mb, X, 16 * 512, 7, 4, FLAG);

    // ---- encoder ----
    int L = 512;
    for (int i = 0; i < 3; ++i) {
        const int rows = 16 * L;
        const unsigned b0 = (unsigned)i * 4u * 512u;
        // QKV: big grid only at L=512 -> mgemm; else 64x64 for concurrency
        if (i == 0) gemm(X, WTE + (size_t)i * 4 * 262144, ebi, b0, QKV, rows, 1536, 512, 512, 1536, false);
        else      gemm64(X, WTE + (size_t)i * 4 * 262144, ebi, b0, QKV, rows, 1536, 512, 512, 1536, false);
        fattn_k<0><<<dim3(cdiv(L, 16), 8, 16), 512, 0, stream>>>(
            QKV, QKV + 512, QKV + 1024, 1536, 1536, L, L);
        gemm64(QKV, WTE + (size_t)(i * 4 + 3) * 262144, ebi, b0 + 1536u, OUT, rows, 512, 512, 1536, 512, false);
        ln_off_k<<<rows, 256, 0, stream>>>(X, OUT, eln1, (unsigned)i * 1024u, X, FLAG);

        if (i == 0) gemm(X, EW1T + (size_t)i * 1048576, effb1, (unsigned)i * 2048u, HID, rows, 2048, 512, 512, 2048, true);
        else      gemm64(X, EW1T + (size_t)i * 1048576, effb1, (unsigned)i * 2048u, HID, rows, 2048, 512, 512, 2048, true);
        gemm64(HID, EW2T + (size_t)i * 1048576, effb2, (unsigned)i * 512u, OUT, rows, 512, 2048, 2048, 512, false);
        ln_off_k<<<rows, 256, 0, stream>>>(X, OUT, eln2, (unsigned)i * 1024u, X, FLAG);

        if (i < 2) {
            const int Lc = L + 2, Mc = 16 * Lc;
            const int* IDXi = (i == 0) ? IDX0 : IDX1;
            mgemm64_k<true, false><<<dim3(8, cdiv(Mc, 64)), 256, 0, stream>>>(
                (const short*)X, IDXi, (const short*)(CWT + (size_t)i * 786432),
                cb, (unsigned)i * 512u, QKV, Mc, 512, 1536, 512, 512, FLAG);
            bnstat1_k<<<64, 256, 0, stream>>>(QKV, PART, Mc);
            bnstat2_k<<<2, 256, 0, stream>>>(PART, STATS, 64, Mc);
            const int Lout = (L + 1) / 2 + 1;   // 514->257, 259->130
            const int tot = 16 * Lout * 512;
            bnpool_k<<<cdiv(tot, 256), 256, 0, stream>>>(
                QKV, STATS, cbn_g, cbn_b, (unsigned)i * 512u, X, Lc, Lout, tot, FLAG);
            L = Lout;
        }
    }
    const int Lm = L;  // 130
    ln_off_k<<<16 * Lm, 256, 0, stream>>>(X, nullptr, enc_norm, 0u, MEMb, FLAG);

    // ---- decoder embedding ----
    const int rowsD = 16 * 256;
    embed_k<<<cdiv(rowsD * 512, 256), 256, 0, stream>>>(
        x_dec, dec_vw, dec_vb, x_mark_dec, dec_mw, dec_mb, Yd, rowsD, 7, 4, FLAG);

    // ---- decoder (all GEMMs via 64x64 for concurrency) ----
    bf16* CQ  = QKV;                       // [4096][512]
    bf16* CKV = QKV + (size_t)4096 * 512;  // [2080][1024]
    for (int i = 0; i < 2; ++i) {
        const unsigned b0 = (unsigned)i * 4u * 512u;
        // self-attention
        gemm64(Yd, DSWt + (size_t)i * 4 * 262144, dsb, b0, QKV, rowsD, 1536, 512, 512, 1536, false);
        fattn_k<1><<<dim3(16, 8, 16), 512, 0, stream>>>(
            QKV, QKV + 512, QKV + 1024, 1536, 1536, 256, 256);
        gemm64(QKV, DSWt + (size_t)(i * 4 + 3) * 262144, dsb, b0 + 1536u, OUT, rowsD, 512, 512, 1536, 512, false);
        ln_off_k<<<rowsD, 256, 0, stream>>>(Yd, OUT, dln, (unsigned)(i * 3 + 0) * 1024u, Yd, FLAG);

        // cross-attention
        gemm64(Yd, DCWt + (size_t)i * 4 * 262144, dcb, b0, CQ, rowsD, 512, 512, 512, 512, false);
        gemm64(MEMb, DCWt + (size_t)(i * 4 + 1) * 262144, dcb, b0 + 512u, CKV, 16 * Lm, 1024, 512, 512, 1024, false);
        fattn_k<2><<<dim3(16, 8, 16), 512, 0, stream>>>(
            CQ, CKV, CKV + 512, 512, 1024, 256, Lm);
        gemm64(CQ, DCWt + (size_t)(i * 4 + 3) * 262144, dcb, b0 + 1536u, OUT, rowsD, 512, 512, 512, 512, false);
        ln_off_k<<<rowsD, 256, 0, stream>>>(Yd, OUT, dln, (unsigned)(i * 3 + 1) * 1024u, Yd, FLAG);

        // FFN
        gemm64(Yd, DW1T + (size_t)i * 1048576, dffb1, (unsigned)i * 2048u, HID, rowsD, 2048, 512, 512, 2048, true);
        gemm64(HID, DW2T + (size_t)i * 1048576, dffb2, (unsigned)i * 512u, OUT, rowsD, 512, 2048, 2048, 512, false);
        ln_off_k<<<rowsD, 256, 0, stream>>>(Yd, OUT, dln, (unsigned)(i * 3 + 2) * 1024u, Yd, FLAG);
    }

    ln_off_k<<<rowsD, 256, 0, stream>>>(Yd, nullptr, dec_norm, 0u, OUT, FLAG);
    fc_k<<<cdiv(rowsD * 7, 256), 256, 0, stream>>>(OUT, fcw, fcb, d_out, rowsD * 7, FLAG);
}

// Round 10
// 1235.982 us; speedup vs baseline: 1.1740x; 1.0643x over previous
//
#include <hip/hip_runtime.h>
#include <hip/hip_bf16.h>

// Informer forward, MI355X. Round 18: GEMM A-panel XCD locality + mgemm_k BK=64.
//  - Round-17: 1315us (mgemm64 BK64+T2 -52us). fattn<0> 92.5us unchanged (VALU-bound,
//    not traffic-bound -- round-16 lesson: its FETCH fell 4x with no dur change).
//  - Lever 1 (T1, m204 bijective): mgemm64 grids are bn-major -> the 8 consecutive
//    ids sharing one A-panel round-robin onto 8 XCDs => A fetched up to 8x (FFN2-L1:
//    A=33.5MB -> ~270MB > MFMA time; O-proj/conv/cross similar). Chunked swizzle
//    (xcd = lin&7 owns a contiguous id range) puts all bn-tiles of an A-panel on one
//    XCD -> A fetched once, L2-resident. Pure permutation -> bit-identical.
//  - Lever 2: mgemm_k ported to the PROVEN round-17 pattern: BK=64 single-buffer
//    (32KB LDS, 5 blk/CU cap >= the 3-4 supplied), T2 swizzle per rule #21, 8
//    barriers x 32 MFMA (was 16 x 16), + same chunked XCD swizzle.
//  - fattn untouched for clean A/B.
// Round 17: passed, absmax 0.0088, 1315.5 us.
// B=16, LE=512, LD=256, D=512, H=8, dk=64, DFF=2048, NE=3, ND=2, TOPK=16.
// Encoder lengths: 512 -> conv(514)/pool -> 257 -> conv(259)/pool -> 130.

#define DM 512
#define DK 64

using bf16 = __hip_bfloat16;
typedef short s8v __attribute__((ext_vector_type(8)));
typedef float f4v __attribute__((ext_vector_type(4)));

__device__ inline float b2f(bf16 x) { return __bfloat162float(x); }
__device__ inline float u2f(unsigned short u) { return __uint_as_float((unsigned)u << 16); }

// flag f: 1 = raw inputs are bf16, 0 = raw inputs are fp32. idx in ELEMENTS.
__device__ inline float ldw(const void* p, unsigned i, int f) {
    return f ? b2f(((const bf16*)p)[i]) : ((const float*)p)[i];
}

// order-preserving float->u32 (monotonic)
__device__ inline unsigned f2ord(float s) {
    unsigned u = __float_as_uint(s);
    return u ^ ((unsigned)((int)u >> 31) | 0x80000000u);
}

// popcount of mask bits strictly below this lane
__device__ inline int popc_lt(unsigned long long m) {
    return (int)__builtin_amdgcn_mbcnt_hi((unsigned)(m >> 32),
            __builtin_amdgcn_mbcnt_lo((unsigned)m, 0u));
}

// bijective chunked XCD swizzle (m204): linear id -> id such that each XCD
// (assumed lin%8 dispatch) owns a CONTIGUOUS id range. Perf-only heuristic.
__device__ inline int xcd_chunk_id(int lin, int nwg) {
    const int xcd = lin & 7;
    const int pos = lin >> 3;
    const int q = nwg >> 3, r = nwg & 7;
    return (xcd < r ? xcd * (q + 1) : r * (q + 1) + (xcd - r) * q) + pos;
}

// async global->LDS, 16 B per lane; lds dst must be wave-uniform (lane i lands at dst+16*i)
__device__ inline void gl_lds16(const short* g, short* l) {
    __builtin_amdgcn_global_load_lds(
        (const __attribute__((address_space(1))) unsigned int*)g,
        (__attribute__((address_space(3))) unsigned int*)l,
        16, 0, 0);
}

// ---------------- dtype sniffer ----------------
__global__ __launch_bounds__(256) void sniff_k(const unsigned* __restrict__ x, int nwords,
                                               int* __restrict__ flag) {
    __shared__ int red[4];
    const int t = threadIdx.x;
    int c = 0;
    for (int i = t; i < nwords; i += 256) c += ((x[i] & 0x7F80u) == 0x3F80u) ? 1 : 0;
    #pragma unroll
    for (int o = 32; o > 0; o >>= 1) c += __shfl_down(c, o);
    __syncthreads();
    if ((t & 63) == 0) red[t >> 6] = c;
    __syncthreads();
    if (t == 0) flag[0] = (red[0] + red[1] + red[2] + red[3] > nwords / 20) ? 1 : 0;
}

// ---------------- reductions (blockDim == 256) ----------------
__device__ inline float block_sum256(float v, float* red) {
    #pragma unroll
    for (int o = 32; o > 0; o >>= 1) v += __shfl_down(v, o);
    __syncthreads();
    if ((threadIdx.x & 63) == 0) red[threadIdx.x >> 6] = v;
    __syncthreads();
    return red[0] + red[1] + red[2] + red[3];
}

// ---------------- embedding ----------------
__global__ __launch_bounds__(256) void embed_k(
    const void* __restrict__ xv, const void* __restrict__ vw, const void* __restrict__ vb,
    const void* __restrict__ xm, const void* __restrict__ mw, const void* __restrict__ mb,
    bf16* __restrict__ Out, int rows, int Cv, int Cm, const int* __restrict__ flagp)
{
    const int f = *flagp;
    int i = blockIdx.x * 256 + threadIdx.x;
    if (i >= rows * DM) return;
    const int r = i >> 9, d = i & 511;
    float acc = ldw(vb, d, f) + ldw(mb, d, f);
    for (int c = 0; c < Cv; ++c) acc += ldw(xv, r * Cv + c, f) * ldw(vw, c * DM + d, f);
    for (int c = 0; c < Cm; ++c) acc += ldw(xm, r * Cm + c, f) * ldw(mw, c * DM + d, f);
    Out[i] = __float2bfloat16(acc);
}

// ---------------- weight transpose: raw [K][N] -> bf16 [N][K]; z batches sub-mats ----------------
__global__ __launch_bounds__(256) void transp_k(
    const void* __restrict__ W, unsigned off, unsigned zstride, bf16* __restrict__ out,
    int K, int N, const int* __restrict__ flagp)
{
    __shared__ float tile[32][33];
    const int f = *flagp;
    const unsigned zo = blockIdx.z * zstride;
    const int t = threadIdx.x;
    const int tx = t & 31, ty = t >> 5;               // 32 x 8
    const int n0 = blockIdx.x * 32, k0 = blockIdx.y * 32;
    #pragma unroll
    for (int i = 0; i < 4; ++i)
        tile[ty + 8 * i][tx] = ldw(W, off + zo + (unsigned)(k0 + ty + 8 * i) * N + n0 + tx, f);
    __syncthreads();
    #pragma unroll
    for (int i = 0; i < 4; ++i)
        out[(size_t)zo + (size_t)(n0 + ty + 8 * i) * K + k0 + tx] = __float2bfloat16(tile[tx][ty + 8 * i]);
}

// ---------------- MFMA GEMM 128x128 (256 thr), BK=64 single-buffer, T2 swizzle ----------------
// 8 K-iters (32 MFMA each) for K=512 (was 16 x 16). Chunked XCD swizzle for A-panel
// L2 locality. Rule #21 layout: linear LDS dest + inverse-swizzled global source +
// swizzled read; kk ascending -> bit-identical accumulation order.
// Used only for large-grid GEMMs (encoder L1 QKV / FFN1: >= 768 blocks).
template<bool G3, bool RELU>
__global__ __launch_bounds__(256) void mgemm_k(
    const short* __restrict__ A, const int* __restrict__ ridx,
    const short* __restrict__ Wt,
    const void* __restrict__ bias, unsigned boff0,
    bf16* __restrict__ C, int M, int N, int K, int lda, int ldc,
    const int* __restrict__ flagp)
{
    __shared__ short As[128 * 64];
    __shared__ short Ws[128 * 64];
    const int t = threadIdx.x;
    const int gx = gridDim.x;
    const int id = xcd_chunk_id(blockIdx.x + gx * blockIdx.y, gx * gridDim.y);
    const int bn = (id % gx) * 128, bm = (id / gx) * 128;
    const int lane = t & 63, wave = t >> 6;
    const int mbase = (wave >> 1) * 64, nbase = (wave & 1) * 64;
    const int l15 = lane & 15, quad = lane >> 4;
    const int lrow = lane >> 3;                        // 8 rows per gl_lds16 call
    const int lk = ((lane & 7) ^ (lrow & 7)) * 8;      // inverse-swizzled source chunk

    f4v acc[4][4] = {};

    for (int k0 = 0; k0 < K; k0 += 64) {
        __syncthreads();
        #pragma unroll
        for (int j = 0; j < 4; ++j) {                  // A: 32 rows per wave
            const int rb = wave * 32 + j * 8;
            const int row = bm + rb + lrow;
            const int rowc = row < M ? row : M - 1;
            const short* g;
            if (G3) {
                const int r = ridx[(k0 >> 9) * M + rowc];
                g = A + (size_t)r * lda + (k0 & 511) + lk;
            } else {
                g = A + (size_t)rowc * lda + k0 + lk;
            }
            gl_lds16(g, &As[rb * 64]);
        }
        #pragma unroll
        for (int j = 0; j < 4; ++j) {                  // B: 32 rows per wave
            const int nb = wave * 32 + j * 8;
            gl_lds16(Wt + (size_t)(bn + nb + lrow) * K + k0 + lk, &Ws[nb * 64]);
        }
        __syncthreads();
        #pragma unroll
        for (int kk = 0; kk < 2; ++kk) {               // k0+32*kk ascending -> bit-identical
            s8v af[4], bfv[4];
            #pragma unroll
            for (int i = 0; i < 4; ++i) {
                const int ra = mbase + i * 16 + l15;
                af[i]  = *(const s8v*)&As[ra * 64 + (((kk * 4 + quad) ^ (ra & 7)) << 3)];
                const int rb2 = nbase + i * 16 + l15;
                bfv[i] = *(const s8v*)&Ws[rb2 * 64 + (((kk * 4 + quad) ^ (rb2 & 7)) << 3)];
            }
            #pragma unroll
            for (int mi = 0; mi < 4; ++mi)
                #pragma unroll
                for (int ni = 0; ni < 4; ++ni)
                    acc[mi][ni] = __builtin_amdgcn_mfma_f32_16x16x32_bf16(
                        af[mi], bfv[ni], acc[mi][ni], 0, 0, 0);
        }
    }

    const int f = *flagp;
    float bv[4];
    #pragma unroll
    for (int ni = 0; ni < 4; ++ni)
        bv[ni] = ldw(bias, boff0 + (unsigned)(bn + nbase + ni * 16 + l15), f);

    #pragma unroll
    for (int mi = 0; mi < 4; ++mi) {
        #pragma unroll
        for (int r = 0; r < 4; ++r) {
            const int row = bm + mbase + mi * 16 + quad * 4 + r;
            if (row < M) {
                #pragma unroll
                for (int ni = 0; ni < 4; ++ni) {
                    float o = acc[mi][ni][r] + bv[ni];
                    if (RELU) o = fmaxf(o, 0.f);
                    C[(size_t)row * ldc + bn + nbase + ni * 16 + l15] = __float2bfloat16(o);
                }
            }
        }
    }
}

// ---------------- MFMA GEMM 64x64 (256 thr, 4 waves x 32x32), BK=64, dbuf ----------------
// grid (N/64, cdiv(M,64)). Chunked XCD swizzle: the gx consecutive ids sharing one
// A-panel stay on ONE XCD -> A fetched once per XCD (was up to 8x: FFN2-L1 A=33.5MB
// -> ~270MB refetch, the dominant GEMM cost). 8 MFMA + 8 swizzled ds_read_b128 per
// iter, one barrier/iter. Bit-identical (pure tile permutation).
template<bool G3, bool RELU>
__global__ __launch_bounds__(256) void mgemm64_k(
    const short* __restrict__ A, const int* __restrict__ ridx,
    const short* __restrict__ Wt,
    const void* __restrict__ bias, unsigned boff0,
    bf16* __restrict__ C, int M, int N, int K, int lda, int ldc,
    const int* __restrict__ flagp)
{
    __shared__ short As[2][64 * 64];
    __shared__ short Ws[2][64 * 64];
    const int t = threadIdx.x;
    const int gx = gridDim.x;
    const int id = xcd_chunk_id(blockIdx.x + gx * blockIdx.y, gx * gridDim.y);
    const int bn = (id % gx) * 64, bm = (id / gx) * 64;
    const int lane = t & 63, wave = t >> 6;
    const int mbase = (wave >> 1) * 32, nbase = (wave & 1) * 32;
    const int l15 = lane & 15, quad = lane >> 4;
    const int lrow = lane >> 3;                        // 8 rows per gl_lds16 call
    const int lk = ((lane & 7) ^ (lrow & 7)) * 8;      // inverse-swizzled source chunk

    f4v acc[2][2] = {};

    auto stage = [&](int buf, int k0) {
        #pragma unroll
        for (int j = 0; j < 2; ++j) {                  // A: 16 rows per wave
            const int rb = wave * 16 + j * 8;
            const int row = bm + rb + lrow;
            const int rowc = row < M ? row : M - 1;
            const short* g;
            if (G3) {
                const int r = ridx[(k0 >> 9) * M + rowc];
                g = A + (size_t)r * lda + (k0 & 511) + lk;
            } else {
                g = A + (size_t)rowc * lda + k0 + lk;
            }
            gl_lds16(g, &As[buf][rb * 64]);
        }
        #pragma unroll
        for (int j = 0; j < 2; ++j) {                  // B: 16 rows per wave
            const int nb = wave * 16 + j * 8;
            gl_lds16(Wt + (size_t)(bn + nb + lrow) * K + k0 + lk, &Ws[buf][nb * 64]);
        }
    };

    const int nt = K >> 6;
    stage(0, 0);
    __syncthreads();
    for (int it = 0; it < nt; ++it) {
        if (it + 1 < nt) stage((it + 1) & 1, (it + 1) << 6);
        const int cb = it & 1;
        #pragma unroll
        for (int kk = 0; kk < 2; ++kk) {               // k0+32*kk ascending -> bit-identical
            s8v af[2], bfv[2];
            #pragma unroll
            for (int i = 0; i < 2; ++i) {
                const int ra = mbase + i * 16 + l15;
                af[i]  = *(const s8v*)&As[cb][ra * 64 + (((kk * 4 + quad) ^ (ra & 7)) << 3)];
                const int rb2 = nbase + i * 16 + l15;
                bfv[i] = *(const s8v*)&Ws[cb][rb2 * 64 + (((kk * 4 + quad) ^ (rb2 & 7)) << 3)];
            }
            #pragma unroll
            for (int mi = 0; mi < 2; ++mi)
                #pragma unroll
                for (int ni = 0; ni < 2; ++ni)
                    acc[mi][ni] = __builtin_amdgcn_mfma_f32_16x16x32_bf16(
                        af[mi], bfv[ni], acc[mi][ni], 0, 0, 0);
        }
        if (it + 1 < nt) __syncthreads();
    }

    const int f = *flagp;
    float bv[2];
    #pragma unroll
    for (int ni = 0; ni < 2; ++ni)
        bv[ni] = ldw(bias, boff0 + (unsigned)(bn + nbase + ni * 16 + l15), f);

    #pragma unroll
    for (int mi = 0; mi < 2; ++mi) {
        #pragma unroll
        for (int r = 0; r < 4; ++r) {
            const int row = bm + mbase + mi * 16 + quad * 4 + r;
            if (row < M) {
                #pragma unroll
                for (int ni = 0; ni < 2; ++ni) {
                    float o = acc[mi][ni][r] + bv[ni];
                    if (RELU) o = fmaxf(o, 0.f);
                    C[(size_t)row * ldc + bn + nbase + ni * 16 + l15] = __float2bfloat16(o);
                }
            }
        }
    }
}

// ---------------- fused tile attention (strided q/k/v), 512 threads ----------------
// MODE 0: ProbSparse top-16. MODE 1: causal. MODE 2: plain cross.
// XCD-locality swizzle: bijective remap so each XCD L2 serves a contiguous id range.
// 8 waves: phase 1 = MFMA QK^T, direct-global K frags, 2-deep load pipeline;
// phase 2+3 = each wave owns rows {wave, wave+8}, processed FUSED.
template<int MODE>
__global__ __launch_bounds__(512, 8) void fattn_k(
    bf16* __restrict__ q, const bf16* __restrict__ k, const bf16* __restrict__ v,
    int ldq, int ldkv, int Lq, int Lk)
{
    __shared__ short Qs[16 * 72];
    __shared__ float S[16 * 516];
    __shared__ int   PC[16][16];
    __shared__ float PE[16][16];

    const int t = threadIdx.x;
    // ---- XCD swizzle (bijective: nwg = gx*128, always % 8 == 0) ----
    const int gx = gridDim.x;
    const int nwg = gx * 128;                         // y=8, z=16 fixed
    const int lin = blockIdx.x + gx * (blockIdx.y + 8 * blockIdx.z);
    const int id = (lin & 7) * (nwg >> 3) + (lin >> 3);
    const int q0 = (id % gx) * 16;
    const int h  = (id / gx) & 7;
    const int b  = id / (gx * 8);

    const int lane = t & 63, wave = t >> 6;           // 8 waves
    const int l15 = lane & 15, quad = lane >> 4;

    const int qv = (Lq - q0) < 16 ? (Lq - q0) : 16;

    const bf16* Kbase = k + (size_t)b * Lk * ldkv + h * DK;
    const bf16* Vbase = v + (size_t)b * Lk * ldkv + h * DK;
    bf16* Qbase = q + (size_t)(b * Lq + q0) * ldq + h * DK;

    const int kmax = (MODE == 1) ? (q0 + 16 < Lk ? q0 + 16 : Lk) : Lk;
    const int ntile = (kmax + 63) >> 6;
    const int kpad = ntile << 6;
    const int nchunk = kpad >> 4;

    {   // Q stage: all 512 threads (4B each; 16 rows x 128B)
        const int qr = t >> 5;
        const int qsrc = qr < qv ? qr : qv - 1;
        *(ushort2*)&Qs[qr * 72 + (t & 31) * 2] =
            *(const ushort2*)(Qbase + (size_t)qsrc * ldq + (t & 31) * 2);
    }
    __syncthreads();

    // ---- phase 1: S = QK^T / 8 (+ masks); 2-deep K-load pipeline ----
    {
        const s8v a0 = *(const s8v*)&Qs[l15 * 72 + quad * 8];
        const s8v a1 = *(const s8v*)&Qs[l15 * 72 + 32 + quad * 8];
        int c = wave;
        s8v b0, b1;
        if (c < nchunk) {
            int srow = c * 16 + l15; if (srow >= Lk) srow = Lk - 1;
            const bf16* kp = Kbase + (size_t)srow * ldkv + quad * 8;
            b0 = *(const s8v*)kp;
            b1 = *(const s8v*)(kp + 32);
        }
        while (c < nchunk) {
            const int cn = c + 8;
            s8v n0, n1;
            if (cn < nchunk) {
                int srow = cn * 16 + l15; if (srow >= Lk) srow = Lk - 1;
                const bf16* kp = Kbase + (size_t)srow * ldkv + quad * 8;
                n0 = *(const s8v*)kp;
                n1 = *(const s8v*)(kp + 32);
            }
            f4v acc = {0.f, 0.f, 0.f, 0.f};
            acc = __builtin_amdgcn_mfma_f32_16x16x32_bf16(a0, b0, acc, 0, 0, 0);
            acc = __builtin_amdgcn_mfma_f32_16x16x32_bf16(a1, b1, acc, 0, 0, 0);
            const int colg = c * 16 + l15;
            #pragma unroll
            for (int r = 0; r < 4; ++r) {
                const int qrow = quad * 4 + r;
                float s = acc[r] * 0.125f;
                if (colg >= Lk) s = -1e9f;
                if (MODE == 1 && colg > q0 + qrow) s = -1e9f;
                S[qrow * 516 + colg] = s;
            }
            b0 = n0; b1 = n1; c = cn;
        }
    }
    __syncthreads();

    // ---- phase 2+3: rows {wave, wave+8} processed fused ----
    const int rowA = wave, rowB = wave + 8;
    float aA = 0.f, aB = 0.f;
    float invA, invB;
    if (MODE == 0) {
        // packed keys: 23-bit quantized score | 9-bit col; 0 for padded cols
        unsigned keyA[8], keyB[8];
        #pragma unroll
        for (int j = 0; j < 8; ++j) {
            const int col = lane + 64 * j;
            const bool ok = col < kpad;
            keyA[j] = ok ? ((f2ord(S[rowA * 516 + col]) & 0xFFFFFE00u) | (unsigned)col) : 0u;
            keyB[j] = ok ? ((f2ord(S[rowB * 516 + col]) & 0xFFFFFE00u) | (unsigned)col) : 0u;
        }
        // row maxes (exp offsets): two interleaved butterflies
        unsigned kmA = keyA[0], kmB = keyB[0];
        #pragma unroll
        for (int j = 1; j < 8; ++j) {
            kmA = kmA > keyA[j] ? kmA : keyA[j];
            kmB = kmB > keyB[j] ? kmB : keyB[j];
        }
        #pragma unroll
        for (int off = 1; off < 64; off <<= 1) {
            const unsigned oA = __shfl_xor(kmA, off);
            const unsigned oB = __shfl_xor(kmB, off);
            kmA = kmA > oA ? kmA : oA;
            kmB = kmB > oB ? kmB : oB;
        }
        const float mrA = S[rowA * 516 + (int)(kmA & 511u)];
        const float mrB = S[rowB * 516 + (int)(kmB & 511u)];

        // interleaved full-32-bit binary searches (independent chains hide each
        // other's VALU->SALU->branch latency). Largest T with count(key >= T) >= 16;
        // keys distinct -> exact 16.
        unsigned TA = 0u, TB = 0u;
        bool dA = false, dB = false;
        for (int bbit = 31; bbit >= 0; --bbit) {
            if (!dA) {
                const unsigned T2 = TA | (1u << bbit);
                int c = 0;
                #pragma unroll
                for (int j = 0; j < 8; ++j)
                    c += (int)__popcll(__ballot(keyA[j] >= T2));
                if (c >= 16) { TA = T2; dA = (c == 16); }
            }
            if (!dB) {
                const unsigned T2 = TB | (1u << bbit);
                int c = 0;
                #pragma unroll
                for (int j = 0; j < 8; ++j)
                    c += (int)__popcll(__ballot(keyB[j] >= T2));
                if (c >= 16) { TB = T2; dB = (c == 16); }
            }
            if (dA && dB) break;
        }

        // compaction: exactly the 16 keys >= T per row -> (col, e) in LDS
        int cntA = 0, cntB = 0;
        #pragma unroll
        for (int j = 0; j < 8; ++j) {
            const bool sA = keyA[j] >= TA;
            const unsigned long long balA = __ballot(sA);
            if (sA) {
                const int p = cntA + popc_lt(balA);
                const int col = (int)(keyA[j] & 511u);
                PC[rowA][p] = col;
                PE[rowA][p] = expf(S[rowA * 516 + col] - mrA);
            }
            cntA += (int)__popcll(balA);
            const bool sB = keyB[j] >= TB;
            const unsigned long long balB = __ballot(sB);
            if (sB) {
                const int p = cntB + popc_lt(balB);
                const int col = (int)(keyB[j] & 511u);
                PC[rowB][p] = col;
                PE[rowB][p] = expf(S[rowB * 516 + col] - mrB);
            }
            cntB += (int)__popcll(balB);
        }
        // wave-private rows: same-wave DS ops in order; no barrier needed

        float denA = 0.f, denB = 0.f;
        #pragma unroll
        for (int it = 0; it < 16; ++it) {
            const int cA = PC[rowA][it];
            const float eA = PE[rowA][it];
            denA += eA;
            aA += eA * b2f(Vbase[(size_t)cA * ldkv + lane]);
            const int cB = PC[rowB][it];
            const float eB = PE[rowB][it];
            denB += eB;
            aB += eB * b2f(Vbase[(size_t)cB * ldkv + lane]);
        }
        invA = 1.f / denA;
        invB = 1.f / denB;
    } else {
        float lvA = -INFINITY, lvB = -INFINITY;
        #pragma unroll
        for (int j = 0; j < 8; ++j) {
            const int col = lane + 64 * j;
            if (col < kpad) {
                lvA = fmaxf(lvA, S[rowA * 516 + col]);
                lvB = fmaxf(lvB, S[rowB * 516 + col]);
            }
        }
        #pragma unroll
        for (int off = 1; off < 64; off <<= 1) {
            lvA = fmaxf(lvA, __shfl_xor(lvA, off));
            lvB = fmaxf(lvB, __shfl_xor(lvB, off));
        }
        float pA = 0.f, pB = 0.f;
        #pragma unroll
        for (int j = 0; j < 8; ++j) {
            const int col = lane + 64 * j;
            if (col < kpad) {
                const float wA = expf(S[rowA * 516 + col] - lvA);
                const float wB = expf(S[rowB * 516 + col] - lvB);
                S[rowA * 516 + col] = wA;
                S[rowB * 516 + col] = wB;
                pA += wA; pB += wB;
            }
        }
        #pragma unroll
        for (int off = 1; off < 64; off <<= 1) {
            pA += __shfl_xor(pA, off);
            pB += __shfl_xor(pB, off);
        }
        invA = 1.f / pA;
        invB = 1.f / pB;
        // fused PV: one V row feeds both rows' FMAs. Causal-masked cols have
        // w = exp(-1e9 - lv) = +0 exactly -> running to kmax is bit-identical.
        #pragma unroll 8
        for (int k2 = 0; k2 < kmax; ++k2) {
            const float vv = b2f(Vbase[(size_t)k2 * ldkv + lane]);
            aA += S[rowA * 516 + k2] * vv;
            aB += S[rowB * 516 + k2] * vv;
        }
    }
    if (rowA < qv)
        Qbase[(size_t)rowA * ldq + lane] = __float2bfloat16(aA * invA);
    if (rowB < qv)
        Qbase[(size_t)rowB * ldq + lane] = __float2bfloat16(aB * invB);
}

// ---------------- layernorm over D=512, optional residual; in-place safe ----------------
__global__ __launch_bounds__(256) void ln_off_k(
    const bf16* __restrict__ X, const bf16* __restrict__ R,
    const void* __restrict__ gb, unsigned goff,
    bf16* __restrict__ Out, const int* __restrict__ flagp)
{
    __shared__ float red[4];
    const int f = *flagp;
    const int t = threadIdx.x;
    const size_t base = (size_t)blockIdx.x * DM;
    float v0 = b2f(X[base + t]), v1 = b2f(X[base + t + 256]);
    if (R) { v0 += b2f(R[base + t]); v1 += b2f(R[base + t + 256]); }
    const float mean = block_sum256(v0 + v1, red) * (1.f / 512.f);
    const float d0 = v0 - mean, d1 = v1 - mean;
    const float var = block_sum256(d0 * d0 + d1 * d1, red) * (1.f / 512.f);
    const float rstd = rsqrtf(var + 1e-5f);
    Out[base + t]       = __float2bfloat16(d0 * rstd * ldw(gb, goff + t, f)       + ldw(gb, goff + 512 + t, f));
    Out[base + t + 256] = __float2bfloat16(d1 * rstd * ldw(gb, goff + t + 256, f) + ldw(gb, goff + 768 + t, f));
}

// ---------------- conv distill helpers ----------------
// conv weights w[2][o][c][j] -> transposed GEMM layout wt[layer][o][j*512+c]
__global__ __launch_bounds__(256) void convw_k(const void* __restrict__ w,
                                               bf16* __restrict__ wt, int total,
                                               const int* __restrict__ flagp) {
    const int f = *flagp;
    int i = blockIdx.x * 256 + threadIdx.x;
    if (i >= total) return;
    const int layer = i / 786432, rem2 = i % 786432;
    const int o = rem2 / 1536, rem = rem2 % 1536;
    const int j = rem >> 9, c = rem & 511;
    wt[i] = __float2bfloat16(ldw(w, (unsigned)layer * 786432u + (unsigned)(o * 512 + c) * 3 + j, f));
}

__global__ __launch_bounds__(256) void convidx_k(int* __restrict__ idx, int Lc, int L, int total) {
    int i = blockIdx.x * 256 + threadIdx.x;
    if (i >= total) return;
    const int j = i / (16 * Lc), mrem = i % (16 * Lc);
    const int b = mrem / Lc, l = mrem % Lc;
    int src = l + j - 2;
    src %= L; if (src < 0) src += L;
    idx[i] = b * L + src;
}

// 64 blocks (PART arena = 64 * 4KB), 4-deep unrolled row loop for memory parallelism
__global__ __launch_bounds__(256) void bnstat1_k(const bf16* __restrict__ Y, float* __restrict__ part, int M) {
    const int t = threadIdx.x;
    const int g = gridDim.x;
    float s0 = 0.f, q0 = 0.f, s1 = 0.f, q1 = 0.f;
    int r = blockIdx.x;
    for (; r + 3 * g < M; r += 4 * g) {
        const ushort2 u0 = *reinterpret_cast<const ushort2*>(Y + (size_t)r * DM + t * 2);
        const ushort2 u1 = *reinterpret_cast<const ushort2*>(Y + (size_t)(r + g) * DM + t * 2);
        const ushort2 u2 = *reinterpret_cast<const ushort2*>(Y + (size_t)(r + 2 * g) * DM + t * 2);
        const ushort2 u3 = *reinterpret_cast<const ushort2*>(Y + (size_t)(r + 3 * g) * DM + t * 2);
        float a, c;
        a = u2f(u0.x); c = u2f(u0.y); s0 += a; q0 += a * a; s1 += c; q1 += c * c;
        a = u2f(u1.x); c = u2f(u1.y); s0 += a; q0 += a * a; s1 += c; q1 += c * c;
        a = u2f(u2.x); c = u2f(u2.y); s0 += a; q0 += a * a; s1 += c; q1 += c * c;
        a = u2f(u3.x); c = u2f(u3.y); s0 += a; q0 += a * a; s1 += c; q1 += c * c;
    }
    for (; r < M; r += g) {
        const ushort2 u = *reinterpret_cast<const ushort2*>(Y + (size_t)r * DM + t * 2);
        const float a = u2f(u.x), c = u2f(u.y);
        s0 += a; q0 += a * a;
        s1 += c; q1 += c * c;
    }
    float* p = part + (size_t)blockIdx.x * 1024;
    p[2 * t] = s0; p[2 * t + 1] = s1;
    p[512 + 2 * t] = q0; p[512 + 2 * t + 1] = q1;
}

__global__ __launch_bounds__(256) void bnstat2_k(const float* __restrict__ part, float* __restrict__ stats,
                                                 int nchunk, int M) {
    const int ch = blockIdx.x * 256 + threadIdx.x;
    if (ch >= 512) return;
    float S = 0.f, Qs = 0.f;
    for (int c = 0; c < nchunk; ++c) { S += part[c * 1024 + ch]; Qs += part[c * 1024 + 512 + ch]; }
    const float mean = S / (float)M;
    const float var = Qs / (float)M - mean * mean;
    stats[ch] = mean;
    stats[512 + ch] = fmaxf(var, 0.f);
}

__global__ __launch_bounds__(256) void bnpool_k(
    const bf16* __restrict__ Yc, const float* __restrict__ stats,
    const void* __restrict__ g, const void* __restrict__ bb, unsigned off,
    bf16* __restrict__ Out, int Lc, int Lout, int total, const int* __restrict__ flagp)
{
    const int f = *flagp;
    int i = blockIdx.x * 256 + threadIdx.x;
    if (i >= total) return;
    const int ch = i & 511;
    const int lp = (i >> 9) % Lout;
    const int b = i / (512 * Lout);
    const float mean = stats[ch], var = stats[512 + ch];
    const float sc = ldw(g, off + ch, f) * rsqrtf(var + 1e-5f);
    const float sh = ldw(bb, off + ch, f) - mean * sc;
    float mx = -INFINITY;
    const int l0 = 2 * lp - 1;
    #pragma unroll
    for (int d = 0; d < 3; ++d) {
        const int l = l0 + d;
        if (l >= 0 && l < Lc) {
            float v = b2f(Yc[((size_t)b * Lc + l) * DM + ch]) * sc + sh;
            v = v > 0.f ? v : expm1f(v);  // ELU
            mx = fmaxf(mx, v);
        }
    }
    Out[((size_t)b * Lout + lp) * DM + ch] = __float2bfloat16(mx);
}

// ---------------- final projection to CO=7, dtype-matched store ----------------
__global__ __launch_bounds__(256) void fc_k(
    const bf16* __restrict__ Yn, const void* __restrict__ fcw, const void* __restrict__ fcb,
    void* __restrict__ out, int total, const int* __restrict__ flagp)
{
    const int f = *flagp;
    int i = blockIdx.x * 256 + threadIdx.x;
    if (i >= total) return;
    const int r = i / 7, co = i % 7;
    const bf16* yr = Yn + (size_t)r * DM;
    float acc = ldw(fcb, co, f);
    for (int d = 0; d < DM; ++d) acc += b2f(yr[d]) * ldw(fcw, d * 7 + co, f);
    if (f) ((bf16*)out)[i] = __float2bfloat16(acc);
    else   ((float*)out)[i] = acc;
}

// =============================================================================
extern "C" void kernel_launch(void* const* d_in, const int* in_sizes, int n_in,
                              void* d_out, int out_size, void* d_ws, size_t ws_size,
                              hipStream_t stream)
{
    const void* x_enc      = d_in[0];
    const void* x_mark_enc = d_in[1];
    const void* x_dec      = d_in[2];
    const void* x_mark_dec = d_in[3];
    const void* enc_vw = d_in[4];
    const void* enc_vb = d_in[5];
    const void* enc_mw = d_in[6];
    const void* enc_mb = d_in[7];
    const void* dec_vw = d_in[8];
    const void* dec_vb = d_in[9];
    const void* dec_mw = d_in[10];
    const void* dec_mb = d_in[11];
    const void* eW    = d_in[12];
    const void* ebi   = d_in[13];
    const void* effw1 = d_in[14];
    const void* effb1 = d_in[15];
    const void* effw2 = d_in[16];
    const void* effb2 = d_in[17];
    const void* eln1  = d_in[18];
    const void* eln2  = d_in[19];
    const void* cw    = d_in[20];
    const void* cb    = d_in[21];
    const void* cbn_g = d_in[22];
    const void* cbn_b = d_in[23];
    const void* enc_norm = d_in[24];
    const void* dsW   = d_in[25];
    const void* dsb   = d_in[26];
    const void* dcW   = d_in[27];
    const void* dcb   = d_in[28];
    const void* dffw1 = d_in[29];
    const void* dffb1 = d_in[30];
    const void* dffw2 = d_in[31];
    const void* dffb2 = d_in[32];
    const void* dln   = d_in[33];
    const void* dec_norm = d_in[34];
    const void* fcw   = d_in[35];
    const void* fcb   = d_in[36];

    // ---- workspace layout (~90 MiB; 111 MiB footprint ran clean in round 1) ----
    // X    [0, 8M)      : encoder acts; MEM + Yd in decoder phase
    // QKV  [8M, 40M)    : fused QKV / FFN hidden (aliased) / conv out / cross CQ+CKV
    // OUT  [40M, 48M)   : O-proj / FFN2 dest
    // WT   [48M, ~86.8M): ALL transposed weights (one-time prologue)
    // misc [88M, ~90M)  : IDX0/IDX1, PART (64*4KB), STATS, FLAG
    char* wsp = (char*)d_ws;
    bf16* X    = (bf16*)wsp;
    bf16* QKV  = (bf16*)(wsp + ((size_t)8 << 20));
    bf16* HID  = QKV;                                 // FFN hidden aliases dead QKV
    bf16* OUT  = (bf16*)(wsp + ((size_t)40 << 20));
    bf16* WT   = (bf16*)(wsp + ((size_t)48 << 20));
    int*   IDX0 = (int*)(wsp + ((size_t)88 << 20));   // 3*16*514 = 24672 ints
    int*   IDX1 = IDX0 + 24672;                       // 3*16*259 = 12432 ints
    float* PART = (float*)(wsp + ((size_t)89 << 20));
    float* STATS= (float*)(wsp + ((size_t)89 << 20) + (1 << 18));
    int*   FLAG = (int*)(wsp + ((size_t)89 << 20) + (1 << 18) + 4096);
    bf16* MEMb = X;                                               // [2080][512]
    bf16* Yd   = (bf16*)(wsp + (size_t)16 * 130 * 512 * 2);       // [4096][512]

    // transposed weight sub-arenas (element offsets)
    bf16* WTE  = WT;                    // enc QKVO: (i*4+q)*262144
    bf16* EW1T = WT + 3145728;          // + i*1048576
    bf16* EW2T = WT + 6291456;          // + i*1048576
    bf16* CWT  = WT + 9437184;          // + i*786432
    bf16* DSWt = WT + 11010048;         // + (i*4+q)*262144
    bf16* DCWt = WT + 13107200;
    bf16* DW1T = WT + 15204352;
    bf16* DW2T = WT + 17301504;

    auto cdiv = [](int a, int b) { return (a + b - 1) / b; };
    auto gemm = [&](const bf16* A, const bf16* Wt, const void* bias, unsigned boff,
                    bf16* C, int M, int N, int K, int lda, int ldc, bool relu) {
        dim3 g(N / 128, cdiv(M, 128));
        if (relu) mgemm_k<false, true><<<g, 256, 0, stream>>>(
            (const short*)A, nullptr, (const short*)Wt, bias, boff, C, M, N, K, lda, ldc, FLAG);
        else      mgemm_k<false, false><<<g, 256, 0, stream>>>(
            (const short*)A, nullptr, (const short*)Wt, bias, boff, C, M, N, K, lda, ldc, FLAG);
    };
    auto gemm64 = [&](const bf16* A, const bf16* Wt, const void* bias, unsigned boff,
                      bf16* C, int M, int N, int K, int lda, int ldc, bool relu) {
        dim3 g(N / 64, cdiv(M, 64));
        if (relu) mgemm64_k<false, true><<<g, 256, 0, stream>>>(
            (const short*)A, nullptr, (const short*)Wt, bias, boff, C, M, N, K, lda, ldc, FLAG);
        else      mgemm64_k<false, false><<<g, 256, 0, stream>>>(
            (const short*)A, nullptr, (const short*)Wt, bias, boff, C, M, N, K, lda, ldc, FLAG);
    };
    auto transp = [&](const void* W, unsigned zstride, int nz, bf16* out, int K, int N) {
        transp_k<<<dim3(N / 32, K / 32, nz), 256, 0, stream>>>(W, 0u, zstride, out, K, N, FLAG);
    };

    // ---- prologue: sniff, all weight transposes, conv indices, embeddings ----
    sniff_k<<<1, 256, 0, stream>>>((const unsigned*)x_mark_enc, 16384, FLAG);
    transp(eW,    262144u, 12, WTE,  512, 512);
    transp(effw1, 1048576u, 3, EW1T, 512, 2048);
    transp(effw2, 1048576u, 3, EW2T, 2048, 512);
    convw_k<<<cdiv(1572864, 256), 256, 0, stream>>>(cw, CWT, 1572864, FLAG);
    transp(dsW,   262144u, 8, DSWt, 512, 512);
    transp(dcW,   262144u, 8, DCWt, 512, 512);
    transp(dffw1, 1048576u, 2, DW1T, 512, 2048);
    transp(dffw2, 1048576u, 2, DW2T, 2048, 512);
    convidx_k<<<cdiv(24672, 256), 256, 0, stream>>>(IDX0, 514, 512, 24672);
    convidx_k<<<cdiv(12432, 256), 256, 0, stream>>>(IDX1, 259, 257, 12432);
    embed_k<<<cdiv(16 * 512 * 512, 256), 256, 0, stream>>>(
        x_enc, enc_vw, enc_vb, x_mark_enc, enc_mw, enc_mb, X, 16 * 512, 7, 4, FLAG);

    // ---- encoder ----
    int L = 512;
    for (int i = 0; i < 3; ++i) {
        const int rows = 16 * L;
        const unsigned b0 = (unsigned)i * 4u * 512u;
        // QKV: big grid only at L=512 -> mgemm; else 64x64 for concurrency
        if (i == 0) gemm(X, WTE + (size_t)i * 4 * 262144, ebi, b0, QKV, rows, 1536, 512, 512, 1536, false);
        else      gemm64(X, WTE + (size_t)i * 4 * 262144, ebi, b0, QKV, rows, 1536, 512, 512, 1536, false);
        fattn_k<0><<<dim3(cdiv(L, 16), 8, 16), 512, 0, stream>>>(
            QKV, QKV + 512, QKV + 1024, 1536, 1536, L, L);
        gemm64(QKV, WTE + (size_t)(i * 4 + 3) * 262144, ebi, b0 + 1536u, OUT, rows, 512, 512, 1536, 512, false);
        ln_off_k<<<rows, 256, 0, stream>>>(X, OUT, eln1, (unsigned)i * 1024u, X, FLAG);

        if (i == 0) gemm(X, EW1T + (size_t)i * 1048576, effb1, (unsigned)i * 2048u, HID, rows, 2048, 512, 512, 2048, true);
        else      gemm64(X, EW1T + (size_t)i * 1048576, effb1, (unsigned)i * 2048u, HID, rows, 2048, 512, 512, 2048, true);
        gemm64(HID, EW2T + (size_t)i * 1048576, effb2, (unsigned)i * 512u, OUT, rows, 512, 2048, 2048, 512, false);
        ln_off_k<<<rows, 256, 0, stream>>>(X, OUT, eln2, (unsigned)i * 1024u, X, FLAG);

        if (i < 2) {
            const int Lc = L + 2, Mc = 16 * Lc;
            const int* IDXi = (i == 0) ? IDX0 : IDX1;
            mgemm64_k<true, false><<<dim3(8, cdiv(Mc, 64)), 256, 0, stream>>>(
                (const short*)X, IDXi, (const short*)(CWT + (size_t)i * 786432),
                cb, (unsigned)i * 512u, QKV, Mc, 512, 1536, 512, 512, FLAG);
            bnstat1_k<<<64, 256, 0, stream>>>(QKV, PART, Mc);
            bnstat2_k<<<2, 256, 0, stream>>>(PART, STATS, 64, Mc);
            const int Lout = (L + 1) / 2 + 1;   // 514->257, 259->130
            const int tot = 16 * Lout * 512;
            bnpool_k<<<cdiv(tot, 256), 256, 0, stream>>>(
                QKV, STATS, cbn_g, cbn_b, (unsigned)i * 512u, X, Lc, Lout, tot, FLAG);
            L = Lout;
        }
    }
    const int Lm = L;  // 130
    ln_off_k<<<16 * Lm, 256, 0, stream>>>(X, nullptr, enc_norm, 0u, MEMb, FLAG);

    // ---- decoder embedding ----
    const int rowsD = 16 * 256;
    embed_k<<<cdiv(rowsD * 512, 256), 256, 0, stream>>>(
        x_dec, dec_vw, dec_vb, x_mark_dec, dec_mw, dec_mb, Yd, rowsD, 7, 4, FLAG);

    // ---- decoder (all GEMMs via 64x64 for concurrency) ----
    bf16* CQ  = QKV;                       // [4096][512]
    bf16* CKV = QKV + (size_t)4096 * 512;  // [2080][1024]
    for (int i = 0; i < 2; ++i) {
        const unsigned b0 = (unsigned)i * 4u * 512u;
        // self-attention
        gemm64(Yd, DSWt + (size_t)i * 4 * 262144, dsb, b0, QKV, rowsD, 1536, 512, 512, 1536, false);
        fattn_k<1><<<dim3(16, 8, 16), 512, 0, stream>>>(
            QKV, QKV + 512, QKV + 1024, 1536, 1536, 256, 256);
        gemm64(QKV, DSWt + (size_t)(i * 4 + 3) * 262144, dsb, b0 + 1536u, OUT, rowsD, 512, 512, 1536, 512, false);
        ln_off_k<<<rowsD, 256, 0, stream>>>(Yd, OUT, dln, (unsigned)(i * 3 + 0) * 1024u, Yd, FLAG);

        // cross-attention
        gemm64(Yd, DCWt + (size_t)i * 4 * 262144, dcb, b0, CQ, rowsD, 512, 512, 512, 512, false);
        gemm64(MEMb, DCWt + (size_t)(i * 4 + 1) * 262144, dcb, b0 + 512u, CKV, 16 * Lm, 1024, 512, 512, 1024, false);
        fattn_k<2><<<dim3(16, 8, 16), 512, 0, stream>>>(
            CQ, CKV, CKV + 512, 512, 1024, 256, Lm);
        gemm64(CQ, DCWt + (size_t)(i * 4 + 3) * 262144, dcb, b0 + 1536u, OUT, rowsD, 512, 512, 512, 512, false);
        ln_off_k<<<rowsD, 256, 0, stream>>>(Yd, OUT, dln, (unsigned)(i * 3 + 1) * 1024u, Yd, FLAG);

        // FFN
        gemm64(Yd, DW1T + (size_t)i * 1048576, dffb1, (unsigned)i * 2048u, HID, rowsD, 2048, 512, 512, 2048, true);
        gemm64(HID, DW2T + (size_t)i * 1048576, dffb2, (unsigned)i * 512u, OUT, rowsD, 512, 2048, 2048, 512, false);
        ln_off_k<<<rowsD, 256, 0, stream>>>(Yd, OUT, dln, (unsigned)(i * 3 + 2) * 1024u, Yd, FLAG);
    }

    ln_off_k<<<rowsD, 256, 0, stream>>>(Yd, nullptr, dec_norm, 0u, OUT, FLAG);
    fc_k<<<cdiv(rowsD * 7, 256), 256, 0, stream>>>(OUT, fcw, fcb, d_out, rowsD * 7, FLAG);
}

// Round 11
// 1226.553 us; speedup vs baseline: 1.1830x; 1.0077x over previous
//
#include <hip/hip_runtime.h>
#include <hip/hip_bf16.h>

// Informer forward, MI355X. Round 19: fattn jm-bounded phase-2 + fast exp.
//  - Round-18: 1236us (A-panel XCD chunk + mgemm_k BK64 = -80us). fattn<0> L512
//    still 92.6us, VALUBusy 65% @ occ 69% -> VALU-issue bound.
//  - Waste found: phase-2/3 loops unroll to j<8 (512 cols) but kpad/64 = jm is
//    5 (L257), 3 (L130), ~2.5 avg (causal), 3 (cross) -> ~half the attention
//    VALU (key build, ~20x8 radix cmps, compaction, softmax passes) runs on
//    constant-zero keys. Fix: wave-uniform `if (j < jm)` guards inside the
//    static unroll (rule #20 safe: indices stay compile-time). Zero-keys never
//    pass any trial (T2 >= 1) -> skipping them is EXACT, selection unchanged.
//  - expf -> __expf (2 inst vs ~8): ~200 VALU/wave (~13%) on every dispatch
//    incl. the hot L512. Weight perturbation ~1e-7 rel; margin 0.0088 vs 0.0347.
//  - GEMMs untouched for clean A/B.
// Round 18: passed, absmax 0.0088, 1236.0 us.
// B=16, LE=512, LD=256, D=512, H=8, dk=64, DFF=2048, NE=3, ND=2, TOPK=16.
// Encoder lengths: 512 -> conv(514)/pool -> 257 -> conv(259)/pool -> 130.

#define DM 512
#define DK 64

using bf16 = __hip_bfloat16;
typedef short s8v __attribute__((ext_vector_type(8)));
typedef float f4v __attribute__((ext_vector_type(4)));

__device__ inline float b2f(bf16 x) { return __bfloat162float(x); }
__device__ inline float u2f(unsigned short u) { return __uint_as_float((unsigned)u << 16); }

// flag f: 1 = raw inputs are bf16, 0 = raw inputs are fp32. idx in ELEMENTS.
__device__ inline float ldw(const void* p, unsigned i, int f) {
    return f ? b2f(((const bf16*)p)[i]) : ((const float*)p)[i];
}

// order-preserving float->u32 (monotonic)
__device__ inline unsigned f2ord(float s) {
    unsigned u = __float_as_uint(s);
    return u ^ ((unsigned)((int)u >> 31) | 0x80000000u);
}

// popcount of mask bits strictly below this lane
__device__ inline int popc_lt(unsigned long long m) {
    return (int)__builtin_amdgcn_mbcnt_hi((unsigned)(m >> 32),
            __builtin_amdgcn_mbcnt_lo((unsigned)m, 0u));
}

// bijective chunked XCD swizzle (m204): linear id -> id such that each XCD
// (assumed lin%8 dispatch) owns a CONTIGUOUS id range. Perf-only heuristic.
__device__ inline int xcd_chunk_id(int lin, int nwg) {
    const int xcd = lin & 7;
    const int pos = lin >> 3;
    const int q = nwg >> 3, r = nwg & 7;
    return (xcd < r ? xcd * (q + 1) : r * (q + 1) + (xcd - r) * q) + pos;
}

// async global->LDS, 16 B per lane; lds dst must be wave-uniform (lane i lands at dst+16*i)
__device__ inline void gl_lds16(const short* g, short* l) {
    __builtin_amdgcn_global_load_lds(
        (const __attribute__((address_space(1))) unsigned int*)g,
        (__attribute__((address_space(3))) unsigned int*)l,
        16, 0, 0);
}

// ---------------- dtype sniffer ----------------
__global__ __launch_bounds__(256) void sniff_k(const unsigned* __restrict__ x, int nwords,
                                               int* __restrict__ flag) {
    __shared__ int red[4];
    const int t = threadIdx.x;
    int c = 0;
    for (int i = t; i < nwords; i += 256) c += ((x[i] & 0x7F80u) == 0x3F80u) ? 1 : 0;
    #pragma unroll
    for (int o = 32; o > 0; o >>= 1) c += __shfl_down(c, o);
    __syncthreads();
    if ((t & 63) == 0) red[t >> 6] = c;
    __syncthreads();
    if (t == 0) flag[0] = (red[0] + red[1] + red[2] + red[3] > nwords / 20) ? 1 : 0;
}

// ---------------- reductions (blockDim == 256) ----------------
__device__ inline float block_sum256(float v, float* red) {
    #pragma unroll
    for (int o = 32; o > 0; o >>= 1) v += __shfl_down(v, o);
    __syncthreads();
    if ((threadIdx.x & 63) == 0) red[threadIdx.x >> 6] = v;
    __syncthreads();
    return red[0] + red[1] + red[2] + red[3];
}

// ---------------- embedding ----------------
__global__ __launch_bounds__(256) void embed_k(
    const void* __restrict__ xv, const void* __restrict__ vw, const void* __restrict__ vb,
    const void* __restrict__ xm, const void* __restrict__ mw, const void* __restrict__ mb,
    bf16* __restrict__ Out, int rows, int Cv, int Cm, const int* __restrict__ flagp)
{
    const int f = *flagp;
    int i = blockIdx.x * 256 + threadIdx.x;
    if (i >= rows * DM) return;
    const int r = i >> 9, d = i & 511;
    float acc = ldw(vb, d, f) + ldw(mb, d, f);
    for (int c = 0; c < Cv; ++c) acc += ldw(xv, r * Cv + c, f) * ldw(vw, c * DM + d, f);
    for (int c = 0; c < Cm; ++c) acc += ldw(xm, r * Cm + c, f) * ldw(mw, c * DM + d, f);
    Out[i] = __float2bfloat16(acc);
}

// ---------------- weight transpose: raw [K][N] -> bf16 [N][K]; z batches sub-mats ----------------
__global__ __launch_bounds__(256) void transp_k(
    const void* __restrict__ W, unsigned off, unsigned zstride, bf16* __restrict__ out,
    int K, int N, const int* __restrict__ flagp)
{
    __shared__ float tile[32][33];
    const int f = *flagp;
    const unsigned zo = blockIdx.z * zstride;
    const int t = threadIdx.x;
    const int tx = t & 31, ty = t >> 5;               // 32 x 8
    const int n0 = blockIdx.x * 32, k0 = blockIdx.y * 32;
    #pragma unroll
    for (int i = 0; i < 4; ++i)
        tile[ty + 8 * i][tx] = ldw(W, off + zo + (unsigned)(k0 + ty + 8 * i) * N + n0 + tx, f);
    __syncthreads();
    #pragma unroll
    for (int i = 0; i < 4; ++i)
        out[(size_t)zo + (size_t)(n0 + ty + 8 * i) * K + k0 + tx] = __float2bfloat16(tile[tx][ty + 8 * i]);
}

// ---------------- MFMA GEMM 128x128 (256 thr), BK=64 single-buffer, T2 swizzle ----------------
// 8 K-iters (32 MFMA each) for K=512. Chunked XCD swizzle for A-panel L2 locality.
// Rule #21 layout: linear LDS dest + inverse-swizzled global source + swizzled read.
// Used only for large-grid GEMMs (encoder L1 QKV / FFN1: >= 768 blocks).
template<bool G3, bool RELU>
__global__ __launch_bounds__(256) void mgemm_k(
    const short* __restrict__ A, const int* __restrict__ ridx,
    const short* __restrict__ Wt,
    const void* __restrict__ bias, unsigned boff0,
    bf16* __restrict__ C, int M, int N, int K, int lda, int ldc,
    const int* __restrict__ flagp)
{
    __shared__ short As[128 * 64];
    __shared__ short Ws[128 * 64];
    const int t = threadIdx.x;
    const int gx = gridDim.x;
    const int id = xcd_chunk_id(blockIdx.x + gx * blockIdx.y, gx * gridDim.y);
    const int bn = (id % gx) * 128, bm = (id / gx) * 128;
    const int lane = t & 63, wave = t >> 6;
    const int mbase = (wave >> 1) * 64, nbase = (wave & 1) * 64;
    const int l15 = lane & 15, quad = lane >> 4;
    const int lrow = lane >> 3;                        // 8 rows per gl_lds16 call
    const int lk = ((lane & 7) ^ (lrow & 7)) * 8;      // inverse-swizzled source chunk

    f4v acc[4][4] = {};

    for (int k0 = 0; k0 < K; k0 += 64) {
        __syncthreads();
        #pragma unroll
        for (int j = 0; j < 4; ++j) {                  // A: 32 rows per wave
            const int rb = wave * 32 + j * 8;
            const int row = bm + rb + lrow;
            const int rowc = row < M ? row : M - 1;
            const short* g;
            if (G3) {
                const int r = ridx[(k0 >> 9) * M + rowc];
                g = A + (size_t)r * lda + (k0 & 511) + lk;
            } else {
                g = A + (size_t)rowc * lda + k0 + lk;
            }
            gl_lds16(g, &As[rb * 64]);
        }
        #pragma unroll
        for (int j = 0; j < 4; ++j) {                  // B: 32 rows per wave
            const int nb = wave * 32 + j * 8;
            gl_lds16(Wt + (size_t)(bn + nb + lrow) * K + k0 + lk, &Ws[nb * 64]);
        }
        __syncthreads();
        #pragma unroll
        for (int kk = 0; kk < 2; ++kk) {               // k0+32*kk ascending -> bit-identical
            s8v af[4], bfv[4];
            #pragma unroll
            for (int i = 0; i < 4; ++i) {
                const int ra = mbase + i * 16 + l15;
                af[i]  = *(const s8v*)&As[ra * 64 + (((kk * 4 + quad) ^ (ra & 7)) << 3)];
                const int rb2 = nbase + i * 16 + l15;
                bfv[i] = *(const s8v*)&Ws[rb2 * 64 + (((kk * 4 + quad) ^ (rb2 & 7)) << 3)];
            }
            #pragma unroll
            for (int mi = 0; mi < 4; ++mi)
                #pragma unroll
                for (int ni = 0; ni < 4; ++ni)
                    acc[mi][ni] = __builtin_amdgcn_mfma_f32_16x16x32_bf16(
                        af[mi], bfv[ni], acc[mi][ni], 0, 0, 0);
        }
    }

    const int f = *flagp;
    float bv[4];
    #pragma unroll
    for (int ni = 0; ni < 4; ++ni)
        bv[ni] = ldw(bias, boff0 + (unsigned)(bn + nbase + ni * 16 + l15), f);

    #pragma unroll
    for (int mi = 0; mi < 4; ++mi) {
        #pragma unroll
        for (int r = 0; r < 4; ++r) {
            const int row = bm + mbase + mi * 16 + quad * 4 + r;
            if (row < M) {
                #pragma unroll
                for (int ni = 0; ni < 4; ++ni) {
                    float o = acc[mi][ni][r] + bv[ni];
                    if (RELU) o = fmaxf(o, 0.f);
                    C[(size_t)row * ldc + bn + nbase + ni * 16 + l15] = __float2bfloat16(o);
                }
            }
        }
    }
}

// ---------------- MFMA GEMM 64x64 (256 thr, 4 waves x 32x32), BK=64, dbuf ----------------
// grid (N/64, cdiv(M,64)). Chunked XCD swizzle: A-panel fetched once per XCD.
// 8 MFMA + 8 swizzled ds_read_b128 per iter, one barrier/iter.
template<bool G3, bool RELU>
__global__ __launch_bounds__(256) void mgemm64_k(
    const short* __restrict__ A, const int* __restrict__ ridx,
    const short* __restrict__ Wt,
    const void* __restrict__ bias, unsigned boff0,
    bf16* __restrict__ C, int M, int N, int K, int lda, int ldc,
    const int* __restrict__ flagp)
{
    __shared__ short As[2][64 * 64];
    __shared__ short Ws[2][64 * 64];
    const int t = threadIdx.x;
    const int gx = gridDim.x;
    const int id = xcd_chunk_id(blockIdx.x + gx * blockIdx.y, gx * gridDim.y);
    const int bn = (id % gx) * 64, bm = (id / gx) * 64;
    const int lane = t & 63, wave = t >> 6;
    const int mbase = (wave >> 1) * 32, nbase = (wave & 1) * 32;
    const int l15 = lane & 15, quad = lane >> 4;
    const int lrow = lane >> 3;                        // 8 rows per gl_lds16 call
    const int lk = ((lane & 7) ^ (lrow & 7)) * 8;      // inverse-swizzled source chunk

    f4v acc[2][2] = {};

    auto stage = [&](int buf, int k0) {
        #pragma unroll
        for (int j = 0; j < 2; ++j) {                  // A: 16 rows per wave
            const int rb = wave * 16 + j * 8;
            const int row = bm + rb + lrow;
            const int rowc = row < M ? row : M - 1;
            const short* g;
            if (G3) {
                const int r = ridx[(k0 >> 9) * M + rowc];
                g = A + (size_t)r * lda + (k0 & 511) + lk;
            } else {
                g = A + (size_t)rowc * lda + k0 + lk;
            }
            gl_lds16(g, &As[buf][rb * 64]);
        }
        #pragma unroll
        for (int j = 0; j < 2; ++j) {                  // B: 16 rows per wave
            const int nb = wave * 16 + j * 8;
            gl_lds16(Wt + (size_t)(bn + nb + lrow) * K + k0 + lk, &Ws[buf][nb * 64]);
        }
    };

    const int nt = K >> 6;
    stage(0, 0);
    __syncthreads();
    for (int it = 0; it < nt; ++it) {
        if (it + 1 < nt) stage((it + 1) & 1, (it + 1) << 6);
        const int cb = it & 1;
        #pragma unroll
        for (int kk = 0; kk < 2; ++kk) {               // k0+32*kk ascending -> bit-identical
            s8v af[2], bfv[2];
            #pragma unroll
            for (int i = 0; i < 2; ++i) {
                const int ra = mbase + i * 16 + l15;
                af[i]  = *(const s8v*)&As[cb][ra * 64 + (((kk * 4 + quad) ^ (ra & 7)) << 3)];
                const int rb2 = nbase + i * 16 + l15;
                bfv[i] = *(const s8v*)&Ws[cb][rb2 * 64 + (((kk * 4 + quad) ^ (rb2 & 7)) << 3)];
            }
            #pragma unroll
            for (int mi = 0; mi < 2; ++mi)
                #pragma unroll
                for (int ni = 0; ni < 2; ++ni)
                    acc[mi][ni] = __builtin_amdgcn_mfma_f32_16x16x32_bf16(
                        af[mi], bfv[ni], acc[mi][ni], 0, 0, 0);
        }
        if (it + 1 < nt) __syncthreads();
    }

    const int f = *flagp;
    float bv[2];
    #pragma unroll
    for (int ni = 0; ni < 2; ++ni)
        bv[ni] = ldw(bias, boff0 + (unsigned)(bn + nbase + ni * 16 + l15), f);

    #pragma unroll
    for (int mi = 0; mi < 2; ++mi) {
        #pragma unroll
        for (int r = 0; r < 4; ++r) {
            const int row = bm + mbase + mi * 16 + quad * 4 + r;
            if (row < M) {
                #pragma unroll
                for (int ni = 0; ni < 2; ++ni) {
                    float o = acc[mi][ni][r] + bv[ni];
                    if (RELU) o = fmaxf(o, 0.f);
                    C[(size_t)row * ldc + bn + nbase + ni * 16 + l15] = __float2bfloat16(o);
                }
            }
        }
    }
}

// ---------------- fused tile attention (strided q/k/v), 512 threads ----------------
// MODE 0: ProbSparse top-16. MODE 1: causal. MODE 2: plain cross.
// XCD-locality swizzle; 8 waves; phase 1 = MFMA QK^T (direct-global K frags, 2-deep
// pipeline); phase 2+3 = rows {wave, wave+8} fused. All phase-2 loops are bounded by
// jm = kpad/64 (wave-uniform guards inside static unrolls; zero-keys never pass any
// radix trial since T2 >= 1, so skipping them is exact). __expf for all softmax exps.
template<int MODE>
__global__ __launch_bounds__(512, 8) void fattn_k(
    bf16* __restrict__ q, const bf16* __restrict__ k, const bf16* __restrict__ v,
    int ldq, int ldkv, int Lq, int Lk)
{
    __shared__ short Qs[16 * 72];
    __shared__ float S[16 * 516];
    __shared__ int   PC[16][16];
    __shared__ float PE[16][16];

    const int t = threadIdx.x;
    // ---- XCD swizzle (bijective: nwg = gx*128, always % 8 == 0) ----
    const int gx = gridDim.x;
    const int nwg = gx * 128;                         // y=8, z=16 fixed
    const int lin = blockIdx.x + gx * (blockIdx.y + 8 * blockIdx.z);
    const int id = (lin & 7) * (nwg >> 3) + (lin >> 3);
    const int q0 = (id % gx) * 16;
    const int h  = (id / gx) & 7;
    const int b  = id / (gx * 8);

    const int lane = t & 63, wave = t >> 6;           // 8 waves
    const int l15 = lane & 15, quad = lane >> 4;

    const int qv = (Lq - q0) < 16 ? (Lq - q0) : 16;

    const bf16* Kbase = k + (size_t)b * Lk * ldkv + h * DK;
    const bf16* Vbase = v + (size_t)b * Lk * ldkv + h * DK;
    bf16* Qbase = q + (size_t)(b * Lq + q0) * ldq + h * DK;

    const int kmax = (MODE == 1) ? (q0 + 16 < Lk ? q0 + 16 : Lk) : Lk;
    const int ntile = (kmax + 63) >> 6;
    const int kpad = ntile << 6;
    const int nchunk = kpad >> 4;
    const int jm = ntile;                             // = kpad / 64, wave-uniform

    {   // Q stage: all 512 threads (4B each; 16 rows x 128B)
        const int qr = t >> 5;
        const int qsrc = qr < qv ? qr : qv - 1;
        *(ushort2*)&Qs[qr * 72 + (t & 31) * 2] =
            *(const ushort2*)(Qbase + (size_t)qsrc * ldq + (t & 31) * 2);
    }
    __syncthreads();

    // ---- phase 1: S = QK^T / 8 (+ masks); 2-deep K-load pipeline ----
    {
        const s8v a0 = *(const s8v*)&Qs[l15 * 72 + quad * 8];
        const s8v a1 = *(const s8v*)&Qs[l15 * 72 + 32 + quad * 8];
        int c = wave;
        s8v b0, b1;
        if (c < nchunk) {
            int srow = c * 16 + l15; if (srow >= Lk) srow = Lk - 1;
            const bf16* kp = Kbase + (size_t)srow * ldkv + quad * 8;
            b0 = *(const s8v*)kp;
            b1 = *(const s8v*)(kp + 32);
        }
        while (c < nchunk) {
            const int cn = c + 8;
            s8v n0, n1;
            if (cn < nchunk) {
                int srow = cn * 16 + l15; if (srow >= Lk) srow = Lk - 1;
                const bf16* kp = Kbase + (size_t)srow * ldkv + quad * 8;
                n0 = *(const s8v*)kp;
                n1 = *(const s8v*)(kp + 32);
            }
            f4v acc = {0.f, 0.f, 0.f, 0.f};
            acc = __builtin_amdgcn_mfma_f32_16x16x32_bf16(a0, b0, acc, 0, 0, 0);
            acc = __builtin_amdgcn_mfma_f32_16x16x32_bf16(a1, b1, acc, 0, 0, 0);
            const int colg = c * 16 + l15;
            #pragma unroll
            for (int r = 0; r < 4; ++r) {
                const int qrow = quad * 4 + r;
                float s = acc[r] * 0.125f;
                if (colg >= Lk) s = -1e9f;
                if (MODE == 1 && colg > q0 + qrow) s = -1e9f;
                S[qrow * 516 + colg] = s;
            }
            b0 = n0; b1 = n1; c = cn;
        }
    }
    __syncthreads();

    // ---- phase 2+3: rows {wave, wave+8} processed fused ----
    const int rowA = wave, rowB = wave + 8;
    float aA = 0.f, aB = 0.f;
    float invA, invB;
    if (MODE == 0) {
        // packed keys: 23-bit quantized score | 9-bit col; j >= jm stays 0
        // (inside j < jm, col = lane + 64j < kpad always; S valid up to kpad)
        unsigned keyA[8], keyB[8];
        #pragma unroll
        for (int j = 0; j < 8; ++j) {
            keyA[j] = 0u; keyB[j] = 0u;
            if (j < jm) {
                const int col = lane + 64 * j;
                keyA[j] = (f2ord(S[rowA * 516 + col]) & 0xFFFFFE00u) | (unsigned)col;
                keyB[j] = (f2ord(S[rowB * 516 + col]) & 0xFFFFFE00u) | (unsigned)col;
            }
        }
        // row maxes (exp offsets): two interleaved butterflies
        unsigned kmA = keyA[0], kmB = keyB[0];
        #pragma unroll
        for (int j = 1; j < 8; ++j) {
            if (j < jm) {
                kmA = kmA > keyA[j] ? kmA : keyA[j];
                kmB = kmB > keyB[j] ? kmB : keyB[j];
            }
        }
        #pragma unroll
        for (int off = 1; off < 64; off <<= 1) {
            const unsigned oA = __shfl_xor(kmA, off);
            const unsigned oB = __shfl_xor(kmB, off);
            kmA = kmA > oA ? kmA : oA;
            kmB = kmB > oB ? kmB : oB;
        }
        const float mrA = S[rowA * 516 + (int)(kmA & 511u)];
        const float mrB = S[rowB * 516 + (int)(kmB & 511u)];

        // interleaved full-32-bit binary searches. Largest T with
        // count(key >= T) >= 16; keys distinct -> terminates at exactly 16.
        // Zero-keys (j >= jm) never satisfy key >= T2 (T2 >= 1) -> skip exact.
        unsigned TA = 0u, TB = 0u;
        bool dA = false, dB = false;
        for (int bbit = 31; bbit >= 0; --bbit) {
            if (!dA) {
                const unsigned T2 = TA | (1u << bbit);
                int c = 0;
                #pragma unroll
                for (int j = 0; j < 8; ++j)
                    if (j < jm) c += (int)__popcll(__ballot(keyA[j] >= T2));
                if (c >= 16) { TA = T2; dA = (c == 16); }
            }
            if (!dB) {
                const unsigned T2 = TB | (1u << bbit);
                int c = 0;
                #pragma unroll
                for (int j = 0; j < 8; ++j)
                    if (j < jm) c += (int)__popcll(__ballot(keyB[j] >= T2));
                if (c >= 16) { TB = T2; dB = (c == 16); }
            }
            if (dA && dB) break;
        }

        // compaction: exactly the 16 keys >= T per row -> (col, e) in LDS
        int cntA = 0, cntB = 0;
        #pragma unroll
        for (int j = 0; j < 8; ++j) {
            if (j < jm) {
                const bool sA = keyA[j] >= TA;
                const unsigned long long balA = __ballot(sA);
                if (sA) {
                    const int p = cntA + popc_lt(balA);
                    const int col = (int)(keyA[j] & 511u);
                    PC[rowA][p] = col;
                    PE[rowA][p] = __expf(S[rowA * 516 + col] - mrA);
                }
                cntA += (int)__popcll(balA);
                const bool sB = keyB[j] >= TB;
                const unsigned long long balB = __ballot(sB);
                if (sB) {
                    const int p = cntB + popc_lt(balB);
                    const int col = (int)(keyB[j] & 511u);
                    PC[rowB][p] = col;
                    PE[rowB][p] = __expf(S[rowB * 516 + col] - mrB);
                }
                cntB += (int)__popcll(balB);
            }
        }
        // wave-private rows: same-wave DS ops in order; no barrier needed

        float denA = 0.f, denB = 0.f;
        #pragma unroll
        for (int it = 0; it < 16; ++it) {
            const int cA = PC[rowA][it];
            const float eA = PE[rowA][it];
            denA += eA;
            aA += eA * b2f(Vbase[(size_t)cA * ldkv + lane]);
            const int cB = PC[rowB][it];
            const float eB = PE[rowB][it];
            denB += eB;
            aB += eB * b2f(Vbase[(size_t)cB * ldkv + lane]);
        }
        invA = 1.f / denA;
        invB = 1.f / denB;
    } else {
        float lvA = -INFINITY, lvB = -INFINITY;
        #pragma unroll
        for (int j = 0; j < 8; ++j) {
            if (j < jm) {
                const int col = lane + 64 * j;   // col < kpad guaranteed
                lvA = fmaxf(lvA, S[rowA * 516 + col]);
                lvB = fmaxf(lvB, S[rowB * 516 + col]);
            }
        }
        #pragma unroll
        for (int off = 1; off < 64; off <<= 1) {
            lvA = fmaxf(lvA, __shfl_xor(lvA, off));
            lvB = fmaxf(lvB, __shfl_xor(lvB, off));
        }
        float pA = 0.f, pB = 0.f;
        #pragma unroll
        for (int j = 0; j < 8; ++j) {
            if (j < jm) {
                const int col = lane + 64 * j;
                const float wA = __expf(S[rowA * 516 + col] - lvA);
                const float wB = __expf(S[rowB * 516 + col] - lvB);
                S[rowA * 516 + col] = wA;
                S[rowB * 516 + col] = wB;
                pA += wA; pB += wB;
            }
        }
        #pragma unroll
        for (int off = 1; off < 64; off <<= 1) {
            pA += __shfl_xor(pA, off);
            pB += __shfl_xor(pB, off);
        }
        invA = 1.f / pA;
        invB = 1.f / pB;
        // fused PV: one V row feeds both rows' FMAs. Causal-masked cols have
        // w = exp(-1e9 - lv) = +0 exactly -> running to kmax is bit-identical.
        #pragma unroll 8
        for (int k2 = 0; k2 < kmax; ++k2) {
            const float vv = b2f(Vbase[(size_t)k2 * ldkv + lane]);
            aA += S[rowA * 516 + k2] * vv;
            aB += S[rowB * 516 + k2] * vv;
        }
    }
    if (rowA < qv)
        Qbase[(size_t)rowA * ldq + lane] = __float2bfloat16(aA * invA);
    if (rowB < qv)
        Qbase[(size_t)rowB * ldq + lane] = __float2bfloat16(aB * invB);
}

// ---------------- layernorm over D=512, optional residual; in-place safe ----------------
__global__ __launch_bounds__(256) void ln_off_k(
    const bf16* __restrict__ X, const bf16* __restrict__ R,
    const void* __restrict__ gb, unsigned goff,
    bf16* __restrict__ Out, const int* __restrict__ flagp)
{
    __shared__ float red[4];
    const int f = *flagp;
    const int t = threadIdx.x;
    const size_t base = (size_t)blockIdx.x * DM;
    float v0 = b2f(X[base + t]), v1 = b2f(X[base + t + 256]);
    if (R) { v0 += b2f(R[base + t]); v1 += b2f(R[base + t + 256]); }
    const float mean = block_sum256(v0 + v1, red) * (1.f / 512.f);
    const float d0 = v0 - mean, d1 = v1 - mean;
    const float var = block_sum256(d0 * d0 + d1 * d1, red) * (1.f / 512.f);
    const float rstd = rsqrtf(var + 1e-5f);
    Out[base + t]       = __float2bfloat16(d0 * rstd * ldw(gb, goff + t, f)       + ldw(gb, goff + 512 + t, f));
    Out[base + t + 256] = __float2bfloat16(d1 * rstd * ldw(gb, goff + t + 256, f) + ldw(gb, goff + 768 + t, f));
}

// ---------------- conv distill helpers ----------------
// conv weights w[2][o][c][j] -> transposed GEMM layout wt[layer][o][j*512+c]
__global__ __launch_bounds__(256) void convw_k(const void* __restrict__ w,
                                               bf16* __restrict__ wt, int total,
                                               const int* __restrict__ flagp) {
    const int f = *flagp;
    int i = blockIdx.x * 256 + threadIdx.x;
    if (i >= total) return;
    const int layer = i / 786432, rem2 = i % 786432;
    const int o = rem2 / 1536, rem = rem2 % 1536;
    const int j = rem >> 9, c = rem & 511;
    wt[i] = __float2bfloat16(ldw(w, (unsigned)layer * 786432u + (unsigned)(o * 512 + c) * 3 + j, f));
}

__global__ __launch_bounds__(256) void convidx_k(int* __restrict__ idx, int Lc, int L, int total) {
    int i = blockIdx.x * 256 + threadIdx.x;
    if (i >= total) return;
    const int j = i / (16 * Lc), mrem = i % (16 * Lc);
    const int b = mrem / Lc, l = mrem % Lc;
    int src = l + j - 2;
    src %= L; if (src < 0) src += L;
    idx[i] = b * L + src;
}

// 64 blocks (PART arena = 64 * 4KB), 4-deep unrolled row loop for memory parallelism
__global__ __launch_bounds__(256) void bnstat1_k(const bf16* __restrict__ Y, float* __restrict__ part, int M) {
    const int t = threadIdx.x;
    const int g = gridDim.x;
    float s0 = 0.f, q0 = 0.f, s1 = 0.f, q1 = 0.f;
    int r = blockIdx.x;
    for (; r + 3 * g < M; r += 4 * g) {
        const ushort2 u0 = *reinterpret_cast<const ushort2*>(Y + (size_t)r * DM + t * 2);
        const ushort2 u1 = *reinterpret_cast<const ushort2*>(Y + (size_t)(r + g) * DM + t * 2);
        const ushort2 u2 = *reinterpret_cast<const ushort2*>(Y + (size_t)(r + 2 * g) * DM + t * 2);
        const ushort2 u3 = *reinterpret_cast<const ushort2*>(Y + (size_t)(r + 3 * g) * DM + t * 2);
        float a, c;
        a = u2f(u0.x); c = u2f(u0.y); s0 += a; q0 += a * a; s1 += c; q1 += c * c;
        a = u2f(u1.x); c = u2f(u1.y); s0 += a; q0 += a * a; s1 += c; q1 += c * c;
        a = u2f(u2.x); c = u2f(u2.y); s0 += a; q0 += a * a; s1 += c; q1 += c * c;
        a = u2f(u3.x); c = u2f(u3.y); s0 += a; q0 += a * a; s1 += c; q1 += c * c;
    }
    for (; r < M; r += g) {
        const ushort2 u = *reinterpret_cast<const ushort2*>(Y + (size_t)r * DM + t * 2);
        const float a = u2f(u.x), c = u2f(u.y);
        s0 += a; q0 += a * a;
        s1 += c; q1 += c * c;
    }
    float* p = part + (size_t)blockIdx.x * 1024;
    p[2 * t] = s0; p[2 * t + 1] = s1;
    p[512 + 2 * t] = q0; p[512 + 2 * t + 1] = q1;
}

__global__ __launch_bounds__(256) void bnstat2_k(const float* __restrict__ part, float* __restrict__ stats,
                                                 int nchunk, int M) {
    const int ch = blockIdx.x * 256 + threadIdx.x;
    if (ch >= 512) return;
    float S = 0.f, Qs = 0.f;
    for (int c = 0; c < nchunk; ++c) { S += part[c * 1024 + ch]; Qs += part[c * 1024 + 512 + ch]; }
    const float mean = S / (float)M;
    const float var = Qs / (float)M - mean * mean;
    stats[ch] = mean;
    stats[512 + ch] = fmaxf(var, 0.f);
}

__global__ __launch_bounds__(256) void bnpool_k(
    const bf16* __restrict__ Yc, const float* __restrict__ stats,
    const void* __restrict__ g, const void* __restrict__ bb, unsigned off,
    bf16* __restrict__ Out, int Lc, int Lout, int total, const int* __restrict__ flagp)
{
    const int f = *flagp;
    int i = blockIdx.x * 256 + threadIdx.x;
    if (i >= total) return;
    const int ch = i & 511;
    const int lp = (i >> 9) % Lout;
    const int b = i / (512 * Lout);
    const float mean = stats[ch], var = stats[512 + ch];
    const float sc = ldw(g, off + ch, f) * rsqrtf(var + 1e-5f);
    const float sh = ldw(bb, off + ch, f) - mean * sc;
    float mx = -INFINITY;
    const int l0 = 2 * lp - 1;
    #pragma unroll
    for (int d = 0; d < 3; ++d) {
        const int l = l0 + d;
        if (l >= 0 && l < Lc) {
            float v = b2f(Yc[((size_t)b * Lc + l) * DM + ch]) * sc + sh;
            v = v > 0.f ? v : expm1f(v);  // ELU
            mx = fmaxf(mx, v);
        }
    }
    Out[((size_t)b * Lout + lp) * DM + ch] = __float2bfloat16(mx);
}

// ---------------- final projection to CO=7, dtype-matched store ----------------
__global__ __launch_bounds__(256) void fc_k(
    const bf16* __restrict__ Yn, const void* __restrict__ fcw, const void* __restrict__ fcb,
    void* __restrict__ out, int total, const int* __restrict__ flagp)
{
    const int f = *flagp;
    int i = blockIdx.x * 256 + threadIdx.x;
    if (i >= total) return;
    const int r = i / 7, co = i % 7;
    const bf16* yr = Yn + (size_t)r * DM;
    float acc = ldw(fcb, co, f);
    for (int d = 0; d < DM; ++d) acc += b2f(yr[d]) * ldw(fcw, d * 7 + co, f);
    if (f) ((bf16*)out)[i] = __float2bfloat16(acc);
    else   ((float*)out)[i] = acc;
}

// =============================================================================
extern "C" void kernel_launch(void* const* d_in, const int* in_sizes, int n_in,
                              void* d_out, int out_size, void* d_ws, size_t ws_size,
                              hipStream_t stream)
{
    const void* x_enc      = d_in[0];
    const void* x_mark_enc = d_in[1];
    const void* x_dec      = d_in[2];
    const void* x_mark_dec = d_in[3];
    const void* enc_vw = d_in[4];
    const void* enc_vb = d_in[5];
    const void* enc_mw = d_in[6];
    const void* enc_mb = d_in[7];
    const void* dec_vw = d_in[8];
    const void* dec_vb = d_in[9];
    const void* dec_mw = d_in[10];
    const void* dec_mb = d_in[11];
    const void* eW    = d_in[12];
    const void* ebi   = d_in[13];
    const void* effw1 = d_in[14];
    const void* effb1 = d_in[15];
    const void* effw2 = d_in[16];
    const void* effb2 = d_in[17];
    const void* eln1  = d_in[18];
    const void* eln2  = d_in[19];
    const void* cw    = d_in[20];
    const void* cb    = d_in[21];
    const void* cbn_g = d_in[22];
    const void* cbn_b = d_in[23];
    const void* enc_norm = d_in[24];
    const void* dsW   = d_in[25];
    const void* dsb   = d_in[26];
    const void* dcW   = d_in[27];
    const void* dcb   = d_in[28];
    const void* dffw1 = d_in[29];
    const void* dffb1 = d_in[30];
    const void* dffw2 = d_in[31];
    const void* dffb2 = d_in[32];
    const void* dln   = d_in[33];
    const void* dec_norm = d_in[34];
    const void* fcw   = d_in[35];
    const void* fcb   = d_in[36];

    // ---- workspace layout (~90 MiB; 111 MiB footprint ran clean in round 1) ----
    // X    [0, 8M)      : encoder acts; MEM + Yd in decoder phase
    // QKV  [8M, 40M)    : fused QKV / FFN hidden (aliased) / conv out / cross CQ+CKV
    // OUT  [40M, 48M)   : O-proj / FFN2 dest
    // WT   [48M, ~86.8M): ALL transposed weights (one-time prologue)
    // misc [88M, ~90M)  : IDX0/IDX1, PART (64*4KB), STATS, FLAG
    char* wsp = (char*)d_ws;
    bf16* X    = (bf16*)wsp;
    bf16* QKV  = (bf16*)(wsp + ((size_t)8 << 20));
    bf16* HID  = QKV;                                 // FFN hidden aliases dead QKV
    bf16* OUT  = (bf16*)(wsp + ((size_t)40 << 20));
    bf16* WT   = (bf16*)(wsp + ((size_t)48 << 20));
    int*   IDX0 = (int*)(wsp + ((size_t)88 << 20));   // 3*16*514 = 24672 ints
    int*   IDX1 = IDX0 + 24672;                       // 3*16*259 = 12432 ints
    float* PART = (float*)(wsp + ((size_t)89 << 20));
    float* STATS= (float*)(wsp + ((size_t)89 << 20) + (1 << 18));
    int*   FLAG = (int*)(wsp + ((size_t)89 << 20) + (1 << 18) + 4096);
    bf16* MEMb = X;                                               // [2080][512]
    bf16* Yd   = (bf16*)(wsp + (size_t)16 * 130 * 512 * 2);       // [4096][512]

    // transposed weight sub-arenas (element offsets)
    bf16* WTE  = WT;                    // enc QKVO: (i*4+q)*262144
    bf16* EW1T = WT + 3145728;          // + i*1048576
    bf16* EW2T = WT + 6291456;          // + i*1048576
    bf16* CWT  = WT + 9437184;          // + i*786432
    bf16* DSWt = WT + 11010048;         // + (i*4+q)*262144
    bf16* DCWt = WT + 13107200;
    bf16* DW1T = WT + 15204352;
    bf16* DW2T = WT + 17301504;

    auto cdiv = [](int a, int b) { return (a + b - 1) / b; };
    auto gemm = [&](const bf16* A, const bf16* Wt, const void* bias, unsigned boff,
                    bf16* C, int M, int N, int K, int lda, int ldc, bool relu) {
        dim3 g(N / 128, cdiv(M, 128));
        if (relu) mgemm_k<false, true><<<g, 256, 0, stream>>>(
            (const short*)A, nullptr, (const short*)Wt, bias, boff, C, M, N, K, lda, ldc, FLAG);
        else      mgemm_k<false, false><<<g, 256, 0, stream>>>(
            (const short*)A, nullptr, (const short*)Wt, bias, boff, C, M, N, K, lda, ldc, FLAG);
    };
    auto gemm64 = [&](const bf16* A, const bf16* Wt, const void* bias, unsigned boff,
                      bf16* C, int M, int N, int K, int lda, int ldc, bool relu) {
        dim3 g(N / 64, cdiv(M, 64));
        if (relu) mgemm64_k<false, true><<<g, 256, 0, stream>>>(
            (const short*)A, nullptr, (const short*)Wt, bias, boff, C, M, N, K, lda, ldc, FLAG);
        else      mgemm64_k<false, false><<<g, 256, 0, stream>>>(
            (const short*)A, nullptr, (const short*)Wt, bias, boff, C, M, N, K, lda, ldc, FLAG);
    };
    auto transp = [&](const void* W, unsigned zstride, int nz, bf16* out, int K, int N) {
        transp_k<<<dim3(N / 32, K / 32, nz), 256, 0, stream>>>(W, 0u, zstride, out, K, N, FLAG);
    };

    // ---- prologue: sniff, all weight transposes, conv indices, embeddings ----
    sniff_k<<<1, 256, 0, stream>>>((const unsigned*)x_mark_enc, 16384, FLAG);
    transp(eW,    262144u, 12, WTE,  512, 512);
    transp(effw1, 1048576u, 3, EW1T, 512, 2048);
    transp(effw2, 1048576u, 3, EW2T, 2048, 512);
    convw_k<<<cdiv(1572864, 256), 256, 0, stream>>>(cw, CWT, 1572864, FLAG);
    transp(dsW,   262144u, 8, DSWt, 512, 512);
    transp(dcW,   262144u, 8, DCWt, 512, 512);
    transp(dffw1, 1048576u, 2, DW1T, 512, 2048);
    transp(dffw2, 1048576u, 2, DW2T, 2048, 512);
    convidx_k<<<cdiv(24672, 256), 256, 0, stream>>>(IDX0, 514, 512, 24672);
    convidx_k<<<cdiv(12432, 256), 256, 0, stream>>>(IDX1, 259, 257, 12432);
    embed_k<<<cdiv(16 * 512 * 512, 256), 256, 0, stream>>>(
        x_enc, enc_vw, enc_vb, x_mark_enc, enc_mw, enc_mb, X, 16 * 512, 7, 4, FLAG);

    // ---- encoder ----
    int L = 512;
    for (int i = 0; i < 3; ++i) {
        const int rows = 16 * L;
        const unsigned b0 = (unsigned)i * 4u * 512u;
        // QKV: big grid only at L=512 -> mgemm; else 64x64 for concurrency
        if (i == 0) gemm(X, WTE + (size_t)i * 4 * 262144, ebi, b0, QKV, rows, 1536, 512, 512, 1536, false);
        else      gemm64(X, WTE + (size_t)i * 4 * 262144, ebi, b0, QKV, rows, 1536, 512, 512, 1536, false);
        fattn_k<0><<<dim3(cdiv(L, 16), 8, 16), 512, 0, stream>>>(
            QKV, QKV + 512, QKV + 1024, 1536, 1536, L, L);
        gemm64(QKV, WTE + (size_t)(i * 4 + 3) * 262144, ebi, b0 + 1536u, OUT, rows, 512, 512, 1536, 512, false);
        ln_off_k<<<rows, 256, 0, stream>>>(X, OUT, eln1, (unsigned)i * 1024u, X, FLAG);

        if (i == 0) gemm(X, EW1T + (size_t)i * 1048576, effb1, (unsigned)i * 2048u, HID, rows, 2048, 512, 512, 2048, true);
        else      gemm64(X, EW1T + (size_t)i * 1048576, effb1, (unsigned)i * 2048u, HID, rows, 2048, 512, 512, 2048, true);
        gemm64(HID, EW2T + (size_t)i * 1048576, effb2, (unsigned)i * 512u, OUT, rows, 512, 2048, 2048, 512, false);
        ln_off_k<<<rows, 256, 0, stream>>>(X, OUT, eln2, (unsigned)i * 1024u, X, FLAG);

        if (i < 2) {
            const int Lc = L + 2, Mc = 16 * Lc;
            const int* IDXi = (i == 0) ? IDX0 : IDX1;
            mgemm64_k<true, false><<<dim3(8, cdiv(Mc, 64)), 256, 0, stream>>>(
                (const short*)X, IDXi, (const short*)(CWT + (size_t)i * 786432),
                cb, (unsigned)i * 512u, QKV, Mc, 512, 1536, 512, 512, FLAG);
            bnstat1_k<<<64, 256, 0, stream>>>(QKV, PART, Mc);
            bnstat2_k<<<2, 256, 0, stream>>>(PART, STATS, 64, Mc);
            const int Lout = (L + 1) / 2 + 1;   // 514->257, 259->130
            const int tot = 16 * Lout * 512;
            bnpool_k<<<cdiv(tot, 256), 256, 0, stream>>>(
                QKV, STATS, cbn_g, cbn_b, (unsigned)i * 512u, X, Lc, Lout, tot, FLAG);
            L = Lout;
        }
    }
    const int Lm = L;  // 130
    ln_off_k<<<16 * Lm, 256, 0, stream>>>(X, nullptr, enc_norm, 0u, MEMb, FLAG);

    // ---- decoder embedding ----
    const int rowsD = 16 * 256;
    embed_k<<<cdiv(rowsD * 512, 256), 256, 0, stream>>>(
        x_dec, dec_vw, dec_vb, x_mark_dec, dec_mw, dec_mb, Yd, rowsD, 7, 4, FLAG);

    // ---- decoder (all GEMMs via 64x64 for concurrency) ----
    bf16* CQ  = QKV;                       // [4096][512]
    bf16* CKV = QKV + (size_t)4096 * 512;  // [2080][1024]
    for (int i = 0; i < 2; ++i) {
        const unsigned b0 = (unsigned)i * 4u * 512u;
        // self-attention
        gemm64(Yd, DSWt + (size_t)i * 4 * 262144, dsb, b0, QKV, rowsD, 1536, 512, 512, 1536, false);
        fattn_k<1><<<dim3(16, 8, 16), 512, 0, stream>>>(
            QKV, QKV + 512, QKV + 1024, 1536, 1536, 256, 256);
        gemm64(QKV, DSWt + (size_t)(i * 4 + 3) * 262144, dsb, b0 + 1536u, OUT, rowsD, 512, 512, 1536, 512, false);
        ln_off_k<<<rowsD, 256, 0, stream>>>(Yd, OUT, dln, (unsigned)(i * 3 + 0) * 1024u, Yd, FLAG);

        // cross-attention
        gemm64(Yd, DCWt + (size_t)i * 4 * 262144, dcb, b0, CQ, rowsD, 512, 512, 512, 512, false);
        gemm64(MEMb, DCWt + (size_t)(i * 4 + 1) * 262144, dcb, b0 + 512u, CKV, 16 * Lm, 1024, 512, 512, 1024, false);
        fattn_k<2><<<dim3(16, 8, 16), 512, 0, stream>>>(
            CQ, CKV, CKV + 512, 512, 1024, 256, Lm);
        gemm64(CQ, DCWt + (size_t)(i * 4 + 3) * 262144, dcb, b0 + 1536u, OUT, rowsD, 512, 512, 512, 512, false);
        ln_off_k<<<rowsD, 256, 0, stream>>>(Yd, OUT, dln, (unsigned)(i * 3 + 1) * 1024u, Yd, FLAG);

        // FFN
        gemm64(Yd, DW1T + (size_t)i * 1048576, dffb1, (unsigned)i * 2048u, HID, rowsD, 2048, 512, 512, 2048, true);
        gemm64(HID, DW2T + (size_t)i * 1048576, dffb2, (unsigned)i * 512u, OUT, rowsD, 512, 2048, 2048, 512, false);
        ln_off_k<<<rowsD, 256, 0, stream>>>(Yd, OUT, dln, (unsigned)(i * 3 + 2) * 1024u, Yd, FLAG);
    }

    ln_off_k<<<rowsD, 256, 0, stream>>>(Yd, nullptr, dec_norm, 0u, OUT, FLAG);
    fc_k<<<cdiv(rowsD * 7, 256), 256, 0, stream>>>(OUT, fcw, fcb, d_out, rowsD * 7, FLAG);
}

// Round 12
// 1223.798 us; speedup vs baseline: 1.1857x; 1.0023x over previous
//
#include <hip/hip_runtime.h>
#include <hip/hip_bf16.h>

// Informer forward, MI355X. Round 20: F8 compile-time specialization of fattn phase-2.
//  - Round-19 post-mortem: net -10us but fattn<0> L512 REGRESSED 92.4 -> 100us
//    (VALUBusy 65 -> 52): at jm==8 the runtime `if (j < jm)` guards never skip work
//    but emit ~50 s_cmp+s_cbranch that break the interleaved-chain scheduling.
//    Smaller dispatches (jm 5/3/2.5) did benefit -> keep guards there.
//  - Fix: template<bool F8>; jmx = F8 ? 8 : jm. F8=true constant-folds every guard
//    -> branchless round-18 body (+__expf). Host picks F8 by Lk: only encoder L1
//    (Lk=512) is F8=true; L257/L130/causal/cross keep the guarded path.
//    Same ops executed -> numerics identical to round 19 (absmax 0.0088).
//  - Everything else untouched (single-lever A/B).
// Round 19: passed, absmax 0.0088, 1226.6 us.
// B=16, LE=512, LD=256, D=512, H=8, dk=64, DFF=2048, NE=3, ND=2, TOPK=16.
// Encoder lengths: 512 -> conv(514)/pool -> 257 -> conv(259)/pool -> 130.

#define DM 512
#define DK 64

using bf16 = __hip_bfloat16;
typedef short s8v __attribute__((ext_vector_type(8)));
typedef float f4v __attribute__((ext_vector_type(4)));

__device__ inline float b2f(bf16 x) { return __bfloat162float(x); }
__device__ inline float u2f(unsigned short u) { return __uint_as_float((unsigned)u << 16); }

// flag f: 1 = raw inputs are bf16, 0 = raw inputs are fp32. idx in ELEMENTS.
__device__ inline float ldw(const void* p, unsigned i, int f) {
    return f ? b2f(((const bf16*)p)[i]) : ((const float*)p)[i];
}

// order-preserving float->u32 (monotonic)
__device__ inline unsigned f2ord(float s) {
    unsigned u = __float_as_uint(s);
    return u ^ ((unsigned)((int)u >> 31) | 0x80000000u);
}

// popcount of mask bits strictly below this lane
__device__ inline int popc_lt(unsigned long long m) {
    return (int)__builtin_amdgcn_mbcnt_hi((unsigned)(m >> 32),
            __builtin_amdgcn_mbcnt_lo((unsigned)m, 0u));
}

// bijective chunked XCD swizzle (m204): linear id -> id such that each XCD
// (assumed lin%8 dispatch) owns a CONTIGUOUS id range. Perf-only heuristic.
__device__ inline int xcd_chunk_id(int lin, int nwg) {
    const int xcd = lin & 7;
    const int pos = lin >> 3;
    const int q = nwg >> 3, r = nwg & 7;
    return (xcd < r ? xcd * (q + 1) : r * (q + 1) + (xcd - r) * q) + pos;
}

// async global->LDS, 16 B per lane; lds dst must be wave-uniform (lane i lands at dst+16*i)
__device__ inline void gl_lds16(const short* g, short* l) {
    __builtin_amdgcn_global_load_lds(
        (const __attribute__((address_space(1))) unsigned int*)g,
        (__attribute__((address_space(3))) unsigned int*)l,
        16, 0, 0);
}

// ---------------- dtype sniffer ----------------
__global__ __launch_bounds__(256) void sniff_k(const unsigned* __restrict__ x, int nwords,
                                               int* __restrict__ flag) {
    __shared__ int red[4];
    const int t = threadIdx.x;
    int c = 0;
    for (int i = t; i < nwords; i += 256) c += ((x[i] & 0x7F80u) == 0x3F80u) ? 1 : 0;
    #pragma unroll
    for (int o = 32; o > 0; o >>= 1) c += __shfl_down(c, o);
    __syncthreads();
    if ((t & 63) == 0) red[t >> 6] = c;
    __syncthreads();
    if (t == 0) flag[0] = (red[0] + red[1] + red[2] + red[3] > nwords / 20) ? 1 : 0;
}

// ---------------- reductions (blockDim == 256) ----------------
__device__ inline float block_sum256(float v, float* red) {
    #pragma unroll
    for (int o = 32; o > 0; o >>= 1) v += __shfl_down(v, o);
    __syncthreads();
    if ((threadIdx.x & 63) == 0) red[threadIdx.x >> 6] = v;
    __syncthreads();
    return red[0] + red[1] + red[2] + red[3];
}

// ---------------- embedding ----------------
__global__ __launch_bounds__(256) void embed_k(
    const void* __restrict__ xv, const void* __restrict__ vw, const void* __restrict__ vb,
    const void* __restrict__ xm, const void* __restrict__ mw, const void* __restrict__ mb,
    bf16* __restrict__ Out, int rows, int Cv, int Cm, const int* __restrict__ flagp)
{
    const int f = *flagp;
    int i = blockIdx.x * 256 + threadIdx.x;
    if (i >= rows * DM) return;
    const int r = i >> 9, d = i & 511;
    float acc = ldw(vb, d, f) + ldw(mb, d, f);
    for (int c = 0; c < Cv; ++c) acc += ldw(xv, r * Cv + c, f) * ldw(vw, c * DM + d, f);
    for (int c = 0; c < Cm; ++c) acc += ldw(xm, r * Cm + c, f) * ldw(mw, c * DM + d, f);
    Out[i] = __float2bfloat16(acc);
}

// ---------------- weight transpose: raw [K][N] -> bf16 [N][K]; z batches sub-mats ----------------
__global__ __launch_bounds__(256) void transp_k(
    const void* __restrict__ W, unsigned off, unsigned zstride, bf16* __restrict__ out,
    int K, int N, const int* __restrict__ flagp)
{
    __shared__ float tile[32][33];
    const int f = *flagp;
    const unsigned zo = blockIdx.z * zstride;
    const int t = threadIdx.x;
    const int tx = t & 31, ty = t >> 5;               // 32 x 8
    const int n0 = blockIdx.x * 32, k0 = blockIdx.y * 32;
    #pragma unroll
    for (int i = 0; i < 4; ++i)
        tile[ty + 8 * i][tx] = ldw(W, off + zo + (unsigned)(k0 + ty + 8 * i) * N + n0 + tx, f);
    __syncthreads();
    #pragma unroll
    for (int i = 0; i < 4; ++i)
        out[(size_t)zo + (size_t)(n0 + ty + 8 * i) * K + k0 + tx] = __float2bfloat16(tile[tx][ty + 8 * i]);
}

// ---------------- MFMA GEMM 128x128 (256 thr), BK=64 single-buffer, T2 swizzle ----------------
// 8 K-iters (32 MFMA each) for K=512. Chunked XCD swizzle for A-panel L2 locality.
// Rule #21 layout: linear LDS dest + inverse-swizzled global source + swizzled read.
// Used only for large-grid GEMMs (encoder L1 QKV / FFN1: >= 768 blocks).
template<bool G3, bool RELU>
__global__ __launch_bounds__(256) void mgemm_k(
    const short* __restrict__ A, const int* __restrict__ ridx,
    const short* __restrict__ Wt,
    const void* __restrict__ bias, unsigned boff0,
    bf16* __restrict__ C, int M, int N, int K, int lda, int ldc,
    const int* __restrict__ flagp)
{
    __shared__ short As[128 * 64];
    __shared__ short Ws[128 * 64];
    const int t = threadIdx.x;
    const int gx = gridDim.x;
    const int id = xcd_chunk_id(blockIdx.x + gx * blockIdx.y, gx * gridDim.y);
    const int bn = (id % gx) * 128, bm = (id / gx) * 128;
    const int lane = t & 63, wave = t >> 6;
    const int mbase = (wave >> 1) * 64, nbase = (wave & 1) * 64;
    const int l15 = lane & 15, quad = lane >> 4;
    const int lrow = lane >> 3;                        // 8 rows per gl_lds16 call
    const int lk = ((lane & 7) ^ (lrow & 7)) * 8;      // inverse-swizzled source chunk

    f4v acc[4][4] = {};

    for (int k0 = 0; k0 < K; k0 += 64) {
        __syncthreads();
        #pragma unroll
        for (int j = 0; j < 4; ++j) {                  // A: 32 rows per wave
            const int rb = wave * 32 + j * 8;
            const int row = bm + rb + lrow;
            const int rowc = row < M ? row : M - 1;
            const short* g;
            if (G3) {
                const int r = ridx[(k0 >> 9) * M + rowc];
                g = A + (size_t)r * lda + (k0 & 511) + lk;
            } else {
                g = A + (size_t)rowc * lda + k0 + lk;
            }
            gl_lds16(g, &As[rb * 64]);
        }
        #pragma unroll
        for (int j = 0; j < 4; ++j) {                  // B: 32 rows per wave
            const int nb = wave * 32 + j * 8;
            gl_lds16(Wt + (size_t)(bn + nb + lrow) * K + k0 + lk, &Ws[nb * 64]);
        }
        __syncthreads();
        #pragma unroll
        for (int kk = 0; kk < 2; ++kk) {               // k0+32*kk ascending -> bit-identical
            s8v af[4], bfv[4];
            #pragma unroll
            for (int i = 0; i < 4; ++i) {
                const int ra = mbase + i * 16 + l15;
                af[i]  = *(const s8v*)&As[ra * 64 + (((kk * 4 + quad) ^ (ra & 7)) << 3)];
                const int rb2 = nbase + i * 16 + l15;
                bfv[i] = *(const s8v*)&Ws[rb2 * 64 + (((kk * 4 + quad) ^ (rb2 & 7)) << 3)];
            }
            #pragma unroll
            for (int mi = 0; mi < 4; ++mi)
                #pragma unroll
                for (int ni = 0; ni < 4; ++ni)
                    acc[mi][ni] = __builtin_amdgcn_mfma_f32_16x16x32_bf16(
                        af[mi], bfv[ni], acc[mi][ni], 0, 0, 0);
        }
    }

    const int f = *flagp;
    float bv[4];
    #pragma unroll
    for (int ni = 0; ni < 4; ++ni)
        bv[ni] = ldw(bias, boff0 + (unsigned)(bn + nbase + ni * 16 + l15), f);

    #pragma unroll
    for (int mi = 0; mi < 4; ++mi) {
        #pragma unroll
        for (int r = 0; r < 4; ++r) {
            const int row = bm + mbase + mi * 16 + quad * 4 + r;
            if (row < M) {
                #pragma unroll
                for (int ni = 0; ni < 4; ++ni) {
                    float o = acc[mi][ni][r] + bv[ni];
                    if (RELU) o = fmaxf(o, 0.f);
                    C[(size_t)row * ldc + bn + nbase + ni * 16 + l15] = __float2bfloat16(o);
                }
            }
        }
    }
}

// ---------------- MFMA GEMM 64x64 (256 thr, 4 waves x 32x32), BK=64, dbuf ----------------
// grid (N/64, cdiv(M,64)). Chunked XCD swizzle: A-panel fetched once per XCD.
// 8 MFMA + 8 swizzled ds_read_b128 per iter, one barrier/iter.
template<bool G3, bool RELU>
__global__ __launch_bounds__(256) void mgemm64_k(
    const short* __restrict__ A, const int* __restrict__ ridx,
    const short* __restrict__ Wt,
    const void* __restrict__ bias, unsigned boff0,
    bf16* __restrict__ C, int M, int N, int K, int lda, int ldc,
    const int* __restrict__ flagp)
{
    __shared__ short As[2][64 * 64];
    __shared__ short Ws[2][64 * 64];
    const int t = threadIdx.x;
    const int gx = gridDim.x;
    const int id = xcd_chunk_id(blockIdx.x + gx * blockIdx.y, gx * gridDim.y);
    const int bn = (id % gx) * 64, bm = (id / gx) * 64;
    const int lane = t & 63, wave = t >> 6;
    const int mbase = (wave >> 1) * 32, nbase = (wave & 1) * 32;
    const int l15 = lane & 15, quad = lane >> 4;
    const int lrow = lane >> 3;                        // 8 rows per gl_lds16 call
    const int lk = ((lane & 7) ^ (lrow & 7)) * 8;      // inverse-swizzled source chunk

    f4v acc[2][2] = {};

    auto stage = [&](int buf, int k0) {
        #pragma unroll
        for (int j = 0; j < 2; ++j) {                  // A: 16 rows per wave
            const int rb = wave * 16 + j * 8;
            const int row = bm + rb + lrow;
            const int rowc = row < M ? row : M - 1;
            const short* g;
            if (G3) {
                const int r = ridx[(k0 >> 9) * M + rowc];
                g = A + (size_t)r * lda + (k0 & 511) + lk;
            } else {
                g = A + (size_t)rowc * lda + k0 + lk;
            }
            gl_lds16(g, &As[buf][rb * 64]);
        }
        #pragma unroll
        for (int j = 0; j < 2; ++j) {                  // B: 16 rows per wave
            const int nb = wave * 16 + j * 8;
            gl_lds16(Wt + (size_t)(bn + nb + lrow) * K + k0 + lk, &Ws[buf][nb * 64]);
        }
    };

    const int nt = K >> 6;
    stage(0, 0);
    __syncthreads();
    for (int it = 0; it < nt; ++it) {
        if (it + 1 < nt) stage((it + 1) & 1, (it + 1) << 6);
        const int cb = it & 1;
        #pragma unroll
        for (int kk = 0; kk < 2; ++kk) {               // k0+32*kk ascending -> bit-identical
            s8v af[2], bfv[2];
            #pragma unroll
            for (int i = 0; i < 2; ++i) {
                const int ra = mbase + i * 16 + l15;
                af[i]  = *(const s8v*)&As[cb][ra * 64 + (((kk * 4 + quad) ^ (ra & 7)) << 3)];
                const int rb2 = nbase + i * 16 + l15;
                bfv[i] = *(const s8v*)&Ws[cb][rb2 * 64 + (((kk * 4 + quad) ^ (rb2 & 7)) << 3)];
            }
            #pragma unroll
            for (int mi = 0; mi < 2; ++mi)
                #pragma unroll
                for (int ni = 0; ni < 2; ++ni)
                    acc[mi][ni] = __builtin_amdgcn_mfma_f32_16x16x32_bf16(
                        af[mi], bfv[ni], acc[mi][ni], 0, 0, 0);
        }
        if (it + 1 < nt) __syncthreads();
    }

    const int f = *flagp;
    float bv[2];
    #pragma unroll
    for (int ni = 0; ni < 2; ++ni)
        bv[ni] = ldw(bias, boff0 + (unsigned)(bn + nbase + ni * 16 + l15), f);

    #pragma unroll
    for (int mi = 0; mi < 2; ++mi) {
        #pragma unroll
        for (int r = 0; r < 4; ++r) {
            const int row = bm + mbase + mi * 16 + quad * 4 + r;
            if (row < M) {
                #pragma unroll
                for (int ni = 0; ni < 2; ++ni) {
                    float o = acc[mi][ni][r] + bv[ni];
                    if (RELU) o = fmaxf(o, 0.f);
                    C[(size_t)row * ldc + bn + nbase + ni * 16 + l15] = __float2bfloat16(o);
                }
            }
        }
    }
}

// ---------------- fused tile attention (strided q/k/v), 512 threads ----------------
// MODE 0: ProbSparse top-16. MODE 1: causal. MODE 2: plain cross.
// F8: compile-time "jm == 8" (host passes true only when Lk == 512) -> all phase-2
// guards constant-fold to the branchless round-18 body. F8=false keeps wave-uniform
// jm guards (helps jm 5/3/2.5 dispatches). XCD-locality swizzle; 8 waves; phase 1 =
// MFMA QK^T (direct-global K frags, 2-deep pipeline); phase 2+3 = rows {wave, wave+8}
// fused; __expf for all softmax exps.
template<int MODE, bool F8>
__global__ __launch_bounds__(512, 8) void fattn_k(
    bf16* __restrict__ q, const bf16* __restrict__ k, const bf16* __restrict__ v,
    int ldq, int ldkv, int Lq, int Lk)
{
    __shared__ short Qs[16 * 72];
    __shared__ float S[16 * 516];
    __shared__ int   PC[16][16];
    __shared__ float PE[16][16];

    const int t = threadIdx.x;
    // ---- XCD swizzle (bijective: nwg = gx*128, always % 8 == 0) ----
    const int gx = gridDim.x;
    const int nwg = gx * 128;                         // y=8, z=16 fixed
    const int lin = blockIdx.x + gx * (blockIdx.y + 8 * blockIdx.z);
    const int id = (lin & 7) * (nwg >> 3) + (lin >> 3);
    const int q0 = (id % gx) * 16;
    const int h  = (id / gx) & 7;
    const int b  = id / (gx * 8);

    const int lane = t & 63, wave = t >> 6;           // 8 waves
    const int l15 = lane & 15, quad = lane >> 4;

    const int qv = (Lq - q0) < 16 ? (Lq - q0) : 16;

    const bf16* Kbase = k + (size_t)b * Lk * ldkv + h * DK;
    const bf16* Vbase = v + (size_t)b * Lk * ldkv + h * DK;
    bf16* Qbase = q + (size_t)(b * Lq + q0) * ldq + h * DK;

    const int kmax = (MODE == 1) ? (q0 + 16 < Lk ? q0 + 16 : Lk) : Lk;
    const int ntile = (kmax + 63) >> 6;
    const int kpad = ntile << 6;
    const int nchunk = kpad >> 4;
    const int jmx = F8 ? 8 : ntile;                   // compile-time 8 when F8

    {   // Q stage: all 512 threads (4B each; 16 rows x 128B)
        const int qr = t >> 5;
        const int qsrc = qr < qv ? qr : qv - 1;
        *(ushort2*)&Qs[qr * 72 + (t & 31) * 2] =
            *(const ushort2*)(Qbase + (size_t)qsrc * ldq + (t & 31) * 2);
    }
    __syncthreads();

    // ---- phase 1: S = QK^T / 8 (+ masks); 2-deep K-load pipeline ----
    {
        const s8v a0 = *(const s8v*)&Qs[l15 * 72 + quad * 8];
        const s8v a1 = *(const s8v*)&Qs[l15 * 72 + 32 + quad * 8];
        int c = wave;
        s8v b0, b1;
        if (c < nchunk) {
            int srow = c * 16 + l15; if (srow >= Lk) srow = Lk - 1;
            const bf16* kp = Kbase + (size_t)srow * ldkv + quad * 8;
            b0 = *(const s8v*)kp;
            b1 = *(const s8v*)(kp + 32);
        }
        while (c < nchunk) {
            const int cn = c + 8;
            s8v n0, n1;
            if (cn < nchunk) {
                int srow = cn * 16 + l15; if (srow >= Lk) srow = Lk - 1;
                const bf16* kp = Kbase + (size_t)srow * ldkv + quad * 8;
                n0 = *(const s8v*)kp;
                n1 = *(const s8v*)(kp + 32);
            }
            f4v acc = {0.f, 0.f, 0.f, 0.f};
            acc = __builtin_amdgcn_mfma_f32_16x16x32_bf16(a0, b0, acc, 0, 0, 0);
            acc = __builtin_amdgcn_mfma_f32_16x16x32_bf16(a1, b1, acc, 0, 0, 0);
            const int colg = c * 16 + l15;
            #pragma unroll
            for (int r = 0; r < 4; ++r) {
                const int qrow = quad * 4 + r;
                float s = acc[r] * 0.125f;
                if (colg >= Lk) s = -1e9f;
                if (MODE == 1 && colg > q0 + qrow) s = -1e9f;
                S[qrow * 516 + colg] = s;
            }
            b0 = n0; b1 = n1; c = cn;
        }
    }
    __syncthreads();

    // ---- phase 2+3: rows {wave, wave+8} processed fused ----
    const int rowA = wave, rowB = wave + 8;
    float aA = 0.f, aB = 0.f;
    float invA, invB;
    if (MODE == 0) {
        // packed keys: 23-bit quantized score | 9-bit col; j >= jmx stays 0
        unsigned keyA[8], keyB[8];
        #pragma unroll
        for (int j = 0; j < 8; ++j) {
            keyA[j] = 0u; keyB[j] = 0u;
            if (j < jmx) {
                const int col = lane + 64 * j;
                keyA[j] = (f2ord(S[rowA * 516 + col]) & 0xFFFFFE00u) | (unsigned)col;
                keyB[j] = (f2ord(S[rowB * 516 + col]) & 0xFFFFFE00u) | (unsigned)col;
            }
        }
        // row maxes (exp offsets): two interleaved butterflies
        unsigned kmA = keyA[0], kmB = keyB[0];
        #pragma unroll
        for (int j = 1; j < 8; ++j) {
            if (j < jmx) {
                kmA = kmA > keyA[j] ? kmA : keyA[j];
                kmB = kmB > keyB[j] ? kmB : keyB[j];
            }
        }
        #pragma unroll
        for (int off = 1; off < 64; off <<= 1) {
            const unsigned oA = __shfl_xor(kmA, off);
            const unsigned oB = __shfl_xor(kmB, off);
            kmA = kmA > oA ? kmA : oA;
            kmB = kmB > oB ? kmB : oB;
        }
        const float mrA = S[rowA * 516 + (int)(kmA & 511u)];
        const float mrB = S[rowB * 516 + (int)(kmB & 511u)];

        // interleaved full-32-bit binary searches. Largest T with
        // count(key >= T) >= 16; keys distinct -> terminates at exactly 16.
        // Zero-keys never satisfy key >= T2 (T2 >= 1) -> skipping exact.
        unsigned TA = 0u, TB = 0u;
        bool dA = false, dB = false;
        for (int bbit = 31; bbit >= 0; --bbit) {
            if (!dA) {
                const unsigned T2 = TA | (1u << bbit);
                int c = 0;
                #pragma unroll
                for (int j = 0; j < 8; ++j)
                    if (j < jmx) c += (int)__popcll(__ballot(keyA[j] >= T2));
                if (c >= 16) { TA = T2; dA = (c == 16); }
            }
            if (!dB) {
                const unsigned T2 = TB | (1u << bbit);
                int c = 0;
                #pragma unroll
                for (int j = 0; j < 8; ++j)
                    if (j < jmx) c += (int)__popcll(__ballot(keyB[j] >= T2));
                if (c >= 16) { TB = T2; dB = (c == 16); }
            }
            if (dA && dB) break;
        }

        // compaction: exactly the 16 keys >= T per row -> (col, e) in LDS
        int cntA = 0, cntB = 0;
        #pragma unroll
        for (int j = 0; j < 8; ++j) {
            if (j < jmx) {
                const bool sA = keyA[j] >= TA;
                const unsigned long long balA = __ballot(sA);
                if (sA) {
                    const int p = cntA + popc_lt(balA);
                    const int col = (int)(keyA[j] & 511u);
                    PC[rowA][p] = col;
                    PE[rowA][p] = __expf(S[rowA * 516 + col] - mrA);
                }
                cntA += (int)__popcll(balA);
                const bool sB = keyB[j] >= TB;
                const unsigned long long balB = __ballot(sB);
                if (sB) {
                    const int p = cntB + popc_lt(balB);
                    const int col = (int)(keyB[j] & 511u);
                    PC[rowB][p] = col;
                    PE[rowB][p] = __expf(S[rowB * 516 + col] - mrB);
                }
                cntB += (int)__popcll(balB);
            }
        }
        // wave-private rows: same-wave DS ops in order; no barrier needed

        float denA = 0.f, denB = 0.f;
        #pragma unroll
        for (int it = 0; it < 16; ++it) {
            const int cA = PC[rowA][it];
            const float eA = PE[rowA][it];
            denA += eA;
            aA += eA * b2f(Vbase[(size_t)cA * ldkv + lane]);
            const int cB = PC[rowB][it];
            const float eB = PE[rowB][it];
            denB += eB;
            aB += eB * b2f(Vbase[(size_t)cB * ldkv + lane]);
        }
        invA = 1.f / denA;
        invB = 1.f / denB;
    } else {
        float lvA = -INFINITY, lvB = -INFINITY;
        #pragma unroll
        for (int j = 0; j < 8; ++j) {
            if (j < jmx) {
                const int col = lane + 64 * j;   // col < kpad guaranteed
                lvA = fmaxf(lvA, S[rowA * 516 + col]);
                lvB = fmaxf(lvB, S[rowB * 516 + col]);
            }
        }
        #pragma unroll
        for (int off = 1; off < 64; off <<= 1) {
            lvA = fmaxf(lvA, __shfl_xor(lvA, off));
            lvB = fmaxf(lvB, __shfl_xor(lvB, off));
        }
        float pA = 0.f, pB = 0.f;
        #pragma unroll
        for (int j = 0; j < 8; ++j) {
            if (j < jmx) {
                const int col = lane + 64 * j;
                const float wA = __expf(S[rowA * 516 + col] - lvA);
                const float wB = __expf(S[rowB * 516 + col] - lvB);
                S[rowA * 516 + col] = wA;
                S[rowB * 516 + col] = wB;
                pA += wA; pB += wB;
            }
        }
        #pragma unroll
        for (int off = 1; off < 64; off <<= 1) {
            pA += __shfl_xor(pA, off);
            pB += __shfl_xor(pB, off);
        }
        invA = 1.f / pA;
        invB = 1.f / pB;
        // fused PV: one V row feeds both rows' FMAs. Causal-masked cols have
        // w = exp(-1e9 - lv) = +0 exactly -> running to kmax is bit-identical.
        #pragma unroll 8
        for (int k2 = 0; k2 < kmax; ++k2) {
            const float vv = b2f(Vbase[(size_t)k2 * ldkv + lane]);
            aA += S[rowA * 516 + k2] * vv;
            aB += S[rowB * 516 + k2] * vv;
        }
    }
    if (rowA < qv)
        Qbase[(size_t)rowA * ldq + lane] = __float2bfloat16(aA * invA);
    if (rowB < qv)
        Qbase[(size_t)rowB * ldq + lane] = __float2bfloat16(aB * invB);
}

// ---------------- layernorm over D=512, optional residual; in-place safe ----------------
__global__ __launch_bounds__(256) void ln_off_k(
    const bf16* __restrict__ X, const bf16* __restrict__ R,
    const void* __restrict__ gb, unsigned goff,
    bf16* __restrict__ Out, const int* __restrict__ flagp)
{
    __shared__ float red[4];
    const int f = *flagp;
    const int t = threadIdx.x;
    const size_t base = (size_t)blockIdx.x * DM;
    float v0 = b2f(X[base + t]), v1 = b2f(X[base + t + 256]);
    if (R) { v0 += b2f(R[base + t]); v1 += b2f(R[base + t + 256]); }
    const float mean = block_sum256(v0 + v1, red) * (1.f / 512.f);
    const float d0 = v0 - mean, d1 = v1 - mean;
    const float var = block_sum256(d0 * d0 + d1 * d1, red) * (1.f / 512.f);
    const float rstd = rsqrtf(var + 1e-5f);
    Out[base + t]       = __float2bfloat16(d0 * rstd * ldw(gb, goff + t, f)       + ldw(gb, goff + 512 + t, f));
    Out[base + t + 256] = __float2bfloat16(d1 * rstd * ldw(gb, goff + t + 256, f) + ldw(gb, goff + 768 + t, f));
}

// ---------------- conv distill helpers ----------------
// conv weights w[2][o][c][j] -> transposed GEMM layout wt[layer][o][j*512+c]
__global__ __launch_bounds__(256) void convw_k(const void* __restrict__ w,
                                               bf16* __restrict__ wt, int total,
                                               const int* __restrict__ flagp) {
    const int f = *flagp;
    int i = blockIdx.x * 256 + threadIdx.x;
    if (i >= total) return;
    const int layer = i / 786432, rem2 = i % 786432;
    const int o = rem2 / 1536, rem = rem2 % 1536;
    const int j = rem >> 9, c = rem & 511;
    wt[i] = __float2bfloat16(ldw(w, (unsigned)layer * 786432u + (unsigned)(o * 512 + c) * 3 + j, f));
}

__global__ __launch_bounds__(256) void convidx_k(int* __restrict__ idx, int Lc, int L, int total) {
    int i = blockIdx.x * 256 + threadIdx.x;
    if (i >= total) return;
    const int j = i / (16 * Lc), mrem = i % (16 * Lc);
    const int b = mrem / Lc, l = mrem % Lc;
    int src = l + j - 2;
    src %= L; if (src < 0) src += L;
    idx[i] = b * L + src;
}

// 64 blocks (PART arena = 64 * 4KB), 4-deep unrolled row loop for memory parallelism
__global__ __launch_bounds__(256) void bnstat1_k(const bf16* __restrict__ Y, float* __restrict__ part, int M) {
    const int t = threadIdx.x;
    const int g = gridDim.x;
    float s0 = 0.f, q0 = 0.f, s1 = 0.f, q1 = 0.f;
    int r = blockIdx.x;
    for (; r + 3 * g < M; r += 4 * g) {
        const ushort2 u0 = *reinterpret_cast<const ushort2*>(Y + (size_t)r * DM + t * 2);
        const ushort2 u1 = *reinterpret_cast<const ushort2*>(Y + (size_t)(r + g) * DM + t * 2);
        const ushort2 u2 = *reinterpret_cast<const ushort2*>(Y + (size_t)(r + 2 * g) * DM + t * 2);
        const ushort2 u3 = *reinterpret_cast<const ushort2*>(Y + (size_t)(r + 3 * g) * DM + t * 2);
        float a, c;
        a = u2f(u0.x); c = u2f(u0.y); s0 += a; q0 += a * a; s1 += c; q1 += c * c;
        a = u2f(u1.x); c = u2f(u1.y); s0 += a; q0 += a * a; s1 += c; q1 += c * c;
        a = u2f(u2.x); c = u2f(u2.y); s0 += a; q0 += a * a; s1 += c; q1 += c * c;
        a = u2f(u3.x); c = u2f(u3.y); s0 += a; q0 += a * a; s1 += c; q1 += c * c;
    }
    for (; r < M; r += g) {
        const ushort2 u = *reinterpret_cast<const ushort2*>(Y + (size_t)r * DM + t * 2);
        const float a = u2f(u.x), c = u2f(u.y);
        s0 += a; q0 += a * a;
        s1 += c; q1 += c * c;
    }
    float* p = part + (size_t)blockIdx.x * 1024;
    p[2 * t] = s0; p[2 * t + 1] = s1;
    p[512 + 2 * t] = q0; p[512 + 2 * t + 1] = q1;
}

__global__ __launch_bounds__(256) void bnstat2_k(const float* __restrict__ part, float* __restrict__ stats,
                                                 int nchunk, int M) {
    const int ch = blockIdx.x * 256 + threadIdx.x;
    if (ch >= 512) return;
    float S = 0.f, Qs = 0.f;
    for (int c = 0; c < nchunk; ++c) { S += part[c * 1024 + ch]; Qs += part[c * 1024 + 512 + ch]; }
    const float mean = S / (float)M;
    const float var = Qs / (float)M - mean * mean;
    stats[ch] = mean;
    stats[512 + ch] = fmaxf(var, 0.f);
}

__global__ __launch_bounds__(256) void bnpool_k(
    const bf16* __restrict__ Yc, const float* __restrict__ stats,
    const void* __restrict__ g, const void* __restrict__ bb, unsigned off,
    bf16* __restrict__ Out, int Lc, int Lout, int total, const int* __restrict__ flagp)
{
    const int f = *flagp;
    int i = blockIdx.x * 256 + threadIdx.x;
    if (i >= total) return;
    const int ch = i & 511;
    const int lp = (i >> 9) % Lout;
    const int b = i / (512 * Lout);
    const float mean = stats[ch], var = stats[512 + ch];
    const float sc = ldw(g, off + ch, f) * rsqrtf(var + 1e-5f);
    const float sh = ldw(bb, off + ch, f) - mean * sc;
    float mx = -INFINITY;
    const int l0 = 2 * lp - 1;
    #pragma unroll
    for (int d = 0; d < 3; ++d) {
        const int l = l0 + d;
        if (l >= 0 && l < Lc) {
            float v = b2f(Yc[((size_t)b * Lc + l) * DM + ch]) * sc + sh;
            v = v > 0.f ? v : expm1f(v);  // ELU
            mx = fmaxf(mx, v);
        }
    }
    Out[((size_t)b * Lout + lp) * DM + ch] = __float2bfloat16(mx);
}

// ---------------- final projection to CO=7, dtype-matched store ----------------
__global__ __launch_bounds__(256) void fc_k(
    const bf16* __restrict__ Yn, const void* __restrict__ fcw, const void* __restrict__ fcb,
    void* __restrict__ out, int total, const int* __restrict__ flagp)
{
    const int f = *flagp;
    int i = blockIdx.x * 256 + threadIdx.x;
    if (i >= total) return;
    const int r = i / 7, co = i % 7;
    const bf16* yr = Yn + (size_t)r * DM;
    float acc = ldw(fcb, co, f);
    for (int d = 0; d < DM; ++d) acc += b2f(yr[d]) * ldw(fcw, d * 7 + co, f);
    if (f) ((bf16*)out)[i] = __float2bfloat16(acc);
    else   ((float*)out)[i] = acc;
}

// =============================================================================
extern "C" void kernel_launch(void* const* d_in, const int* in_sizes, int n_in,
                              void* d_out, int out_size, void* d_ws, size_t ws_size,
                              hipStream_t stream)
{
    const void* x_enc      = d_in[0];
    const void* x_mark_enc = d_in[1];
    const void* x_dec      = d_in[2];
    const void* x_mark_dec = d_in[3];
    const void* enc_vw = d_in[4];
    const void* enc_vb = d_in[5];
    const void* enc_mw = d_in[6];
    const void* enc_mb = d_in[7];
    const void* dec_vw = d_in[8];
    const void* dec_vb = d_in[9];
    const void* dec_mw = d_in[10];
    const void* dec_mb = d_in[11];
    const void* eW    = d_in[12];
    const void* ebi   = d_in[13];
    const void* effw1 = d_in[14];
    const void* effb1 = d_in[15];
    const void* effw2 = d_in[16];
    const void* effb2 = d_in[17];
    const void* eln1  = d_in[18];
    const void* eln2  = d_in[19];
    const void* cw    = d_in[20];
    const void* cb    = d_in[21];
    const void* cbn_g = d_in[22];
    const void* cbn_b = d_in[23];
    const void* enc_norm = d_in[24];
    const void* dsW   = d_in[25];
    const void* dsb   = d_in[26];
    const void* dcW   = d_in[27];
    const void* dcb   = d_in[28];
    const void* dffw1 = d_in[29];
    const void* dffb1 = d_in[30];
    const void* dffw2 = d_in[31];
    const void* dffb2 = d_in[32];
    const void* dln   = d_in[33];
    const void* dec_norm = d_in[34];
    const void* fcw   = d_in[35];
    const void* fcb   = d_in[36];

    // ---- workspace layout (~90 MiB; 111 MiB footprint ran clean in round 1) ----
    // X    [0, 8M)      : encoder acts; MEM + Yd in decoder phase
    // QKV  [8M, 40M)    : fused QKV / FFN hidden (aliased) / conv out / cross CQ+CKV
    // OUT  [40M, 48M)   : O-proj / FFN2 dest
    // WT   [48M, ~86.8M): ALL transposed weights (one-time prologue)
    // misc [88M, ~90M)  : IDX0/IDX1, PART (64*4KB), STATS, FLAG
    char* wsp = (char*)d_ws;
    bf16* X    = (bf16*)wsp;
    bf16* QKV  = (bf16*)(wsp + ((size_t)8 << 20));
    bf16* HID  = QKV;                                 // FFN hidden aliases dead QKV
    bf16* OUT  = (bf16*)(wsp + ((size_t)40 << 20));
    bf16* WT   = (bf16*)(wsp + ((size_t)48 << 20));
    int*   IDX0 = (int*)(wsp + ((size_t)88 << 20));   // 3*16*514 = 24672 ints
    int*   IDX1 = IDX0 + 24672;                       // 3*16*259 = 12432 ints
    float* PART = (float*)(wsp + ((size_t)89 << 20));
    float* STATS= (float*)(wsp + ((size_t)89 << 20) + (1 << 18));
    int*   FLAG = (int*)(wsp + ((size_t)89 << 20) + (1 << 18) + 4096);
    bf16* MEMb = X;                                               // [2080][512]
    bf16* Yd   = (bf16*)(wsp + (size_t)16 * 130 * 512 * 2);       // [4096][512]

    // transposed weight sub-arenas (element offsets)
    bf16* WTE  = WT;                    // enc QKVO: (i*4+q)*262144
    bf16* EW1T = WT + 3145728;          // + i*1048576
    bf16* EW2T = WT + 6291456;          // + i*1048576
    bf16* CWT  = WT + 9437184;          // + i*786432
    bf16* DSWt = WT + 11010048;         // + (i*4+q)*262144
    bf16* DCWt = WT + 13107200;
    bf16* DW1T = WT + 15204352;
    bf16* DW2T = WT + 17301504;

    auto cdiv = [](int a, int b) { return (a + b - 1) / b; };
    auto gemm = [&](const bf16* A, const bf16* Wt, const void* bias, unsigned boff,
                    bf16* C, int M, int N, int K, int lda, int ldc, bool relu) {
        dim3 g(N / 128, cdiv(M, 128));
        if (relu) mgemm_k<false, true><<<g, 256, 0, stream>>>(
            (const short*)A, nullptr, (const short*)Wt, bias, boff, C, M, N, K, lda, ldc, FLAG);
        else      mgemm_k<false, false><<<g, 256, 0, stream>>>(
            (const short*)A, nullptr, (const short*)Wt, bias, boff, C, M, N, K, lda, ldc, FLAG);
    };
    auto gemm64 = [&](const bf16* A, const bf16* Wt, const void* bias, unsigned boff,
                      bf16* C, int M, int N, int K, int lda, int ldc, bool relu) {
        dim3 g(N / 64, cdiv(M, 64));
        if (relu) mgemm64_k<false, true><<<g, 256, 0, stream>>>(
            (const short*)A, nullptr, (const short*)Wt, bias, boff, C, M, N, K, lda, ldc, FLAG);
        else      mgemm64_k<false, false><<<g, 256, 0, stream>>>(
            (const short*)A, nullptr, (const short*)Wt, bias, boff, C, M, N, K, lda, ldc, FLAG);
    };
    auto transp = [&](const void* W, unsigned zstride, int nz, bf16* out, int K, int N) {
        transp_k<<<dim3(N / 32, K / 32, nz), 256, 0, stream>>>(W, 0u, zstride, out, K, N, FLAG);
    };

    // ---- prologue: sniff, all weight transposes, conv indices, embeddings ----
    sniff_k<<<1, 256, 0, stream>>>((const unsigned*)x_mark_enc, 16384, FLAG);
    transp(eW,    262144u, 12, WTE,  512, 512);
    transp(effw1, 1048576u, 3, EW1T, 512, 2048);
    transp(effw2, 1048576u, 3, EW2T, 2048, 512);
    convw_k<<<cdiv(1572864, 256), 256, 0, stream>>>(cw, CWT, 1572864, FLAG);
    transp(dsW,   262144u, 8, DSWt, 512, 512);
    transp(dcW,   262144u, 8, DCWt, 512, 512);
    transp(dffw1, 1048576u, 2, DW1T, 512, 2048);
    transp(dffw2, 1048576u, 2, DW2T, 2048, 512);
    convidx_k<<<cdiv(24672, 256), 256, 0, stream>>>(IDX0, 514, 512, 24672);
    convidx_k<<<cdiv(12432, 256), 256, 0, stream>>>(IDX1, 259, 257, 12432);
    embed_k<<<cdiv(16 * 512 * 512, 256), 256, 0, stream>>>(
        x_enc, enc_vw, enc_vb, x_mark_enc, enc_mw, enc_mb, X, 16 * 512, 7, 4, FLAG);

    // ---- encoder ----
    int L = 512;
    for (int i = 0; i < 3; ++i) {
        const int rows = 16 * L;
        const unsigned b0 = (unsigned)i * 4u * 512u;
        // QKV: big grid only at L=512 -> mgemm; else 64x64 for concurrency
        if (i == 0) gemm(X, WTE + (size_t)i * 4 * 262144, ebi, b0, QKV, rows, 1536, 512, 512, 1536, false);
        else      gemm64(X, WTE + (size_t)i * 4 * 262144, ebi, b0, QKV, rows, 1536, 512, 512, 1536, false);
        if (L == 512)
            fattn_k<0, true><<<dim3(cdiv(L, 16), 8, 16), 512, 0, stream>>>(
                QKV, QKV + 512, QKV + 1024, 1536, 1536, L, L);
        else
            fattn_k<0, false><<<dim3(cdiv(L, 16), 8, 16), 512, 0, stream>>>(
                QKV, QKV + 512, QKV + 1024, 1536, 1536, L, L);
        gemm64(QKV, WTE + (size_t)(i * 4 + 3) * 262144, ebi, b0 + 1536u, OUT, rows, 512, 512, 1536, 512, false);
        ln_off_k<<<rows, 256, 0, stream>>>(X, OUT, eln1, (unsigned)i * 1024u, X, FLAG);

        if (i == 0) gemm(X, EW1T + (size_t)i * 1048576, effb1, (unsigned)i * 2048u, HID, rows, 2048, 512, 512, 2048, true);
        else      gemm64(X, EW1T + (size_t)i * 1048576, effb1, (unsigned)i * 2048u, HID, rows, 2048, 512, 512, 2048, true);
        gemm64(HID, EW2T + (size_t)i * 1048576, effb2, (unsigned)i * 512u, OUT, rows, 512, 2048, 2048, 512, false);
        ln_off_k<<<rows, 256, 0, stream>>>(X, OUT, eln2, (unsigned)i * 1024u, X, FLAG);

        if (i < 2) {
            const int Lc = L + 2, Mc = 16 * Lc;
            const int* IDXi = (i == 0) ? IDX0 : IDX1;
            mgemm64_k<true, false><<<dim3(8, cdiv(Mc, 64)), 256, 0, stream>>>(
                (const short*)X, IDXi, (const short*)(CWT + (size_t)i * 786432),
                cb, (unsigned)i * 512u, QKV, Mc, 512, 1536, 512, 512, FLAG);
            bnstat1_k<<<64, 256, 0, stream>>>(QKV, PART, Mc);
            bnstat2_k<<<2, 256, 0, stream>>>(PART, STATS, 64, Mc);
            const int Lout = (L + 1) / 2 + 1;   // 514->257, 259->130
            const int tot = 16 * Lout * 512;
            bnpool_k<<<cdiv(tot, 256), 256, 0, stream>>>(
                QKV, STATS, cbn_g, cbn_b, (unsigned)i * 512u, X, Lc, Lout, tot, FLAG);
            L = Lout;
        }
    }
    const int Lm = L;  // 130
    ln_off_k<<<16 * Lm, 256, 0, stream>>>(X, nullptr, enc_norm, 0u, MEMb, FLAG);

    // ---- decoder embedding ----
    const int rowsD = 16 * 256;
    embed_k<<<cdiv(rowsD * 512, 256), 256, 0, stream>>>(
        x_dec, dec_vw, dec_vb, x_mark_dec, dec_mw, dec_mb, Yd, rowsD, 7, 4, FLAG);

    // ---- decoder (all GEMMs via 64x64 for concurrency) ----
    bf16* CQ  = QKV;                       // [4096][512]
    bf16* CKV = QKV + (size_t)4096 * 512;  // [2080][1024]
    for (int i = 0; i < 2; ++i) {
        const unsigned b0 = (unsigned)i * 4u * 512u;
        // self-attention
        gemm64(Yd, DSWt + (size_t)i * 4 * 262144, dsb, b0, QKV, rowsD, 1536, 512, 512, 1536, false);
        fattn_k<1, false><<<dim3(16, 8, 16), 512, 0, stream>>>(
            QKV, QKV + 512, QKV + 1024, 1536, 1536, 256, 256);
        gemm64(QKV, DSWt + (size_t)(i * 4 + 3) * 262144, dsb, b0 + 1536u, OUT, rowsD, 512, 512, 1536, 512, false);
        ln_off_k<<<rowsD, 256, 0, stream>>>(Yd, OUT, dln, (unsigned)(i * 3 + 0) * 1024u, Yd, FLAG);

        // cross-attention
        gemm64(Yd, DCWt + (size_t)i * 4 * 262144, dcb, b0, CQ, rowsD, 512, 512, 512, 512, false);
        gemm64(MEMb, DCWt + (size_t)(i * 4 + 1) * 262144, dcb, b0 + 512u, CKV, 16 * Lm, 1024, 512, 512, 1024, false);
        fattn_k<2, false><<<dim3(16, 8, 16), 512, 0, stream>>>(
            CQ, CKV, CKV + 512, 512, 1024, 256, Lm);
        gemm64(CQ, DCWt + (size_t)(i * 4 + 3) * 262144, dcb, b0 + 1536u, OUT, rowsD, 512, 512, 512, 512, false);
        ln_off_k<<<rowsD, 256, 0, stream>>>(Yd, OUT, dln, (unsigned)(i * 3 + 1) * 1024u, Yd, FLAG);

        // FFN
        gemm64(Yd, DW1T + (size_t)i * 1048576, dffb1, (unsigned)i * 2048u, HID, rowsD, 2048, 512, 512, 2048, true);
        gemm64(HID, DW2T + (size_t)i * 1048576, dffb2, (unsigned)i * 512u, OUT, rowsD, 512, 2048, 2048, 512, false);
        ln_off_k<<<rowsD, 256, 0, stream>>>(Yd, OUT, dln, (unsigned)(i * 3 + 2) * 1024u, Yd, FLAG);
    }

    ln_off_k<<<rowsD, 256, 0, stream>>>(Yd, nullptr, dec_norm, 0u, OUT, FLAG);
    fc_k<<<cdiv(rowsD * 7, 256), 256, 0, stream>>>(OUT, fcw, fcb, d_out, rowsD * 7, FLAG);
}

// Round 13
// 1213.945 us; speedup vs baseline: 1.1953x; 1.0081x over previous
//
#include <hip/hip_runtime.h>
#include <hip/hip_bf16.h>

// Informer forward, MI355X. Round 21: vectorize the elementwise tail (G13).
//  - Round-20: 1223.8us; F8 recovered L512 fattn to 93.3us (prediction matched).
//    Attention ~200us (structural floor for now), GEMMs ~600-650us, elementwise/LN
//    tail ~250-300us across ~25 launches.
//  - ln_off_k did FOUR scalar 2B bf16 loads + two scalar stores per thread
//    (Common-mistake #2: hipcc won't vectorize; 2-2.5x cost). Now each thread owns
//    contiguous pair (2t, 2t+1): one ushort2 load each for X/R, one ushort2 store.
//    fp32 reduction order changes pair grouping only (LN margin 0.0088 vs 0.0347).
//  - fc_k walked 512 bf16 scalars/thread; now s8v (16B) chunks, 8 FMAs per load,
//    same accumulation order.
//  - GEMMs + fattn untouched (clean A/B).
// Round 20: passed, absmax 0.0088, 1223.8 us.
// B=16, LE=512, LD=256, D=512, H=8, dk=64, DFF=2048, NE=3, ND=2, TOPK=16.
// Encoder lengths: 512 -> conv(514)/pool -> 257 -> conv(259)/pool -> 130.

#define DM 512
#define DK 64

using bf16 = __hip_bfloat16;
typedef short s8v __attribute__((ext_vector_type(8)));
typedef float f4v __attribute__((ext_vector_type(4)));

__device__ inline float b2f(bf16 x) { return __bfloat162float(x); }
__device__ inline float u2f(unsigned short u) { return __uint_as_float((unsigned)u << 16); }

// flag f: 1 = raw inputs are bf16, 0 = raw inputs are fp32. idx in ELEMENTS.
__device__ inline float ldw(const void* p, unsigned i, int f) {
    return f ? b2f(((const bf16*)p)[i]) : ((const float*)p)[i];
}

// order-preserving float->u32 (monotonic)
__device__ inline unsigned f2ord(float s) {
    unsigned u = __float_as_uint(s);
    return u ^ ((unsigned)((int)u >> 31) | 0x80000000u);
}

// popcount of mask bits strictly below this lane
__device__ inline int popc_lt(unsigned long long m) {
    return (int)__builtin_amdgcn_mbcnt_hi((unsigned)(m >> 32),
            __builtin_amdgcn_mbcnt_lo((unsigned)m, 0u));
}

// bijective chunked XCD swizzle (m204): linear id -> id such that each XCD
// (assumed lin%8 dispatch) owns a CONTIGUOUS id range. Perf-only heuristic.
__device__ inline int xcd_chunk_id(int lin, int nwg) {
    const int xcd = lin & 7;
    const int pos = lin >> 3;
    const int q = nwg >> 3, r = nwg & 7;
    return (xcd < r ? xcd * (q + 1) : r * (q + 1) + (xcd - r) * q) + pos;
}

// async global->LDS, 16 B per lane; lds dst must be wave-uniform (lane i lands at dst+16*i)
__device__ inline void gl_lds16(const short* g, short* l) {
    __builtin_amdgcn_global_load_lds(
        (const __attribute__((address_space(1))) unsigned int*)g,
        (__attribute__((address_space(3))) unsigned int*)l,
        16, 0, 0);
}

// ---------------- dtype sniffer ----------------
__global__ __launch_bounds__(256) void sniff_k(const unsigned* __restrict__ x, int nwords,
                                               int* __restrict__ flag) {
    __shared__ int red[4];
    const int t = threadIdx.x;
    int c = 0;
    for (int i = t; i < nwords; i += 256) c += ((x[i] & 0x7F80u) == 0x3F80u) ? 1 : 0;
    #pragma unroll
    for (int o = 32; o > 0; o >>= 1) c += __shfl_down(c, o);
    __syncthreads();
    if ((t & 63) == 0) red[t >> 6] = c;
    __syncthreads();
    if (t == 0) flag[0] = (red[0] + red[1] + red[2] + red[3] > nwords / 20) ? 1 : 0;
}

// ---------------- reductions (blockDim == 256) ----------------
__device__ inline float block_sum256(float v, float* red) {
    #pragma unroll
    for (int o = 32; o > 0; o >>= 1) v += __shfl_down(v, o);
    __syncthreads();
    if ((threadIdx.x & 63) == 0) red[threadIdx.x >> 6] = v;
    __syncthreads();
    return red[0] + red[1] + red[2] + red[3];
}

// ---------------- embedding ----------------
__global__ __launch_bounds__(256) void embed_k(
    const void* __restrict__ xv, const void* __restrict__ vw, const void* __restrict__ vb,
    const void* __restrict__ xm, const void* __restrict__ mw, const void* __restrict__ mb,
    bf16* __restrict__ Out, int rows, int Cv, int Cm, const int* __restrict__ flagp)
{
    const int f = *flagp;
    int i = blockIdx.x * 256 + threadIdx.x;
    if (i >= rows * DM) return;
    const int r = i >> 9, d = i & 511;
    float acc = ldw(vb, d, f) + ldw(mb, d, f);
    for (int c = 0; c < Cv; ++c) acc += ldw(xv, r * Cv + c, f) * ldw(vw, c * DM + d, f);
    for (int c = 0; c < Cm; ++c) acc += ldw(xm, r * Cm + c, f) * ldw(mw, c * DM + d, f);
    Out[i] = __float2bfloat16(acc);
}

// ---------------- weight transpose: raw [K][N] -> bf16 [N][K]; z batches sub-mats ----------------
__global__ __launch_bounds__(256) void transp_k(
    const void* __restrict__ W, unsigned off, unsigned zstride, bf16* __restrict__ out,
    int K, int N, const int* __restrict__ flagp)
{
    __shared__ float tile[32][33];
    const int f = *flagp;
    const unsigned zo = blockIdx.z * zstride;
    const int t = threadIdx.x;
    const int tx = t & 31, ty = t >> 5;               // 32 x 8
    const int n0 = blockIdx.x * 32, k0 = blockIdx.y * 32;
    #pragma unroll
    for (int i = 0; i < 4; ++i)
        tile[ty + 8 * i][tx] = ldw(W, off + zo + (unsigned)(k0 + ty + 8 * i) * N + n0 + tx, f);
    __syncthreads();
    #pragma unroll
    for (int i = 0; i < 4; ++i)
        out[(size_t)zo + (size_t)(n0 + ty + 8 * i) * K + k0 + tx] = __float2bfloat16(tile[tx][ty + 8 * i]);
}

// ---------------- MFMA GEMM 128x128 (256 thr), BK=64 single-buffer, T2 swizzle ----------------
// 8 K-iters (32 MFMA each) for K=512. Chunked XCD swizzle for A-panel L2 locality.
// Rule #21 layout: linear LDS dest + inverse-swizzled global source + swizzled read.
// Used only for large-grid GEMMs (encoder L1 QKV / FFN1: >= 768 blocks).
template<bool G3, bool RELU>
__global__ __launch_bounds__(256) void mgemm_k(
    const short* __restrict__ A, const int* __restrict__ ridx,
    const short* __restrict__ Wt,
    const void* __restrict__ bias, unsigned boff0,
    bf16* __restrict__ C, int M, int N, int K, int lda, int ldc,
    const int* __restrict__ flagp)
{
    __shared__ short As[128 * 64];
    __shared__ short Ws[128 * 64];
    const int t = threadIdx.x;
    const int gx = gridDim.x;
    const int id = xcd_chunk_id(blockIdx.x + gx * blockIdx.y, gx * gridDim.y);
    const int bn = (id % gx) * 128, bm = (id / gx) * 128;
    const int lane = t & 63, wave = t >> 6;
    const int mbase = (wave >> 1) * 64, nbase = (wave & 1) * 64;
    const int l15 = lane & 15, quad = lane >> 4;
    const int lrow = lane >> 3;                        // 8 rows per gl_lds16 call
    const int lk = ((lane & 7) ^ (lrow & 7)) * 8;      // inverse-swizzled source chunk

    f4v acc[4][4] = {};

    for (int k0 = 0; k0 < K; k0 += 64) {
        __syncthreads();
        #pragma unroll
        for (int j = 0; j < 4; ++j) {                  // A: 32 rows per wave
            const int rb = wave * 32 + j * 8;
            const int row = bm + rb + lrow;
            const int rowc = row < M ? row : M - 1;
            const short* g;
            if (G3) {
                const int r = ridx[(k0 >> 9) * M + rowc];
                g = A + (size_t)r * lda + (k0 & 511) + lk;
            } else {
                g = A + (size_t)rowc * lda + k0 + lk;
            }
            gl_lds16(g, &As[rb * 64]);
        }
        #pragma unroll
        for (int j = 0; j < 4; ++j) {                  // B: 32 rows per wave
            const int nb = wave * 32 + j * 8;
            gl_lds16(Wt + (size_t)(bn + nb + lrow) * K + k0 + lk, &Ws[nb * 64]);
        }
        __syncthreads();
        #pragma unroll
        for (int kk = 0; kk < 2; ++kk) {               // k0+32*kk ascending -> bit-identical
            s8v af[4], bfv[4];
            #pragma unroll
            for (int i = 0; i < 4; ++i) {
                const int ra = mbase + i * 16 + l15;
                af[i]  = *(const s8v*)&As[ra * 64 + (((kk * 4 + quad) ^ (ra & 7)) << 3)];
                const int rb2 = nbase + i * 16 + l15;
                bfv[i] = *(const s8v*)&Ws[rb2 * 64 + (((kk * 4 + quad) ^ (rb2 & 7)) << 3)];
            }
            #pragma unroll
            for (int mi = 0; mi < 4; ++mi)
                #pragma unroll
                for (int ni = 0; ni < 4; ++ni)
                    acc[mi][ni] = __builtin_amdgcn_mfma_f32_16x16x32_bf16(
                        af[mi], bfv[ni], acc[mi][ni], 0, 0, 0);
        }
    }

    const int f = *flagp;
    float bv[4];
    #pragma unroll
    for (int ni = 0; ni < 4; ++ni)
        bv[ni] = ldw(bias, boff0 + (unsigned)(bn + nbase + ni * 16 + l15), f);

    #pragma unroll
    for (int mi = 0; mi < 4; ++mi) {
        #pragma unroll
        for (int r = 0; r < 4; ++r) {
            const int row = bm + mbase + mi * 16 + quad * 4 + r;
            if (row < M) {
                #pragma unroll
                for (int ni = 0; ni < 4; ++ni) {
                    float o = acc[mi][ni][r] + bv[ni];
                    if (RELU) o = fmaxf(o, 0.f);
                    C[(size_t)row * ldc + bn + nbase + ni * 16 + l15] = __float2bfloat16(o);
                }
            }
        }
    }
}

// ---------------- MFMA GEMM 64x64 (256 thr, 4 waves x 32x32), BK=64, dbuf ----------------
// grid (N/64, cdiv(M,64)). Chunked XCD swizzle: A-panel fetched once per XCD.
// 8 MFMA + 8 swizzled ds_read_b128 per iter, one barrier/iter.
template<bool G3, bool RELU>
__global__ __launch_bounds__(256) void mgemm64_k(
    const short* __restrict__ A, const int* __restrict__ ridx,
    const short* __restrict__ Wt,
    const void* __restrict__ bias, unsigned boff0,
    bf16* __restrict__ C, int M, int N, int K, int lda, int ldc,
    const int* __restrict__ flagp)
{
    __shared__ short As[2][64 * 64];
    __shared__ short Ws[2][64 * 64];
    const int t = threadIdx.x;
    const int gx = gridDim.x;
    const int id = xcd_chunk_id(blockIdx.x + gx * blockIdx.y, gx * gridDim.y);
    const int bn = (id % gx) * 64, bm = (id / gx) * 64;
    const int lane = t & 63, wave = t >> 6;
    const int mbase = (wave >> 1) * 32, nbase = (wave & 1) * 32;
    const int l15 = lane & 15, quad = lane >> 4;
    const int lrow = lane >> 3;                        // 8 rows per gl_lds16 call
    const int lk = ((lane & 7) ^ (lrow & 7)) * 8;      // inverse-swizzled source chunk

    f4v acc[2][2] = {};

    auto stage = [&](int buf, int k0) {
        #pragma unroll
        for (int j = 0; j < 2; ++j) {                  // A: 16 rows per wave
            const int rb = wave * 16 + j * 8;
            const int row = bm + rb + lrow;
            const int rowc = row < M ? row : M - 1;
            const short* g;
            if (G3) {
                const int r = ridx[(k0 >> 9) * M + rowc];
                g = A + (size_t)r * lda + (k0 & 511) + lk;
            } else {
                g = A + (size_t)rowc * lda + k0 + lk;
            }
            gl_lds16(g, &As[buf][rb * 64]);
        }
        #pragma unroll
        for (int j = 0; j < 2; ++j) {                  // B: 16 rows per wave
            const int nb = wave * 16 + j * 8;
            gl_lds16(Wt + (size_t)(bn + nb + lrow) * K + k0 + lk, &Ws[buf][nb * 64]);
        }
    };

    const int nt = K >> 6;
    stage(0, 0);
    __syncthreads();
    for (int it = 0; it < nt; ++it) {
        if (it + 1 < nt) stage((it + 1) & 1, (it + 1) << 6);
        const int cb = it & 1;
        #pragma unroll
        for (int kk = 0; kk < 2; ++kk) {               // k0+32*kk ascending -> bit-identical
            s8v af[2], bfv[2];
            #pragma unroll
            for (int i = 0; i < 2; ++i) {
                const int ra = mbase + i * 16 + l15;
                af[i]  = *(const s8v*)&As[cb][ra * 64 + (((kk * 4 + quad) ^ (ra & 7)) << 3)];
                const int rb2 = nbase + i * 16 + l15;
                bfv[i] = *(const s8v*)&Ws[cb][rb2 * 64 + (((kk * 4 + quad) ^ (rb2 & 7)) << 3)];
            }
            #pragma unroll
            for (int mi = 0; mi < 2; ++mi)
                #pragma unroll
                for (int ni = 0; ni < 2; ++ni)
                    acc[mi][ni] = __builtin_amdgcn_mfma_f32_16x16x32_bf16(
                        af[mi], bfv[ni], acc[mi][ni], 0, 0, 0);
        }
        if (it + 1 < nt) __syncthreads();
    }

    const int f = *flagp;
    float bv[2];
    #pragma unroll
    for (int ni = 0; ni < 2; ++ni)
        bv[ni] = ldw(bias, boff0 + (unsigned)(bn + nbase + ni * 16 + l15), f);

    #pragma unroll
    for (int mi = 0; mi < 2; ++mi) {
        #pragma unroll
        for (int r = 0; r < 4; ++r) {
            const int row = bm + mbase + mi * 16 + quad * 4 + r;
            if (row < M) {
                #pragma unroll
                for (int ni = 0; ni < 2; ++ni) {
                    float o = acc[mi][ni][r] + bv[ni];
                    if (RELU) o = fmaxf(o, 0.f);
                    C[(size_t)row * ldc + bn + nbase + ni * 16 + l15] = __float2bfloat16(o);
                }
            }
        }
    }
}

// ---------------- fused tile attention (strided q/k/v), 512 threads ----------------
// MODE 0: ProbSparse top-16. MODE 1: causal. MODE 2: plain cross.
// F8: compile-time "jm == 8" (host passes true only when Lk == 512) -> all phase-2
// guards constant-fold to the branchless round-18 body. F8=false keeps wave-uniform
// jm guards. XCD-locality swizzle; 8 waves; phase 1 = MFMA QK^T (direct-global K
// frags, 2-deep pipeline); phase 2+3 = rows {wave, wave+8} fused; __expf softmax.
template<int MODE, bool F8>
__global__ __launch_bounds__(512, 8) void fattn_k(
    bf16* __restrict__ q, const bf16* __restrict__ k, const bf16* __restrict__ v,
    int ldq, int ldkv, int Lq, int Lk)
{
    __shared__ short Qs[16 * 72];
    __shared__ float S[16 * 516];
    __shared__ int   PC[16][16];
    __shared__ float PE[16][16];

    const int t = threadIdx.x;
    // ---- XCD swizzle (bijective: nwg = gx*128, always % 8 == 0) ----
    const int gx = gridDim.x;
    const int nwg = gx * 128;                         // y=8, z=16 fixed
    const int lin = blockIdx.x + gx * (blockIdx.y + 8 * blockIdx.z);
    const int id = (lin & 7) * (nwg >> 3) + (lin >> 3);
    const int q0 = (id % gx) * 16;
    const int h  = (id / gx) & 7;
    const int b  = id / (gx * 8);

    const int lane = t & 63, wave = t >> 6;           // 8 waves
    const int l15 = lane & 15, quad = lane >> 4;

    const int qv = (Lq - q0) < 16 ? (Lq - q0) : 16;

    const bf16* Kbase = k + (size_t)b * Lk * ldkv + h * DK;
    const bf16* Vbase = v + (size_t)b * Lk * ldkv + h * DK;
    bf16* Qbase = q + (size_t)(b * Lq + q0) * ldq + h * DK;

    const int kmax = (MODE == 1) ? (q0 + 16 < Lk ? q0 + 16 : Lk) : Lk;
    const int ntile = (kmax + 63) >> 6;
    const int kpad = ntile << 6;
    const int nchunk = kpad >> 4;
    const int jmx = F8 ? 8 : ntile;                   // compile-time 8 when F8

    {   // Q stage: all 512 threads (4B each; 16 rows x 128B)
        const int qr = t >> 5;
        const int qsrc = qr < qv ? qr : qv - 1;
        *(ushort2*)&Qs[qr * 72 + (t & 31) * 2] =
            *(const ushort2*)(Qbase + (size_t)qsrc * ldq + (t & 31) * 2);
    }
    __syncthreads();

    // ---- phase 1: S = QK^T / 8 (+ masks); 2-deep K-load pipeline ----
    {
        const s8v a0 = *(const s8v*)&Qs[l15 * 72 + quad * 8];
        const s8v a1 = *(const s8v*)&Qs[l15 * 72 + 32 + quad * 8];
        int c = wave;
        s8v b0, b1;
        if (c < nchunk) {
            int srow = c * 16 + l15; if (srow >= Lk) srow = Lk - 1;
            const bf16* kp = Kbase + (size_t)srow * ldkv + quad * 8;
            b0 = *(const s8v*)kp;
            b1 = *(const s8v*)(kp + 32);
        }
        while (c < nchunk) {
            const int cn = c + 8;
            s8v n0, n1;
            if (cn < nchunk) {
                int srow = cn * 16 + l15; if (srow >= Lk) srow = Lk - 1;
                const bf16* kp = Kbase + (size_t)srow * ldkv + quad * 8;
                n0 = *(const s8v*)kp;
                n1 = *(const s8v*)(kp + 32);
            }
            f4v acc = {0.f, 0.f, 0.f, 0.f};
            acc = __builtin_amdgcn_mfma_f32_16x16x32_bf16(a0, b0, acc, 0, 0, 0);
            acc = __builtin_amdgcn_mfma_f32_16x16x32_bf16(a1, b1, acc, 0, 0, 0);
            const int colg = c * 16 + l15;
            #pragma unroll
            for (int r = 0; r < 4; ++r) {
                const int qrow = quad * 4 + r;
                float s = acc[r] * 0.125f;
                if (colg >= Lk) s = -1e9f;
                if (MODE == 1 && colg > q0 + qrow) s = -1e9f;
                S[qrow * 516 + colg] = s;
            }
            b0 = n0; b1 = n1; c = cn;
        }
    }
    __syncthreads();

    // ---- phase 2+3: rows {wave, wave+8} processed fused ----
    const int rowA = wave, rowB = wave + 8;
    float aA = 0.f, aB = 0.f;
    float invA, invB;
    if (MODE == 0) {
        // packed keys: 23-bit quantized score | 9-bit col; j >= jmx stays 0
        unsigned keyA[8], keyB[8];
        #pragma unroll
        for (int j = 0; j < 8; ++j) {
            keyA[j] = 0u; keyB[j] = 0u;
            if (j < jmx) {
                const int col = lane + 64 * j;
                keyA[j] = (f2ord(S[rowA * 516 + col]) & 0xFFFFFE00u) | (unsigned)col;
                keyB[j] = (f2ord(S[rowB * 516 + col]) & 0xFFFFFE00u) | (unsigned)col;
            }
        }
        // row maxes (exp offsets): two interleaved butterflies
        unsigned kmA = keyA[0], kmB = keyB[0];
        #pragma unroll
        for (int j = 1; j < 8; ++j) {
            if (j < jmx) {
                kmA = kmA > keyA[j] ? kmA : keyA[j];
                kmB = kmB > keyB[j] ? kmB : keyB[j];
            }
        }
        #pragma unroll
        for (int off = 1; off < 64; off <<= 1) {
            const unsigned oA = __shfl_xor(kmA, off);
            const unsigned oB = __shfl_xor(kmB, off);
            kmA = kmA > oA ? kmA : oA;
            kmB = kmB > oB ? kmB : oB;
        }
        const float mrA = S[rowA * 516 + (int)(kmA & 511u)];
        const float mrB = S[rowB * 516 + (int)(kmB & 511u)];

        // interleaved full-32-bit binary searches. Largest T with
        // count(key >= T) >= 16; keys distinct -> terminates at exactly 16.
        // Zero-keys never satisfy key >= T2 (T2 >= 1) -> skipping exact.
        unsigned TA = 0u, TB = 0u;
        bool dA = false, dB = false;
        for (int bbit = 31; bbit >= 0; --bbit) {
            if (!dA) {
                const unsigned T2 = TA | (1u << bbit);
                int c = 0;
                #pragma unroll
                for (int j = 0; j < 8; ++j)
                    if (j < jmx) c += (int)__popcll(__ballot(keyA[j] >= T2));
                if (c >= 16) { TA = T2; dA = (c == 16); }
            }
            if (!dB) {
                const unsigned T2 = TB | (1u << bbit);
                int c = 0;
                #pragma unroll
                for (int j = 0; j < 8; ++j)
                    if (j < jmx) c += (int)__popcll(__ballot(keyB[j] >= T2));
                if (c >= 16) { TB = T2; dB = (c == 16); }
            }
            if (dA && dB) break;
        }

        // compaction: exactly the 16 keys >= T per row -> (col, e) in LDS
        int cntA = 0, cntB = 0;
        #pragma unroll
        for (int j = 0; j < 8; ++j) {
            if (j < jmx) {
                const bool sA = keyA[j] >= TA;
                const unsigned long long balA = __ballot(sA);
                if (sA) {
                    const int p = cntA + popc_lt(balA);
                    const int col = (int)(keyA[j] & 511u);
                    PC[rowA][p] = col;
                    PE[rowA][p] = __expf(S[rowA * 516 + col] - mrA);
                }
                cntA += (int)__popcll(balA);
                const bool sB = keyB[j] >= TB;
                const unsigned long long balB = __ballot(sB);
                if (sB) {
                    const int p = cntB + popc_lt(balB);
                    const int col = (int)(keyB[j] & 511u);
                    PC[rowB][p] = col;
                    PE[rowB][p] = __expf(S[rowB * 516 + col] - mrB);
                }
                cntB += (int)__popcll(balB);
            }
        }
        // wave-private rows: same-wave DS ops in order; no barrier needed

        float denA = 0.f, denB = 0.f;
        #pragma unroll
        for (int it = 0; it < 16; ++it) {
            const int cA = PC[rowA][it];
            const float eA = PE[rowA][it];
            denA += eA;
            aA += eA * b2f(Vbase[(size_t)cA * ldkv + lane]);
            const int cB = PC[rowB][it];
            const float eB = PE[rowB][it];
            denB += eB;
            aB += eB * b2f(Vbase[(size_t)cB * ldkv + lane]);
        }
        invA = 1.f / denA;
        invB = 1.f / denB;
    } else {
        float lvA = -INFINITY, lvB = -INFINITY;
        #pragma unroll
        for (int j = 0; j < 8; ++j) {
            if (j < jmx) {
                const int col = lane + 64 * j;   // col < kpad guaranteed
                lvA = fmaxf(lvA, S[rowA * 516 + col]);
                lvB = fmaxf(lvB, S[rowB * 516 + col]);
            }
        }
        #pragma unroll
        for (int off = 1; off < 64; off <<= 1) {
            lvA = fmaxf(lvA, __shfl_xor(lvA, off));
            lvB = fmaxf(lvB, __shfl_xor(lvB, off));
        }
        float pA = 0.f, pB = 0.f;
        #pragma unroll
        for (int j = 0; j < 8; ++j) {
            if (j < jmx) {
                const int col = lane + 64 * j;
                const float wA = __expf(S[rowA * 516 + col] - lvA);
                const float wB = __expf(S[rowB * 516 + col] - lvB);
                S[rowA * 516 + col] = wA;
                S[rowB * 516 + col] = wB;
                pA += wA; pB += wB;
            }
        }
        #pragma unroll
        for (int off = 1; off < 64; off <<= 1) {
            pA += __shfl_xor(pA, off);
            pB += __shfl_xor(pB, off);
        }
        invA = 1.f / pA;
        invB = 1.f / pB;
        // fused PV: one V row feeds both rows' FMAs. Causal-masked cols have
        // w = exp(-1e9 - lv) = +0 exactly -> running to kmax is bit-identical.
        #pragma unroll 8
        for (int k2 = 0; k2 < kmax; ++k2) {
            const float vv = b2f(Vbase[(size_t)k2 * ldkv + lane]);
            aA += S[rowA * 516 + k2] * vv;
            aB += S[rowB * 516 + k2] * vv;
        }
    }
    if (rowA < qv)
        Qbase[(size_t)rowA * ldq + lane] = __float2bfloat16(aA * invA);
    if (rowB < qv)
        Qbase[(size_t)rowB * ldq + lane] = __float2bfloat16(aB * invB);
}

// ---------------- layernorm over D=512, optional residual; in-place safe ----------------
// Vectorized (G13): each thread owns contiguous pair (2t, 2t+1): ushort2 loads/stores.
__global__ __launch_bounds__(256) void ln_off_k(
    const bf16* __restrict__ X, const bf16* __restrict__ R,
    const void* __restrict__ gb, unsigned goff,
    bf16* __restrict__ Out, const int* __restrict__ flagp)
{
    __shared__ float red[4];
    const int f = *flagp;
    const int t = threadIdx.x;
    const size_t base = (size_t)blockIdx.x * DM;
    const ushort2 ux = *(const ushort2*)(X + base + 2 * t);
    float v0 = u2f(ux.x), v1 = u2f(ux.y);
    if (R) {
        const ushort2 ur = *(const ushort2*)(R + base + 2 * t);
        v0 += u2f(ur.x); v1 += u2f(ur.y);
    }
    const float mean = block_sum256(v0 + v1, red) * (1.f / 512.f);
    const float d0 = v0 - mean, d1 = v1 - mean;
    const float var = block_sum256(d0 * d0 + d1 * d1, red) * (1.f / 512.f);
    const float rstd = rsqrtf(var + 1e-5f);
    const float o0 = d0 * rstd * ldw(gb, goff + 2 * t, f)     + ldw(gb, goff + 512 + 2 * t, f);
    const float o1 = d1 * rstd * ldw(gb, goff + 2 * t + 1, f) + ldw(gb, goff + 512 + 2 * t + 1, f);
    ushort2 ou;
    { bf16 h0 = __float2bfloat16(o0); ou.x = *(unsigned short*)&h0; }
    { bf16 h1 = __float2bfloat16(o1); ou.y = *(unsigned short*)&h1; }
    *(ushort2*)(Out + base + 2 * t) = ou;
}

// ---------------- conv distill helpers ----------------
// conv weights w[2][o][c][j] -> transposed GEMM layout wt[layer][o][j*512+c]
__global__ __launch_bounds__(256) void convw_k(const void* __restrict__ w,
                                               bf16* __restrict__ wt, int total,
                                               const int* __restrict__ flagp) {
    const int f = *flagp;
    int i = blockIdx.x * 256 + threadIdx.x;
    if (i >= total) return;
    const int layer = i / 786432, rem2 = i % 786432;
    const int o = rem2 / 1536, rem = rem2 % 1536;
    const int j = rem >> 9, c = rem & 511;
    wt[i] = __float2bfloat16(ldw(w, (unsigned)layer * 786432u + (unsigned)(o * 512 + c) * 3 + j, f));
}

__global__ __launch_bounds__(256) void convidx_k(int* __restrict__ idx, int Lc, int L, int total) {
    int i = blockIdx.x * 256 + threadIdx.x;
    if (i >= total) return;
    const int j = i / (16 * Lc), mrem = i % (16 * Lc);
    const int b = mrem / Lc, l = mrem % Lc;
    int src = l + j - 2;
    src %= L; if (src < 0) src += L;
    idx[i] = b * L + src;
}

// 64 blocks (PART arena = 64 * 4KB), 4-deep unrolled row loop for memory parallelism
__global__ __launch_bounds__(256) void bnstat1_k(const bf16* __restrict__ Y, float* __restrict__ part, int M) {
    const int t = threadIdx.x;
    const int g = gridDim.x;
    float s0 = 0.f, q0 = 0.f, s1 = 0.f, q1 = 0.f;
    int r = blockIdx.x;
    for (; r + 3 * g < M; r += 4 * g) {
        const ushort2 u0 = *reinterpret_cast<const ushort2*>(Y + (size_t)r * DM + t * 2);
        const ushort2 u1 = *reinterpret_cast<const ushort2*>(Y + (size_t)(r + g) * DM + t * 2);
        const ushort2 u2 = *reinterpret_cast<const ushort2*>(Y + (size_t)(r + 2 * g) * DM + t * 2);
        const ushort2 u3 = *reinterpret_cast<const ushort2*>(Y + (size_t)(r + 3 * g) * DM + t * 2);
        float a, c;
        a = u2f(u0.x); c = u2f(u0.y); s0 += a; q0 += a * a; s1 += c; q1 += c * c;
        a = u2f(u1.x); c = u2f(u1.y); s0 += a; q0 += a * a; s1 += c; q1 += c * c;
        a = u2f(u2.x); c = u2f(u2.y); s0 += a; q0 += a * a; s1 += c; q1 += c * c;
        a = u2f(u3.x); c = u2f(u3.y); s0 += a; q0 += a * a; s1 += c; q1 += c * c;
    }
    for (; r < M; r += g) {
        const ushort2 u = *reinterpret_cast<const ushort2*>(Y + (size_t)r * DM + t * 2);
        const float a = u2f(u.x), c = u2f(u.y);
        s0 += a; q0 += a * a;
        s1 += c; q1 += c * c;
    }
    float* p = part + (size_t)blockIdx.x * 1024;
    p[2 * t] = s0; p[2 * t + 1] = s1;
    p[512 + 2 * t] = q0; p[512 + 2 * t + 1] = q1;
}

__global__ __launch_bounds__(256) void bnstat2_k(const float* __restrict__ part, float* __restrict__ stats,
                                                 int nchunk, int M) {
    const int ch = blockIdx.x * 256 + threadIdx.x;
    if (ch >= 512) return;
    float S = 0.f, Qs = 0.f;
    for (int c = 0; c < nchunk; ++c) { S += part[c * 1024 + ch]; Qs += part[c * 1024 + 512 + ch]; }
    const float mean = S / (float)M;
    const float var = Qs / (float)M - mean * mean;
    stats[ch] = mean;
    stats[512 + ch] = fmaxf(var, 0.f);
}

__global__ __launch_bounds__(256) void bnpool_k(
    const bf16* __restrict__ Yc, const float* __restrict__ stats,
    const void* __restrict__ g, const void* __restrict__ bb, unsigned off,
    bf16* __restrict__ Out, int Lc, int Lout, int total, const int* __restrict__ flagp)
{
    const int f = *flagp;
    int i = blockIdx.x * 256 + threadIdx.x;
    if (i >= total) return;
    const int ch = i & 511;
    const int lp = (i >> 9) % Lout;
    const int b = i / (512 * Lout);
    const float mean = stats[ch], var = stats[512 + ch];
    const float sc = ldw(g, off + ch, f) * rsqrtf(var + 1e-5f);
    const float sh = ldw(bb, off + ch, f) - mean * sc;
    float mx = -INFINITY;
    const int l0 = 2 * lp - 1;
    #pragma unroll
    for (int d = 0; d < 3; ++d) {
        const int l = l0 + d;
        if (l >= 0 && l < Lc) {
            float v = b2f(Yc[((size_t)b * Lc + l) * DM + ch]) * sc + sh;
            v = v > 0.f ? v : expm1f(v);  // ELU
            mx = fmaxf(mx, v);
        }
    }
    Out[((size_t)b * Lout + lp) * DM + ch] = __float2bfloat16(mx);
}

// ---------------- final projection to CO=7, dtype-matched store ----------------
// Vectorized yr reads (s8v, 16 B); same accumulation order (sequential d).
__global__ __launch_bounds__(256) void fc_k(
    const bf16* __restrict__ Yn, const void* __restrict__ fcw, const void* __restrict__ fcb,
    void* __restrict__ out, int total, const int* __restrict__ flagp)
{
    const int f = *flagp;
    int i = blockIdx.x * 256 + threadIdx.x;
    if (i >= total) return;
    const int r = i / 7, co = i % 7;
    const bf16* yr = Yn + (size_t)r * DM;
    float acc = ldw(fcb, co, f);
    for (int d = 0; d < DM; d += 8) {
        const s8v y = *(const s8v*)(yr + d);
        #pragma unroll
        for (int jj = 0; jj < 8; ++jj)
            acc += u2f((unsigned short)y[jj]) * ldw(fcw, (unsigned)(d + jj) * 7 + co, f);
    }
    if (f) ((bf16*)out)[i] = __float2bfloat16(acc);
    else   ((float*)out)[i] = acc;
}

// =============================================================================
extern "C" void kernel_launch(void* const* d_in, const int* in_sizes, int n_in,
                              void* d_out, int out_size, void* d_ws, size_t ws_size,
                              hipStream_t stream)
{
    const void* x_enc      = d_in[0];
    const void* x_mark_enc = d_in[1];
    const void* x_dec      = d_in[2];
    const void* x_mark_dec = d_in[3];
    const void* enc_vw = d_in[4];
    const void* enc_vb = d_in[5];
    const void* enc_mw = d_in[6];
    const void* enc_mb = d_in[7];
    const void* dec_vw = d_in[8];
    const void* dec_vb = d_in[9];
    const void* dec_mw = d_in[10];
    const void* dec_mb = d_in[11];
    const void* eW    = d_in[12];
    const void* ebi   = d_in[13];
    const void* effw1 = d_in[14];
    const void* effb1 = d_in[15];
    const void* effw2 = d_in[16];
    const void* effb2 = d_in[17];
    const void* eln1  = d_in[18];
    const void* eln2  = d_in[19];
    const void* cw    = d_in[20];
    const void* cb    = d_in[21];
    const void* cbn_g = d_in[22];
    const void* cbn_b = d_in[23];
    const void* enc_norm = d_in[24];
    const void* dsW   = d_in[25];
    const void* dsb   = d_in[26];
    const void* dcW   = d_in[27];
    const void* dcb   = d_in[28];
    const void* dffw1 = d_in[29];
    const void* dffb1 = d_in[30];
    const void* dffw2 = d_in[31];
    const void* dffb2 = d_in[32];
    const void* dln   = d_in[33];
    const void* dec_norm = d_in[34];
    const void* fcw   = d_in[35];
    const void* fcb   = d_in[36];

    // ---- workspace layout (~90 MiB; 111 MiB footprint ran clean in round 1) ----
    // X    [0, 8M)      : encoder acts; MEM + Yd in decoder phase
    // QKV  [8M, 40M)    : fused QKV / FFN hidden (aliased) / conv out / cross CQ+CKV
    // OUT  [40M, 48M)   : O-proj / FFN2 dest
    // WT   [48M, ~86.8M): ALL transposed weights (one-time prologue)
    // misc [88M, ~90M)  : IDX0/IDX1, PART (64*4KB), STATS, FLAG
    char* wsp = (char*)d_ws;
    bf16* X    = (bf16*)wsp;
    bf16* QKV  = (bf16*)(wsp + ((size_t)8 << 20));
    bf16* HID  = QKV;                                 // FFN hidden aliases dead QKV
    bf16* OUT  = (bf16*)(wsp + ((size_t)40 << 20));
    bf16* WT   = (bf16*)(wsp + ((size_t)48 << 20));
    int*   IDX0 = (int*)(wsp + ((size_t)88 << 20));   // 3*16*514 = 24672 ints
    int*   IDX1 = IDX0 + 24672;                       // 3*16*259 = 12432 ints
    float* PART = (float*)(wsp + ((size_t)89 << 20));
    float* STATS= (float*)(wsp + ((size_t)89 << 20) + (1 << 18));
    int*   FLAG = (int*)(wsp + ((size_t)89 << 20) + (1 << 18) + 4096);
    bf16* MEMb = X;                                               // [2080][512]
    bf16* Yd   = (bf16*)(wsp + (size_t)16 * 130 * 512 * 2);       // [4096][512]

    // transposed weight sub-arenas (element offsets)
    bf16* WTE  = WT;                    // enc QKVO: (i*4+q)*262144
    bf16* EW1T = WT + 3145728;          // + i*1048576
    bf16* EW2T = WT + 6291456;          // + i*1048576
    bf16* CWT  = WT + 9437184;          // + i*786432
    bf16* DSWt = WT + 11010048;         // + (i*4+q)*262144
    bf16* DCWt = WT + 13107200;
    bf16* DW1T = WT + 15204352;
    bf16* DW2T = WT + 17301504;

    auto cdiv = [](int a, int b) { return (a + b - 1) / b; };
    auto gemm = [&](const bf16* A, const bf16* Wt, const void* bias, unsigned boff,
                    bf16* C, int M, int N, int K, int lda, int ldc, bool relu) {
        dim3 g(N / 128, cdiv(M, 128));
        if (relu) mgemm_k<false, true><<<g, 256, 0, stream>>>(
            (const short*)A, nullptr, (const short*)Wt, bias, boff, C, M, N, K, lda, ldc, FLAG);
        else      mgemm_k<false, false><<<g, 256, 0, stream>>>(
            (const short*)A, nullptr, (const short*)Wt, bias, boff, C, M, N, K, lda, ldc, FLAG);
    };
    auto gemm64 = [&](const bf16* A, const bf16* Wt, const void* bias, unsigned boff,
                      bf16* C, int M, int N, int K, int lda, int ldc, bool relu) {
        dim3 g(N / 64, cdiv(M, 64));
        if (relu) mgemm64_k<false, true><<<g, 256, 0, stream>>>(
            (const short*)A, nullptr, (const short*)Wt, bias, boff, C, M, N, K, lda, ldc, FLAG);
        else      mgemm64_k<false, false><<<g, 256, 0, stream>>>(
            (const short*)A, nullptr, (const short*)Wt, bias, boff, C, M, N, K, lda, ldc, FLAG);
    };
    auto transp = [&](const void* W, unsigned zstride, int nz, bf16* out, int K, int N) {
        transp_k<<<dim3(N / 32, K / 32, nz), 256, 0, stream>>>(W, 0u, zstride, out, K, N, FLAG);
    };

    // ---- prologue: sniff, all weight transposes, conv indices, embeddings ----
    sniff_k<<<1, 256, 0, stream>>>((const unsigned*)x_mark_enc, 16384, FLAG);
    transp(eW,    262144u, 12, WTE,  512, 512);
    transp(effw1, 1048576u, 3, EW1T, 512, 2048);
    transp(effw2, 1048576u, 3, EW2T, 2048, 512);
    convw_k<<<cdiv(1572864, 256), 256, 0, stream>>>(cw, CWT, 1572864, FLAG);
    transp(dsW,   262144u, 8, DSWt, 512, 512);
    transp(dcW,   262144u, 8, DCWt, 512, 512);
    transp(dffw1, 1048576u, 2, DW1T, 512, 2048);
    transp(dffw2, 1048576u, 2, DW2T, 2048, 512);
    convidx_k<<<cdiv(24672, 256), 256, 0, stream>>>(IDX0, 514, 512, 24672);
    convidx_k<<<cdiv(12432, 256), 256, 0, stream>>>(IDX1, 259, 257, 12432);
    embed_k<<<cdiv(16 * 512 * 512, 256), 256, 0, stream>>>(
        x_enc, enc_vw, enc_vb, x_mark_enc, enc_mw, enc_mb, X, 16 * 512, 7, 4, FLAG);

    // ---- encoder ----
    int L = 512;
    for (int i = 0; i < 3; ++i) {
        const int rows = 16 * L;
        const unsigned b0 = (unsigned)i * 4u * 512u;
        // QKV: big grid only at L=512 -> mgemm; else 64x64 for concurrency
        if (i == 0) gemm(X, WTE + (size_t)i * 4 * 262144, ebi, b0, QKV, rows, 1536, 512, 512, 1536, false);
        else      gemm64(X, WTE + (size_t)i * 4 * 262144, ebi, b0, QKV, rows, 1536, 512, 512, 1536, false);
        if (L == 512)
            fattn_k<0, true><<<dim3(cdiv(L, 16), 8, 16), 512, 0, stream>>>(
                QKV, QKV + 512, QKV + 1024, 1536, 1536, L, L);
        else
            fattn_k<0, false><<<dim3(cdiv(L, 16), 8, 16), 512, 0, stream>>>(
                QKV, QKV + 512, QKV + 1024, 1536, 1536, L, L);
        gemm64(QKV, WTE + (size_t)(i * 4 + 3) * 262144, ebi, b0 + 1536u, OUT, rows, 512, 512, 1536, 512, false);
        ln_off_k<<<rows, 256, 0, stream>>>(X, OUT, eln1, (unsigned)i * 1024u, X, FLAG);

        if (i == 0) gemm(X, EW1T + (size_t)i * 1048576, effb1, (unsigned)i * 2048u, HID, rows, 2048, 512, 512, 2048, true);
        else      gemm64(X, EW1T + (size_t)i * 1048576, effb1, (unsigned)i * 2048u, HID, rows, 2048, 512, 512, 2048, true);
        gemm64(HID, EW2T + (size_t)i * 1048576, effb2, (unsigned)i * 512u, OUT, rows, 512, 2048, 2048, 512, false);
        ln_off_k<<<rows, 256, 0, stream>>>(X, OUT, eln2, (unsigned)i * 1024u, X, FLAG);

        if (i < 2) {
            const int Lc = L + 2, Mc = 16 * Lc;
            const int* IDXi = (i == 0) ? IDX0 : IDX1;
            mgemm64_k<true, false><<<dim3(8, cdiv(Mc, 64)), 256, 0, stream>>>(
                (const short*)X, IDXi, (const short*)(CWT + (size_t)i * 786432),
                cb, (unsigned)i * 512u, QKV, Mc, 512, 1536, 512, 512, FLAG);
            bnstat1_k<<<64, 256, 0, stream>>>(QKV, PART, Mc);
            bnstat2_k<<<2, 256, 0, stream>>>(PART, STATS, 64, Mc);
            const int Lout = (L + 1) / 2 + 1;   // 514->257, 259->130
            const int tot = 16 * Lout * 512;
            bnpool_k<<<cdiv(tot, 256), 256, 0, stream>>>(
                QKV, STATS, cbn_g, cbn_b, (unsigned)i * 512u, X, Lc, Lout, tot, FLAG);
            L = Lout;
        }
    }
    const int Lm = L;  // 130
    ln_off_k<<<16 * Lm, 256, 0, stream>>>(X, nullptr, enc_norm, 0u, MEMb, FLAG);

    // ---- decoder embedding ----
    const int rowsD = 16 * 256;
    embed_k<<<cdiv(rowsD * 512, 256), 256, 0, stream>>>(
        x_dec, dec_vw, dec_vb, x_mark_dec, dec_mw, dec_mb, Yd, rowsD, 7, 4, FLAG);

    // ---- decoder (all GEMMs via 64x64 for concurrency) ----
    bf16* CQ  = QKV;                       // [4096][512]
    bf16* CKV = QKV + (size_t)4096 * 512;  // [2080][1024]
    for (int i = 0; i < 2; ++i) {
        const unsigned b0 = (unsigned)i * 4u * 512u;
        // self-attention
        gemm64(Yd, DSWt + (size_t)i * 4 * 262144, dsb, b0, QKV, rowsD, 1536, 512, 512, 1536, false);
        fattn_k<1, false><<<dim3(16, 8, 16), 512, 0, stream>>>(
            QKV, QKV + 512, QKV + 1024, 1536, 1536, 256, 256);
        gemm64(QKV, DSWt + (size_t)(i * 4 + 3) * 262144, dsb, b0 + 1536u, OUT, rowsD, 512, 512, 1536, 512, false);
        ln_off_k<<<rowsD, 256, 0, stream>>>(Yd, OUT, dln, (unsigned)(i * 3 + 0) * 1024u, Yd, FLAG);

        // cross-attention
        gemm64(Yd, DCWt + (size_t)i * 4 * 262144, dcb, b0, CQ, rowsD, 512, 512, 512, 512, false);
        gemm64(MEMb, DCWt + (size_t)(i * 4 + 1) * 262144, dcb, b0 + 512u, CKV, 16 * Lm, 1024, 512, 512, 1024, false);
        fattn_k<2, false><<<dim3(16, 8, 16), 512, 0, stream>>>(
            CQ, CKV, CKV + 512, 512, 1024, 256, Lm);
        gemm64(CQ, DCWt + (size_t)(i * 4 + 3) * 262144, dcb, b0 + 1536u, OUT, rowsD, 512, 512, 512, 512, false);
        ln_off_k<<<rowsD, 256, 0, stream>>>(Yd, OUT, dln, (unsigned)(i * 3 + 1) * 1024u, Yd, FLAG);

        // FFN
        gemm64(Yd, DW1T + (size_t)i * 1048576, dffb1, (unsigned)i * 2048u, HID, rowsD, 2048, 512, 512, 2048, true);
        gemm64(HID, DW2T + (size_t)i * 1048576, dffb2, (unsigned)i * 512u, OUT, rowsD, 512, 2048, 2048, 512, false);
        ln_off_k<<<rowsD, 256, 0, stream>>>(Yd, OUT, dln, (unsigned)(i * 3 + 2) * 1024u, Yd, FLAG);
    }

    ln_off_k<<<rowsD, 256, 0, stream>>>(Yd, nullptr, dec_norm, 0u, OUT, FLAG);
    fc_k<<<cdiv(rowsD * 7, 256), 256, 0, stream>>>(OUT, fcw, fcb, d_out, rowsD * 7, FLAG);
}